// Round 10
// baseline (495.798 us; speedup 1.0000x reference)
//
#include <hip/hip_runtime.h>
#include <math.h>

#define NN 50000
#define NE 400000
#define DDIM 128
#define NHEAD 4
#define NRAD 50
#define NGRAPH 100
#define TEMB 32
#define DOUT 512
#define CUTF 6.0f
#define PI_F 3.14159265358979323846f

#define SCAN_N ((NN + 255) / 256)  // 196 scan blocks

typedef unsigned int uint;
typedef unsigned short ushort;
typedef __attribute__((ext_vector_type(8))) short short8;
typedef __attribute__((ext_vector_type(4))) float f32x4;

// ---------------- helpers ----------------

__device__ __forceinline__ float gelu_tanh(float v) {
  float u = 0.7978845608028654f * (v + 0.044715f * v * v * v);
  return 0.5f * v * (1.0f + tanhf(u));
}

__device__ __forceinline__ ushort f2bf(float f) {  // RNE
  uint u = __float_as_uint(f);
  uint r = (u + 0x7fffu + ((u >> 16) & 1u)) >> 16;
  return (ushort)r;
}
__device__ __forceinline__ float bfl(uint u) { return __uint_as_float(u << 16); }
__device__ __forceinline__ float bfh(uint u) { return __uint_as_float(u & 0xffff0000u); }

// DPP sum reductions on the VALU (no ds_bpermute).
// 16-lane: quad xor1 (0xB1), quad xor2 (0x4E), row_half_mirror (0x141), row_mirror (0x140).
__device__ __forceinline__ float red16(float v) {
  v += __int_as_float(__builtin_amdgcn_update_dpp(0, __float_as_int(v), 0xB1, 0xF, 0xF, true));
  v += __int_as_float(__builtin_amdgcn_update_dpp(0, __float_as_int(v), 0x4E, 0xF, 0xF, true));
  v += __int_as_float(__builtin_amdgcn_update_dpp(0, __float_as_int(v), 0x141, 0xF, 0xF, true));
  v += __int_as_float(__builtin_amdgcn_update_dpp(0, __float_as_int(v), 0x140, 0xF, 0xF, true));
  return v;
}
// 8-lane sum (within aligned 8-lane groups)
__device__ __forceinline__ float red8(float v) {
  v += __int_as_float(__builtin_amdgcn_update_dpp(0, __float_as_int(v), 0xB1, 0xF, 0xF, true));
  v += __int_as_float(__builtin_amdgcn_update_dpp(0, __float_as_int(v), 0x4E, 0xF, 0xF, true));
  v += __int_as_float(__builtin_amdgcn_update_dpp(0, __float_as_int(v), 0x141, 0xF, 0xF, true));
  return v;
}

__global__ void k_fill_f(float* p, float v, int n) {
  int i = blockIdx.x * blockDim.x + threadIdx.x;
  if (i < n) p[i] = v;
}
__global__ void k_fill_i(int* p, int v, int n) {
  int i = blockIdx.x * blockDim.x + threadIdx.x;
  if (i < n) p[i] = v;
}

// ---------------- weight pre-convert + transpose: Wtb[l][fam][c][k] bf16 ----------------

__global__ void k_wconv(const float* __restrict__ Wq, const float* __restrict__ Wk,
                        const float* __restrict__ Wv, const float* __restrict__ Wo,
                        const float* __restrict__ Wm1, const float* __restrict__ Wm2,
                        ushort* __restrict__ Wtb) {
  int idx = blockIdx.x * 256 + threadIdx.x;  // 12*16384
  int m = idx >> 14;
  int r = idx & 16383;
  int c = r >> 7, k = r & 127;
  int l = m / 6, fam = m % 6;
  const float* src = fam == 0 ? Wq : fam == 1 ? Wk : fam == 2 ? Wv
                   : fam == 3 ? Wo : fam == 4 ? Wm1 : Wm2;
  Wtb[idx] = f2bf(src[l * 16384 + k * 128 + c]);
}

// ---------------- init: x = [emb[at], pos] @ W_init + b ----------------

__global__ void k_init(const float* __restrict__ pos, const int* __restrict__ at,
                       const float* __restrict__ emb, const float* __restrict__ W,
                       const float* __restrict__ b, float* __restrict__ x) {
  int idx = blockIdx.x * blockDim.x + threadIdx.x;
  if (idx >= NN * DDIM) return;
  int n = idx >> 7, c = idx & 127;
  const float* er = emb + (size_t)at[n] * TEMB;
  float acc = b[c];
#pragma unroll
  for (int t = 0; t < TEMB; ++t) acc = fmaf(er[t], W[t * DDIM + c], acc);
  acc = fmaf(pos[n * 3 + 0], W[(TEMB + 0) * DDIM + c], acc);
  acc = fmaf(pos[n * 3 + 1], W[(TEMB + 1) * DDIM + c], acc);
  acc = fmaf(pos[n * 3 + 2], W[(TEMB + 2) * DDIM + c], acc);
  x[idx] = acc;
}

// ---------------- per-edge distance + degree histogram (fused) ----------------

__global__ void k_edge(const float* __restrict__ pos, const int* __restrict__ ei,
                       float* __restrict__ de, int* __restrict__ deg) {
  int e = blockIdx.x * blockDim.x + threadIdx.x;
  if (e >= NE) return;
  int s = ei[e], t = ei[NE + e];
  float dx = pos[s * 3 + 0] - pos[t * 3 + 0] + 1e-8f;
  float dy = pos[s * 3 + 1] - pos[t * 3 + 1] + 1e-8f;
  float dz = pos[s * 3 + 2] - pos[t * 3 + 2] + 1e-8f;
  de[e] = sqrtf(dx * dx + dy * dy + dz * dz);
  atomicAdd(&deg[t], 1);
}

// ---------------- CSR build: parallel 3-pass exclusive scan ----------------

__global__ void k_scan1(const int* __restrict__ deg, int* __restrict__ bsum) {
  __shared__ int red[256];
  int i = blockIdx.x * 256 + threadIdx.x;
  red[threadIdx.x] = (i < NN) ? deg[i] : 0;
  __syncthreads();
  for (int off = 128; off > 0; off >>= 1) {
    if (threadIdx.x < off) red[threadIdx.x] += red[threadIdx.x + off];
    __syncthreads();
  }
  if (threadIdx.x == 0) bsum[blockIdx.x] = red[0];
}

__global__ void k_scan2(int* __restrict__ bsum) {  // 1 block, 256 threads >= SCAN_N
  __shared__ int sh[256];
  int t = threadIdx.x;
  int v = (t < SCAN_N) ? bsum[t] : 0;
  sh[t] = v;
  __syncthreads();
  for (int off = 1; off < 256; off <<= 1) {
    int u = (t >= off) ? sh[t - off] : 0;
    __syncthreads();
    sh[t] += u;
    __syncthreads();
  }
  if (t < SCAN_N) bsum[t] = (t == 0) ? 0 : sh[t - 1];
}

__global__ void k_scan3(const int* __restrict__ deg, const int* __restrict__ bsum,
                        int* __restrict__ rowptr, int* __restrict__ cnear,
                        int* __restrict__ cfar) {
  __shared__ int sh[256];
  int t = threadIdx.x;
  int i = blockIdx.x * 256 + t;
  int v = (i < NN) ? deg[i] : 0;
  sh[t] = v;
  __syncthreads();
  for (int off = 1; off < 256; off <<= 1) {
    int u = (t >= off) ? sh[t - off] : 0;
    __syncthreads();
    sh[t] += u;
    __syncthreads();
  }
  int excl = bsum[blockIdx.x] + sh[t] - v;
  if (i < NN) {
    rowptr[i] = excl;
    cnear[i] = excl;
    cfar[i] = excl + v;  // = rowptr[i+1]
    if (i == NN - 1) rowptr[NN] = excl + v;
  }
}

// scatter into near-first / far-last segmented CSR, packed records {src, d}
__global__ void k_scatter(const int* __restrict__ ei, const float* __restrict__ de,
                          int* __restrict__ cnear, int* __restrict__ cfar,
                          int2* __restrict__ er) {
  int e = blockIdx.x * blockDim.x + threadIdx.x;
  if (e >= NE) return;
  int src = ei[e], dst = ei[NE + e];
  float d = de[e];
  int idx;
  if (d < CUTF)
    idx = atomicAdd(&cnear[dst], 1);
  else
    idx = atomicSub(&cfar[dst], 1) - 1;
  er[idx] = make_int2(src, __float_as_int(d));
}

// ---------------- fused QKV GEMM: stage x once, 3 weights ----------------
// block 256 = 4 waves; 128 rows x 128 cols; 16x16x32 bf16 MFMA; wave owns 32 rows.

__global__ __launch_bounds__(256) void k_qkv(
    const float* __restrict__ x, const ushort* __restrict__ Wt3,
    ushort* __restrict__ qo, ushort* __restrict__ ko, ushort* __restrict__ vo) {
  __shared__ ushort Al[128 * 128];
  __shared__ ushort Wl[128 * 128];
  const int tid = threadIdx.x;
  const int r0 = blockIdx.x * 128;

  for (int i = tid; i < 128 * 16; i += 256) {
    int r = i >> 4, g = i & 15;
    int gr = r0 + r;
    float4 f0 = {0, 0, 0, 0}, f1 = {0, 0, 0, 0};
    if (gr < NN) {
      f0 = *(const float4*)&x[(size_t)gr * 128 + g * 8];
      f1 = *(const float4*)&x[(size_t)gr * 128 + g * 8 + 4];
    }
    int gs = g ^ (r & 7);
    ushort4 u0 = {f2bf(f0.x), f2bf(f0.y), f2bf(f0.z), f2bf(f0.w)};
    ushort4 u1 = {f2bf(f1.x), f2bf(f1.y), f2bf(f1.z), f2bf(f1.w)};
    *(ushort4*)&Al[r * 128 + gs * 8] = u0;
    *(ushort4*)&Al[r * 128 + gs * 8 + 4] = u1;
  }

  const int w = tid >> 6, l = tid & 63;
  const int lg = l >> 4, lr = l & 15;

  for (int m = 0; m < 3; ++m) {
    for (int i = tid; i < 128 * 16; i += 256) {
      int c = i >> 4, g = i & 15;
      ushort4 w0 = *(const ushort4*)&Wt3[m * 16384 + c * 128 + g * 8];
      ushort4 w1 = *(const ushort4*)&Wt3[m * 16384 + c * 128 + g * 8 + 4];
      int gs = g ^ (c & 7);
      *(ushort4*)&Wl[c * 128 + gs * 8] = w0;
      *(ushort4*)&Wl[c * 128 + gs * 8 + 4] = w1;
    }
    __syncthreads();

    f32x4 acc[2][8];
#pragma unroll
    for (int rt = 0; rt < 2; ++rt)
#pragma unroll
      for (int ct = 0; ct < 8; ++ct) acc[rt][ct] = (f32x4){0.f, 0.f, 0.f, 0.f};

#pragma unroll
    for (int ks = 0; ks < 4; ++ks) {
      short8 af[2];
#pragma unroll
      for (int rt = 0; rt < 2; ++rt) {
        int arow = w * 32 + rt * 16 + lr;
        int ga = (ks * 4 + lg) ^ (arow & 7);
        af[rt] = *(const short8*)&Al[arow * 128 + ga * 8];
      }
#pragma unroll
      for (int ct = 0; ct < 8; ++ct) {
        int col = ct * 16 + lr;
        int gb = (ks * 4 + lg) ^ (col & 7);
        short8 bf = *(const short8*)&Wl[col * 128 + gb * 8];
#pragma unroll
        for (int rt = 0; rt < 2; ++rt)
          acc[rt][ct] = __builtin_amdgcn_mfma_f32_16x16x32_bf16(af[rt], bf, acc[rt][ct], 0, 0, 0);
      }
    }

    ushort* o = (m == 0) ? qo : (m == 1) ? ko : vo;
#pragma unroll
    for (int rt = 0; rt < 2; ++rt)
#pragma unroll
      for (int ct = 0; ct < 8; ++ct) {
        int col = ct * 16 + lr;
#pragma unroll
        for (int r = 0; r < 4; ++r) {
          int row = r0 + w * 32 + rt * 16 + lg * 4 + r;
          if (row < NN) o[(size_t)row * 128 + col] = f2bf(acc[rt][ct][r]);
        }
      }
    __syncthreads();
  }
}

// ---------------- general GEMM: out = act(A@W + bias) (+resid) (+fused LN), A bf16 ----------------

template <bool BIAS, bool GELU, bool RESID, bool LNF>
__global__ __launch_bounds__(256) void k_gemm2(
    const ushort* __restrict__ A, const ushort* __restrict__ Wt,
    const float* __restrict__ bias, const float* __restrict__ resid,
    void* __restrict__ outp, const float* __restrict__ lng,
    const float* __restrict__ lnb, ushort* __restrict__ lnout) {
  __shared__ ushort Al[128 * 128];
  __shared__ ushort Wl[128 * 128];
  const int tid = threadIdx.x;
  const int r0 = blockIdx.x * 128;

  for (int i = tid; i < 128 * 16; i += 256) {
    int r = i >> 4, g = i & 15;
    int gr = r0 + r;
    ushort4 v0 = {0, 0, 0, 0}, v1 = {0, 0, 0, 0};
    if (gr < NN) {
      v0 = *(const ushort4*)&A[(size_t)gr * 128 + g * 8];
      v1 = *(const ushort4*)&A[(size_t)gr * 128 + g * 8 + 4];
    }
    int gs = g ^ (r & 7);
    *(ushort4*)&Al[r * 128 + gs * 8] = v0;
    *(ushort4*)&Al[r * 128 + gs * 8 + 4] = v1;
  }
  for (int i = tid; i < 128 * 16; i += 256) {
    int c = i >> 4, g = i & 15;
    ushort4 w0 = *(const ushort4*)&Wt[c * 128 + g * 8];
    ushort4 w1 = *(const ushort4*)&Wt[c * 128 + g * 8 + 4];
    int gs = g ^ (c & 7);
    *(ushort4*)&Wl[c * 128 + gs * 8] = w0;
    *(ushort4*)&Wl[c * 128 + gs * 8 + 4] = w1;
  }
  __syncthreads();

  const int w = tid >> 6, l = tid & 63;
  const int lg = l >> 4, lr = l & 15;
  f32x4 acc[2][8];
#pragma unroll
  for (int rt = 0; rt < 2; ++rt)
#pragma unroll
    for (int ct = 0; ct < 8; ++ct) acc[rt][ct] = (f32x4){0.f, 0.f, 0.f, 0.f};

#pragma unroll
  for (int ks = 0; ks < 4; ++ks) {
    short8 af[2];
#pragma unroll
    for (int rt = 0; rt < 2; ++rt) {
      int arow = w * 32 + rt * 16 + lr;
      int ga = (ks * 4 + lg) ^ (arow & 7);
      af[rt] = *(const short8*)&Al[arow * 128 + ga * 8];
    }
#pragma unroll
    for (int ct = 0; ct < 8; ++ct) {
      int col = ct * 16 + lr;
      int gb = (ks * 4 + lg) ^ (col & 7);
      short8 bf = *(const short8*)&Wl[col * 128 + gb * 8];
#pragma unroll
      for (int rt = 0; rt < 2; ++rt)
        acc[rt][ct] = __builtin_amdgcn_mfma_f32_16x16x32_bf16(af[rt], bf, acc[rt][ct], 0, 0, 0);
    }
  }

#pragma unroll
  for (int rt = 0; rt < 2; ++rt)
#pragma unroll
    for (int r = 0; r < 4; ++r) {
      int row = r0 + w * 32 + rt * 16 + lg * 4 + r;
      bool ok = row < NN;  // uniform across the 16-lane lr group
      float v[8];
#pragma unroll
      for (int ct = 0; ct < 8; ++ct) {
        int col = ct * 16 + lr;
        float vv = acc[rt][ct][r];
        if (BIAS) vv += bias[col];
        if (GELU) vv = gelu_tanh(vv);
        if (RESID) vv += ok ? resid[(size_t)row * 128 + col] : 0.f;
        v[ct] = vv;
      }
      if (RESID || LNF) {
        if (ok)
#pragma unroll
          for (int ct = 0; ct < 8; ++ct)
            ((float*)outp)[(size_t)row * 128 + ct * 16 + lr] = v[ct];
      } else {
        if (ok)
#pragma unroll
          for (int ct = 0; ct < 8; ++ct)
            ((ushort*)outp)[(size_t)row * 128 + ct * 16 + lr] = f2bf(v[ct]);
      }
      if (LNF) {
        float s = 0.f, ss = 0.f;
#pragma unroll
        for (int ct = 0; ct < 8; ++ct) {
          s += v[ct];
          ss = fmaf(v[ct], v[ct], ss);
        }
#pragma unroll
        for (int msk = 8; msk >= 1; msk >>= 1) {
          s += __shfl_xor(s, msk);
          ss += __shfl_xor(ss, msk);
        }
        float mean = s * (1.0f / DDIM);
        float var = ss * (1.0f / DDIM) - mean * mean;
        float inv = rsqrtf(var + 1e-5f);
        if (ok)
#pragma unroll
          for (int ct = 0; ct < 8; ++ct) {
            int col = ct * 16 + lr;
            lnout[(size_t)row * 128 + col] =
                f2bf((v[ct] - mean) * inv * lng[col] + lnb[col]);
          }
      }
    }
}

// ---------------- qe precompute: qe[n][j][h] ----------------

__global__ __launch_bounds__(256) void k_qe(const ushort* __restrict__ qnb,
                                            const float* __restrict__ We,
                                            ushort* __restrict__ qe) {
  __shared__ float Wlds[NRAD][DDIM + 1];
  __shared__ float qlds[4][DDIM];
  int tid = threadIdx.x;
  for (int i = tid; i < NRAD * DDIM; i += 256) Wlds[i / DDIM][i % DDIM] = We[i];
  __syncthreads();
  int w = tid >> 6, t = tid & 63;
  for (int rep = 0; rep < 2; ++rep) {
    int n = blockIdx.x * 8 + rep * 4 + w;
    uint qu = *(const uint*)&qnb[(size_t)n * DDIM + 2 * t];
    qlds[w][2 * t] = bfl(qu);
    qlds[w][2 * t + 1] = bfh(qu);
    if (t < NRAD) {
      float e0 = 0.f, e1 = 0.f, e2 = 0.f, e3 = 0.f;
#pragma unroll
      for (int d = 0; d < 32; ++d) e0 = fmaf(Wlds[t][d], qlds[w][d], e0);
#pragma unroll
      for (int d = 32; d < 64; ++d) e1 = fmaf(Wlds[t][d], qlds[w][d], e1);
#pragma unroll
      for (int d = 64; d < 96; ++d) e2 = fmaf(Wlds[t][d], qlds[w][d], e2);
#pragma unroll
      for (int d = 96; d < 128; ++d) e3 = fmaf(Wlds[t][d], qlds[w][d], e3);
      ushort4 o = {f2bf(e0), f2bf(e1), f2bf(e2), f2bf(e3)};
      *(ushort4*)&qe[(size_t)n * (NRAD * 4) + 4 * t] = o;
    }
  }
}

// ---------------- fused attention v6: near full-wave + far half-wave (2 edges/wave) ----------------

__device__ __forceinline__ float rbf_fill(float d, int j) {
  const float step = CUTF / (NRAD - 1);
  const float gamma = (NRAD / CUTF) * (NRAD / CUTF);
  float mu = j * step;
  float dm = d - mu;
  float env = 0.5f * (__cosf(PI_F * d / CUTF) + 1.0f);
  return __expf(-gamma * dm * dm) * env;
}

#define SCALE_QK 0.17677669529663687f

__global__ __launch_bounds__(256) void k_attn6(
    const ushort* __restrict__ qnb, const ushort* __restrict__ knb,
    const ushort* __restrict__ vnb, const ushort* __restrict__ qe,
    const int2* __restrict__ er, const int* __restrict__ rowptr,
    const int* __restrict__ nearend, const float* __restrict__ We,
    ushort* __restrict__ msgb) {
  __shared__ float qel[4][64][4];   // [wave][j][head]; reused for arbn in epilogue
  __shared__ float rbl[4][64];
  __shared__ float aml[4][128];     // far-accumulator remap buffer (per wave)
  __shared__ ushort Wel[NRAD * DDIM];
  const int tid = threadIdx.x;
  for (int i = tid; i < NRAD * DDIM; i += 256) Wel[i] = f2bf(We[i]);
  __syncthreads();

  const int w = tid >> 6, t = tid & 63;
  const int n = blockIdx.x * 4 + w;
  const int h = t >> 4;       // near-layout head (16-lane groups)
  const int j0 = t & 15;
  const int hw = t >> 5;      // half-wave id (far loop)
  const int c = t & 31;       // lane in half; owns dims 4c..4c+3 (far loop)
  uint qu = *(const uint*)&qnb[(size_t)n * DDIM + 2 * t];
  const float q0 = bfl(qu), q1 = bfh(qu);
  uint2 qp = *(const uint2*)&qnb[(size_t)n * DDIM + 4 * c];
  const float fq0 = bfl(qp.x), fq1 = bfh(qp.x), fq2 = bfl(qp.y), fq3 = bfh(qp.y);
  if (t < NRAD) {
    ushort4 qv = *(const ushort4*)&qe[(size_t)n * (NRAD * 4) + 4 * t];
    qel[w][t][0] = bfl(qv.x);
    qel[w][t][1] = bfl(qv.y);
    qel[w][t][2] = bfl(qv.z);
    qel[w][t][3] = bfl(qv.w);
  } else {
    qel[w][t][0] = 0.f; qel[w][t][1] = 0.f; qel[w][t][2] = 0.f; qel[w][t][3] = 0.f;
  }
  const int start = rowptr[n], nend = nearend[n], end = rowptr[n + 1];

  float s = 0.f, a0 = 0.f, a1 = 0.f;
  float4 arb = {0.f, 0.f, 0.f, 0.f};

  // ---- near loop (radial features active), full wave per edge ----
  for (int cb = start; cb < nend; cb += 64) {
    int cnt = min(nend - cb, 64);
    int2 e_t = make_int2(0, 0);
    if (t < cnt) e_t = er[cb + t];
    for (int i = 0; i < cnt; ++i) {
      int src = __shfl(e_t.x, i);
      float dd = __shfl(__int_as_float(e_t.y), i);
      uint ku = *(const uint*)&knb[(size_t)src * DDIM + 2 * t];
      uint vu = *(const uint*)&vnb[(size_t)src * DDIM + 2 * t];
      float pr = q0 * bfl(ku) + q1 * bfh(ku);
      float rb = (t < NRAD) ? rbf_fill(dd, t) : 0.f;
      rbl[w][t] = rb;
      pr = fmaf(rbl[w][j0], qel[w][j0][h], pr);
      pr = fmaf(rbl[w][j0 + 16], qel[w][j0 + 16][h], pr);
      pr = fmaf(rbl[w][j0 + 32], qel[w][j0 + 32][h], pr);
      pr = fmaf(rbl[w][j0 + 48], qel[w][j0 + 48][h], pr);
      pr = red16(pr);
      float ae = __expf(fminf(pr * SCALE_QK, 60.f));
      s += ae;
      a0 = fmaf(ae, bfl(vu), a0);
      a1 = fmaf(ae, bfh(vu), a1);
      float aex = __shfl(ae, 0);
      float aey = __shfl(ae, 16);
      float aez = __shfl(ae, 32);
      float aew = __shfl(ae, 48);
      arb.x = fmaf(rb, aex, arb.x);
      arb.y = fmaf(rb, aey, arb.y);
      arb.z = fmaf(rb, aez, arb.z);
      arb.w = fmaf(rb, aew, arb.w);
    }
  }

  // ---- far loop: 2 edges per wave (one per 32-lane half), 4 dims/lane ----
  float sf = 0.f, af0 = 0.f, af1 = 0.f, af2 = 0.f, af3 = 0.f;
  for (int cb = nend; cb < end; cb += 64) {
    int cnt = min(end - cb, 64);
    int src_t = 0;
    if (t < cnt) src_t = er[cb + t].x;
    for (int i = hw; i < cnt; i += 2) {
      int src = __shfl(src_t, i);
      uint2 ku = *(const uint2*)&knb[(size_t)src * DDIM + 4 * c];
      uint2 vu = *(const uint2*)&vnb[(size_t)src * DDIM + 4 * c];
      float pr = fq0 * bfl(ku.x) + fq1 * bfh(ku.x);
      pr = fmaf(fq2, bfl(ku.y), pr);
      pr = fmaf(fq3, bfh(ku.y), pr);
      pr = red8(pr);
      float ae = __expf(fminf(pr * SCALE_QK, 60.f));
      sf += ae;
      af0 = fmaf(ae, bfl(vu.x), af0);
      af1 = fmaf(ae, bfh(vu.x), af1);
      af2 = fmaf(ae, bfl(vu.y), af2);
      af3 = fmaf(ae, bfh(vu.y), af3);
    }
  }
  // combine the two halves (same dims, different edge subsets)
  sf += __shfl_xor(sf, 32);
  af0 += __shfl_xor(af0, 32);
  af1 += __shfl_xor(af1, 32);
  af2 += __shfl_xor(af2, 32);
  af3 += __shfl_xor(af3, 32);
  // remap far accumulators (4 dims/lane) into near layout (2 dims/lane) via LDS
  aml[w][4 * c + 0] = af0;
  aml[w][4 * c + 1] = af1;
  aml[w][4 * c + 2] = af2;
  aml[w][4 * c + 3] = af3;
  a0 += aml[w][2 * t];
  a1 += aml[w][2 * t + 1];

  // ---- finalize: normalize; msg = a_norm + (arb_norm @ We) ----
  float4 s4;
  s4.x = __shfl(s, 0) + __shfl(sf, 0);
  s4.y = __shfl(s, 16) + __shfl(sf, 8);
  s4.z = __shfl(s, 32) + __shfl(sf, 16);
  s4.w = __shfl(s, 48) + __shfl(sf, 24);
  float4 inv4 = {1.f / (s4.x + 1e-9f), 1.f / (s4.y + 1e-9f),
                 1.f / (s4.z + 1e-9f), 1.f / (s4.w + 1e-9f)};
  float invo = (h == 0) ? inv4.x : (h == 1) ? inv4.y : (h == 2) ? inv4.z : inv4.w;
  if (t < NRAD) {
    qel[w][t][0] = arb.x * inv4.x;
    qel[w][t][1] = arb.y * inv4.y;
    qel[w][t][2] = arb.z * inv4.z;
    qel[w][t][3] = arb.w * inv4.w;
  }
  a0 *= invo;
  a1 *= invo;
#pragma unroll 10
  for (int j = 0; j < NRAD; ++j) {
    float ar = qel[w][j][h];
    uint wu = *(const uint*)&Wel[j * DDIM + 2 * t];
    a0 = fmaf(ar, bfl(wu), a0);
    a1 = fmaf(ar, bfh(wu), a1);
  }
  uint pk = (uint)f2bf(a0) | ((uint)f2bf(a1) << 16);
  *(uint*)&msgb[(size_t)n * DDIM + 2 * t] = pk;
}

// ---------------- graph sum (batch is sorted): 32 nodes/block, boundary atomics ----------------

#define GS_NODES 32
__global__ void k_graphsum(const float* __restrict__ x, const int* __restrict__ batch,
                           float* __restrict__ g) {
  int t = threadIdx.x;  // 128 dims
  int n0 = blockIdx.x * GS_NODES;
  int nend = n0 + GS_NODES;
  if (nend > NN) nend = NN;
  if (n0 >= NN) return;
  float acc = 0.f;
  int cur = batch[n0];
  for (int n = n0; n < nend; ++n) {
    int bb = batch[n];
    if (bb != cur) {
      atomicAdd(&g[(size_t)cur * DDIM + t], acc);
      acc = 0.f;
      cur = bb;
    }
    acc += x[(size_t)n * DDIM + t];
  }
  atomicAdd(&g[(size_t)cur * DDIM + t], acc);
}

// ---------------- output projection ----------------

__global__ void k_out(const float* __restrict__ g, const float* __restrict__ W,
                      const float* __restrict__ b, float* __restrict__ out) {
  int idx = blockIdx.x * blockDim.x + threadIdx.x;
  if (idx >= NGRAPH * DOUT) return;
  int r = idx / DOUT, c = idx % DOUT;
  float acc = b[c];
#pragma unroll 8
  for (int k = 0; k < DDIM; ++k) acc = fmaf(g[r * DDIM + k], W[k * DOUT + c], acc);
  out[idx] = acc;
}

// ---------------- launch ----------------

extern "C" void kernel_launch(void* const* d_in, const int* in_sizes, int n_in,
                              void* d_out, int out_size, void* d_ws, size_t ws_size,
                              hipStream_t stream) {
  const float* pos = (const float*)d_in[0];
  const int* at = (const int*)d_in[1];
  const int* ei = (const int*)d_in[2];
  const int* batch = (const int*)d_in[3];
  const float* emb = (const float*)d_in[4];
  const float* W_init = (const float*)d_in[5];
  const float* b_init = (const float*)d_in[6];
  const float* Wq = (const float*)d_in[7];
  const float* Wk = (const float*)d_in[8];
  const float* Wv = (const float*)d_in[9];
  const float* We = (const float*)d_in[10];
  const float* Wo = (const float*)d_in[11];
  const float* Wm1 = (const float*)d_in[12];
  const float* bm1 = (const float*)d_in[13];
  const float* Wm2 = (const float*)d_in[14];
  const float* bm2 = (const float*)d_in[15];
  const float* ln_g = (const float*)d_in[16];
  const float* ln_b = (const float*)d_in[17];
  const float* W_out = (const float*)d_in[18];
  const float* b_out = (const float*)d_in[19];
  float* out = (float*)d_out;

  const size_t ND = (size_t)NN * DDIM;  // 6.4M
  float* x = (float*)d_ws;              // f32 ND
  ushort* qnb = (ushort*)(x + ND);      // bf16 ND (alias hb)
  ushort* knb = qnb + ND;               // bf16 ND (alias h2)
  ushort* vnb = knb + ND;               // bf16 ND
  ushort* msgb = vnb + ND;              // bf16 ND
  ushort* qe = msgb + ND;               // bf16 NN*200
  ushort* Wtb = qe + (size_t)NN * 200;  // bf16 12*16384
  float* de = (float*)(Wtb + 12 * 16384);  // f32 NE
  int* deg = (int*)(de + NE);
  int* cnear = deg + NN;
  int* cfar = cnear + NN;
  int* rowptr = cfar + NN;
  int2* er = (int2*)(rowptr + NN + 64);  // NE int2
  float* gb = (float*)(er + NE);         // NG*DDIM
  int* bsum = (int*)(gb + NGRAPH * DDIM);  // SCAN_N
  // total ~96 MB

  ushort* hb = qnb;
  ushort* h2 = knb;

  k_wconv<<<12 * 16384 / 256, 256, 0, stream>>>(Wq, Wk, Wv, Wo, Wm1, Wm2, Wtb);
  k_fill_i<<<(NN + 255) / 256, 256, 0, stream>>>(deg, 0, NN);
  k_init<<<(NN * DDIM + 255) / 256, 256, 0, stream>>>(pos, at, emb, W_init, b_init, x);
  k_edge<<<(NE + 255) / 256, 256, 0, stream>>>(pos, ei, de, deg);
  k_scan1<<<SCAN_N, 256, 0, stream>>>(deg, bsum);
  k_scan2<<<1, 256, 0, stream>>>(bsum);
  k_scan3<<<SCAN_N, 256, 0, stream>>>(deg, bsum, rowptr, cnear, cfar);
  k_scatter<<<(NE + 255) / 256, 256, 0, stream>>>(ei, de, cnear, cfar, er);

  const int gg = (NN + 127) / 128;  // 391
  for (int l = 0; l < 2; ++l) {
    const ushort* Wt_l = Wtb + (size_t)l * 6 * 16384;
    const float* We_l = We + (size_t)l * NRAD * DDIM;

    k_qkv<<<gg, 256, 0, stream>>>(x, Wt_l, qnb, knb, vnb);
    k_qe<<<NN / 8, 256, 0, stream>>>(qnb, We_l, qe);
    k_attn6<<<NN / 4, 256, 0, stream>>>(qnb, knb, vnb, qe, er, rowptr, cnear, We_l, msgb);

    // x += msg@Wo, fused layernorm -> hb
    k_gemm2<false, false, true, true><<<gg, 256, 0, stream>>>(
        msgb, Wt_l + 3 * 16384, nullptr, x, x,
        ln_g + (size_t)l * DDIM, ln_b + (size_t)l * DDIM, hb);
    // h2 = gelu(hb@Wm1 + bm1)
    k_gemm2<true, true, false, false><<<gg, 256, 0, stream>>>(
        hb, Wt_l + 4 * 16384, bm1 + (size_t)l * DDIM, nullptr, h2, nullptr, nullptr, nullptr);
    // x += h2@Wm2 + bm2
    k_gemm2<true, false, true, false><<<gg, 256, 0, stream>>>(
        h2, Wt_l + 5 * 16384, bm2 + (size_t)l * DDIM, x, x, nullptr, nullptr, nullptr);
  }

  k_fill_f<<<(NGRAPH * DDIM + 255) / 256, 256, 0, stream>>>(gb, 0.f, NGRAPH * DDIM);
  k_graphsum<<<(NN + GS_NODES - 1) / GS_NODES, 128, 0, stream>>>(x, batch, gb);
  k_out<<<(NGRAPH * DOUT + 255) / 256, 256, 0, stream>>>(gb, W_out, b_out, out);
}

// Round 11
// 471.863 us; speedup vs baseline: 1.0507x; 1.0507x over previous
//
#include <hip/hip_runtime.h>
#include <math.h>

#define NN 50000
#define NE 400000
#define DDIM 128
#define NHEAD 4
#define NRAD 50
#define NGRAPH 100
#define TEMB 32
#define DOUT 512
#define CUTF 6.0f
#define PI_F 3.14159265358979323846f

#define SCAN_N ((NN + 255) / 256)  // 196 scan blocks

typedef unsigned int uint;
typedef unsigned short ushort;
typedef __attribute__((ext_vector_type(8))) short short8;
typedef __attribute__((ext_vector_type(4))) float f32x4;

// ---------------- helpers ----------------

__device__ __forceinline__ float gelu_tanh(float v) {
  float u = 0.7978845608028654f * (v + 0.044715f * v * v * v);
  return 0.5f * v * (1.0f + tanhf(u));
}

__device__ __forceinline__ ushort f2bf(float f) {  // RNE
  uint u = __float_as_uint(f);
  uint r = (u + 0x7fffu + ((u >> 16) & 1u)) >> 16;
  return (ushort)r;
}
__device__ __forceinline__ float bfl(uint u) { return __uint_as_float(u << 16); }
__device__ __forceinline__ float bfh(uint u) { return __uint_as_float(u & 0xffff0000u); }

// DPP sum reductions on the VALU (no ds_bpermute).
__device__ __forceinline__ float red16(float v) {
  v += __int_as_float(__builtin_amdgcn_update_dpp(0, __float_as_int(v), 0xB1, 0xF, 0xF, true));
  v += __int_as_float(__builtin_amdgcn_update_dpp(0, __float_as_int(v), 0x4E, 0xF, 0xF, true));
  v += __int_as_float(__builtin_amdgcn_update_dpp(0, __float_as_int(v), 0x141, 0xF, 0xF, true));
  v += __int_as_float(__builtin_amdgcn_update_dpp(0, __float_as_int(v), 0x140, 0xF, 0xF, true));
  return v;
}
__device__ __forceinline__ float red8(float v) {
  v += __int_as_float(__builtin_amdgcn_update_dpp(0, __float_as_int(v), 0xB1, 0xF, 0xF, true));
  v += __int_as_float(__builtin_amdgcn_update_dpp(0, __float_as_int(v), 0x4E, 0xF, 0xF, true));
  v += __int_as_float(__builtin_amdgcn_update_dpp(0, __float_as_int(v), 0x141, 0xF, 0xF, true));
  return v;
}

__global__ void k_fill_f(float* p, float v, int n) {
  int i = blockIdx.x * blockDim.x + threadIdx.x;
  if (i < n) p[i] = v;
}
__global__ void k_fill_i(int* p, int v, int n) {
  int i = blockIdx.x * blockDim.x + threadIdx.x;
  if (i < n) p[i] = v;
}

// ---------------- weight pre-convert + transpose: Wtb[l][fam][c][k] bf16 ----------------

__global__ void k_wconv(const float* __restrict__ Wq, const float* __restrict__ Wk,
                        const float* __restrict__ Wv, const float* __restrict__ Wo,
                        const float* __restrict__ Wm1, const float* __restrict__ Wm2,
                        ushort* __restrict__ Wtb) {
  int idx = blockIdx.x * 256 + threadIdx.x;  // 12*16384
  int m = idx >> 14;
  int r = idx & 16383;
  int c = r >> 7, k = r & 127;
  int l = m / 6, fam = m % 6;
  const float* src = fam == 0 ? Wq : fam == 1 ? Wk : fam == 2 ? Wv
                   : fam == 3 ? Wo : fam == 4 ? Wm1 : Wm2;
  Wtb[idx] = f2bf(src[l * 16384 + k * 128 + c]);
}

// ---------------- WeWo precompute: WW[l][c][k256], k256=4j+h ----------------
// WW[l][c][4j+h] = sum_{dk<32} We[l][j][32h+dk] * Wo[l][32h+dk][c]; zero for k>=200.

__global__ void k_wewo(const float* __restrict__ We, const float* __restrict__ Wo,
                       ushort* __restrict__ WW) {
  int idx = blockIdx.x * 256 + threadIdx.x;  // 2*128*256
  int l = idx >> 15;
  int r = idx & 32767;
  int c = r >> 8, k = r & 255;
  float acc = 0.f;
  if (k < 200) {
    int j = k >> 2, h = k & 3;
    const float* we = We + (size_t)l * NRAD * DDIM + j * DDIM + 32 * h;
    const float* wo = Wo + (size_t)l * DDIM * DDIM + (size_t)(32 * h) * DDIM + c;
#pragma unroll 8
    for (int dk = 0; dk < 32; ++dk) acc = fmaf(we[dk], wo[(size_t)dk * DDIM], acc);
  }
  WW[idx] = f2bf(acc);
}

// ---------------- init: x = [emb[at], pos] @ W_init + b ----------------

__global__ void k_init(const float* __restrict__ pos, const int* __restrict__ at,
                       const float* __restrict__ emb, const float* __restrict__ W,
                       const float* __restrict__ b, float* __restrict__ x) {
  int idx = blockIdx.x * blockDim.x + threadIdx.x;
  if (idx >= NN * DDIM) return;
  int n = idx >> 7, c = idx & 127;
  const float* er = emb + (size_t)at[n] * TEMB;
  float acc = b[c];
#pragma unroll
  for (int t = 0; t < TEMB; ++t) acc = fmaf(er[t], W[t * DDIM + c], acc);
  acc = fmaf(pos[n * 3 + 0], W[(TEMB + 0) * DDIM + c], acc);
  acc = fmaf(pos[n * 3 + 1], W[(TEMB + 1) * DDIM + c], acc);
  acc = fmaf(pos[n * 3 + 2], W[(TEMB + 2) * DDIM + c], acc);
  x[idx] = acc;
}

// ---------------- per-edge distance + degree histogram (fused) ----------------

__global__ void k_edge(const float* __restrict__ pos, const int* __restrict__ ei,
                       float* __restrict__ de, int* __restrict__ deg) {
  int e = blockIdx.x * blockDim.x + threadIdx.x;
  if (e >= NE) return;
  int s = ei[e], t = ei[NE + e];
  float dx = pos[s * 3 + 0] - pos[t * 3 + 0] + 1e-8f;
  float dy = pos[s * 3 + 1] - pos[t * 3 + 1] + 1e-8f;
  float dz = pos[s * 3 + 2] - pos[t * 3 + 2] + 1e-8f;
  de[e] = sqrtf(dx * dx + dy * dy + dz * dz);
  atomicAdd(&deg[t], 1);
}

// ---------------- CSR build: parallel 3-pass exclusive scan ----------------

__global__ void k_scan1(const int* __restrict__ deg, int* __restrict__ bsum) {
  __shared__ int red[256];
  int i = blockIdx.x * 256 + threadIdx.x;
  red[threadIdx.x] = (i < NN) ? deg[i] : 0;
  __syncthreads();
  for (int off = 128; off > 0; off >>= 1) {
    if (threadIdx.x < off) red[threadIdx.x] += red[threadIdx.x + off];
    __syncthreads();
  }
  if (threadIdx.x == 0) bsum[blockIdx.x] = red[0];
}

__global__ void k_scan2(int* __restrict__ bsum) {  // 1 block, 256 threads >= SCAN_N
  __shared__ int sh[256];
  int t = threadIdx.x;
  int v = (t < SCAN_N) ? bsum[t] : 0;
  sh[t] = v;
  __syncthreads();
  for (int off = 1; off < 256; off <<= 1) {
    int u = (t >= off) ? sh[t - off] : 0;
    __syncthreads();
    sh[t] += u;
    __syncthreads();
  }
  if (t < SCAN_N) bsum[t] = (t == 0) ? 0 : sh[t - 1];
}

__global__ void k_scan3(const int* __restrict__ deg, const int* __restrict__ bsum,
                        int* __restrict__ rowptr, int* __restrict__ cnear,
                        int* __restrict__ cfar) {
  __shared__ int sh[256];
  int t = threadIdx.x;
  int i = blockIdx.x * 256 + t;
  int v = (i < NN) ? deg[i] : 0;
  sh[t] = v;
  __syncthreads();
  for (int off = 1; off < 256; off <<= 1) {
    int u = (t >= off) ? sh[t - off] : 0;
    __syncthreads();
    sh[t] += u;
    __syncthreads();
  }
  int excl = bsum[blockIdx.x] + sh[t] - v;
  if (i < NN) {
    rowptr[i] = excl;
    cnear[i] = excl;
    cfar[i] = excl + v;  // = rowptr[i+1]
    if (i == NN - 1) rowptr[NN] = excl + v;
  }
}

// scatter into near-first / far-last segmented CSR, packed records {src, d}
__global__ void k_scatter(const int* __restrict__ ei, const float* __restrict__ de,
                          int* __restrict__ cnear, int* __restrict__ cfar,
                          int2* __restrict__ er) {
  int e = blockIdx.x * blockDim.x + threadIdx.x;
  if (e >= NE) return;
  int src = ei[e], dst = ei[NE + e];
  float d = de[e];
  int idx;
  if (d < CUTF)
    idx = atomicAdd(&cnear[dst], 1);
  else
    idx = atomicSub(&cfar[dst], 1) - 1;
  er[idx] = make_int2(src, __float_as_int(d));
}

// ---------------- fused QKV GEMM: stage x once, 3 weights ----------------

__global__ __launch_bounds__(256) void k_qkv(
    const float* __restrict__ x, const ushort* __restrict__ Wt3,
    ushort* __restrict__ qo, ushort* __restrict__ ko, ushort* __restrict__ vo) {
  __shared__ ushort Al[128 * 128];
  __shared__ ushort Wl[128 * 128];
  const int tid = threadIdx.x;
  const int r0 = blockIdx.x * 128;

  for (int i = tid; i < 128 * 16; i += 256) {
    int r = i >> 4, g = i & 15;
    int gr = r0 + r;
    float4 f0 = {0, 0, 0, 0}, f1 = {0, 0, 0, 0};
    if (gr < NN) {
      f0 = *(const float4*)&x[(size_t)gr * 128 + g * 8];
      f1 = *(const float4*)&x[(size_t)gr * 128 + g * 8 + 4];
    }
    int gs = g ^ (r & 7);
    ushort4 u0 = {f2bf(f0.x), f2bf(f0.y), f2bf(f0.z), f2bf(f0.w)};
    ushort4 u1 = {f2bf(f1.x), f2bf(f1.y), f2bf(f1.z), f2bf(f1.w)};
    *(ushort4*)&Al[r * 128 + gs * 8] = u0;
    *(ushort4*)&Al[r * 128 + gs * 8 + 4] = u1;
  }

  const int w = tid >> 6, l = tid & 63;
  const int lg = l >> 4, lr = l & 15;

  for (int m = 0; m < 3; ++m) {
    for (int i = tid; i < 128 * 16; i += 256) {
      int c = i >> 4, g = i & 15;
      ushort4 w0 = *(const ushort4*)&Wt3[m * 16384 + c * 128 + g * 8];
      ushort4 w1 = *(const ushort4*)&Wt3[m * 16384 + c * 128 + g * 8 + 4];
      int gs = g ^ (c & 7);
      *(ushort4*)&Wl[c * 128 + gs * 8] = w0;
      *(ushort4*)&Wl[c * 128 + gs * 8 + 4] = w1;
    }
    __syncthreads();

    f32x4 acc[2][8];
#pragma unroll
    for (int rt = 0; rt < 2; ++rt)
#pragma unroll
      for (int ct = 0; ct < 8; ++ct) acc[rt][ct] = (f32x4){0.f, 0.f, 0.f, 0.f};

#pragma unroll
    for (int ks = 0; ks < 4; ++ks) {
      short8 af[2];
#pragma unroll
      for (int rt = 0; rt < 2; ++rt) {
        int arow = w * 32 + rt * 16 + lr;
        int ga = (ks * 4 + lg) ^ (arow & 7);
        af[rt] = *(const short8*)&Al[arow * 128 + ga * 8];
      }
#pragma unroll
      for (int ct = 0; ct < 8; ++ct) {
        int col = ct * 16 + lr;
        int gb = (ks * 4 + lg) ^ (col & 7);
        short8 bf = *(const short8*)&Wl[col * 128 + gb * 8];
#pragma unroll
        for (int rt = 0; rt < 2; ++rt)
          acc[rt][ct] = __builtin_amdgcn_mfma_f32_16x16x32_bf16(af[rt], bf, acc[rt][ct], 0, 0, 0);
      }
    }

    ushort* o = (m == 0) ? qo : (m == 1) ? ko : vo;
#pragma unroll
    for (int rt = 0; rt < 2; ++rt)
#pragma unroll
      for (int ct = 0; ct < 8; ++ct) {
        int col = ct * 16 + lr;
#pragma unroll
        for (int r = 0; r < 4; ++r) {
          int row = r0 + w * 32 + rt * 16 + lg * 4 + r;
          if (row < NN) o[(size_t)row * 128 + col] = f2bf(acc[rt][ct][r]);
        }
      }
    __syncthreads();
  }
}

// ---------------- general GEMM: out = act(A@W + bias) (+resid) (+fused LN)
// EXTK: additionally accumulate arbn[NN,200] @ WW[256,128] (2 chunked passes).

template <bool BIAS, bool GELU, bool RESID, bool LNF, bool EXTK>
__global__ __launch_bounds__(256) void k_gemm2(
    const ushort* __restrict__ A, const ushort* __restrict__ Wt,
    const float* __restrict__ bias, const float* __restrict__ resid,
    void* __restrict__ outp, const float* __restrict__ lng,
    const float* __restrict__ lnb, ushort* __restrict__ lnout,
    const ushort* __restrict__ arbn, const ushort* __restrict__ WW) {
  __shared__ ushort Al[128 * 128];
  __shared__ ushort Wl[128 * 128];
  const int tid = threadIdx.x;
  const int r0 = blockIdx.x * 128;

  for (int i = tid; i < 128 * 16; i += 256) {
    int r = i >> 4, g = i & 15;
    int gr = r0 + r;
    ushort4 v0 = {0, 0, 0, 0}, v1 = {0, 0, 0, 0};
    if (gr < NN) {
      v0 = *(const ushort4*)&A[(size_t)gr * 128 + g * 8];
      v1 = *(const ushort4*)&A[(size_t)gr * 128 + g * 8 + 4];
    }
    int gs = g ^ (r & 7);
    *(ushort4*)&Al[r * 128 + gs * 8] = v0;
    *(ushort4*)&Al[r * 128 + gs * 8 + 4] = v1;
  }
  for (int i = tid; i < 128 * 16; i += 256) {
    int c = i >> 4, g = i & 15;
    ushort4 w0 = *(const ushort4*)&Wt[c * 128 + g * 8];
    ushort4 w1 = *(const ushort4*)&Wt[c * 128 + g * 8 + 4];
    int gs = g ^ (c & 7);
    *(ushort4*)&Wl[c * 128 + gs * 8] = w0;
    *(ushort4*)&Wl[c * 128 + gs * 8 + 4] = w1;
  }
  __syncthreads();

  const int w = tid >> 6, l = tid & 63;
  const int lg = l >> 4, lr = l & 15;
  f32x4 acc[2][8];
#pragma unroll
  for (int rt = 0; rt < 2; ++rt)
#pragma unroll
    for (int ct = 0; ct < 8; ++ct) acc[rt][ct] = (f32x4){0.f, 0.f, 0.f, 0.f};

#pragma unroll
  for (int ks = 0; ks < 4; ++ks) {
    short8 af[2];
#pragma unroll
    for (int rt = 0; rt < 2; ++rt) {
      int arow = w * 32 + rt * 16 + lr;
      int ga = (ks * 4 + lg) ^ (arow & 7);
      af[rt] = *(const short8*)&Al[arow * 128 + ga * 8];
    }
#pragma unroll
    for (int ct = 0; ct < 8; ++ct) {
      int col = ct * 16 + lr;
      int gb = (ks * 4 + lg) ^ (col & 7);
      short8 bf = *(const short8*)&Wl[col * 128 + gb * 8];
#pragma unroll
      for (int rt = 0; rt < 2; ++rt)
        acc[rt][ct] = __builtin_amdgcn_mfma_f32_16x16x32_bf16(af[rt], bf, acc[rt][ct], 0, 0, 0);
    }
  }

  if (EXTK) {
    for (int q = 0; q < 2; ++q) {
      __syncthreads();  // prior mfma reads done
      for (int i = tid; i < 128 * 16; i += 256) {
        int r = i >> 4, g = i & 15;
        int gr = r0 + r;
        ushort4 v0 = {0, 0, 0, 0}, v1 = {0, 0, 0, 0};
        if (gr < NN && (q == 0 || g < 9)) {
          v0 = *(const ushort4*)&arbn[(size_t)gr * 200 + q * 128 + g * 8];
          v1 = *(const ushort4*)&arbn[(size_t)gr * 200 + q * 128 + g * 8 + 4];
        }
        int gs = g ^ (r & 7);
        *(ushort4*)&Al[r * 128 + gs * 8] = v0;
        *(ushort4*)&Al[r * 128 + gs * 8 + 4] = v1;
      }
      for (int i = tid; i < 128 * 16; i += 256) {
        int c = i >> 4, g = i & 15;
        ushort4 w0 = *(const ushort4*)&WW[c * 256 + q * 128 + g * 8];
        ushort4 w1 = *(const ushort4*)&WW[c * 256 + q * 128 + g * 8 + 4];
        int gs = g ^ (c & 7);
        *(ushort4*)&Wl[c * 128 + gs * 8] = w0;
        *(ushort4*)&Wl[c * 128 + gs * 8 + 4] = w1;
      }
      __syncthreads();
#pragma unroll
      for (int ks = 0; ks < 4; ++ks) {
        short8 af[2];
#pragma unroll
        for (int rt = 0; rt < 2; ++rt) {
          int arow = w * 32 + rt * 16 + lr;
          int ga = (ks * 4 + lg) ^ (arow & 7);
          af[rt] = *(const short8*)&Al[arow * 128 + ga * 8];
        }
#pragma unroll
        for (int ct = 0; ct < 8; ++ct) {
          int col = ct * 16 + lr;
          int gb = (ks * 4 + lg) ^ (col & 7);
          short8 bf = *(const short8*)&Wl[col * 128 + gb * 8];
#pragma unroll
          for (int rt = 0; rt < 2; ++rt)
            acc[rt][ct] = __builtin_amdgcn_mfma_f32_16x16x32_bf16(af[rt], bf, acc[rt][ct], 0, 0, 0);
        }
      }
    }
  }

#pragma unroll
  for (int rt = 0; rt < 2; ++rt)
#pragma unroll
    for (int r = 0; r < 4; ++r) {
      int row = r0 + w * 32 + rt * 16 + lg * 4 + r;
      bool ok = row < NN;  // uniform across the 16-lane lr group
      float v[8];
#pragma unroll
      for (int ct = 0; ct < 8; ++ct) {
        int col = ct * 16 + lr;
        float vv = acc[rt][ct][r];
        if (BIAS) vv += bias[col];
        if (GELU) vv = gelu_tanh(vv);
        if (RESID) vv += ok ? resid[(size_t)row * 128 + col] : 0.f;
        v[ct] = vv;
      }
      if (RESID || LNF) {
        if (ok)
#pragma unroll
          for (int ct = 0; ct < 8; ++ct)
            ((float*)outp)[(size_t)row * 128 + ct * 16 + lr] = v[ct];
      } else {
        if (ok)
#pragma unroll
          for (int ct = 0; ct < 8; ++ct)
            ((ushort*)outp)[(size_t)row * 128 + ct * 16 + lr] = f2bf(v[ct]);
      }
      if (LNF) {
        float s = 0.f, ss = 0.f;
#pragma unroll
        for (int ct = 0; ct < 8; ++ct) {
          s += v[ct];
          ss = fmaf(v[ct], v[ct], ss);
        }
#pragma unroll
        for (int msk = 8; msk >= 1; msk >>= 1) {
          s += __shfl_xor(s, msk);
          ss += __shfl_xor(ss, msk);
        }
        float mean = s * (1.0f / DDIM);
        float var = ss * (1.0f / DDIM) - mean * mean;
        float inv = rsqrtf(var + 1e-5f);
        if (ok)
#pragma unroll
          for (int ct = 0; ct < 8; ++ct) {
            int col = ct * 16 + lr;
            lnout[(size_t)row * 128 + col] =
                f2bf((v[ct] - mean) * inv * lng[col] + lnb[col]);
          }
      }
    }
}

// ---------------- qe precompute: qe[n][4j+h] ----------------

__global__ __launch_bounds__(256) void k_qe(const ushort* __restrict__ qnb,
                                            const float* __restrict__ We,
                                            ushort* __restrict__ qe) {
  __shared__ float Wlds[NRAD][DDIM + 1];
  __shared__ float qlds[4][DDIM];
  int tid = threadIdx.x;
  for (int i = tid; i < NRAD * DDIM; i += 256) Wlds[i / DDIM][i % DDIM] = We[i];
  __syncthreads();
  int w = tid >> 6, t = tid & 63;
  for (int rep = 0; rep < 2; ++rep) {
    int n = blockIdx.x * 8 + rep * 4 + w;
    uint qu = *(const uint*)&qnb[(size_t)n * DDIM + 2 * t];
    qlds[w][2 * t] = bfl(qu);
    qlds[w][2 * t + 1] = bfh(qu);
    if (t < NRAD) {
      float e0 = 0.f, e1 = 0.f, e2 = 0.f, e3 = 0.f;
#pragma unroll
      for (int d = 0; d < 32; ++d) e0 = fmaf(Wlds[t][d], qlds[w][d], e0);
#pragma unroll
      for (int d = 32; d < 64; ++d) e1 = fmaf(Wlds[t][d], qlds[w][d], e1);
#pragma unroll
      for (int d = 64; d < 96; ++d) e2 = fmaf(Wlds[t][d], qlds[w][d], e2);
#pragma unroll
      for (int d = 96; d < 128; ++d) e3 = fmaf(Wlds[t][d], qlds[w][d], e3);
      ushort4 o = {f2bf(e0), f2bf(e1), f2bf(e2), f2bf(e3)};
      *(ushort4*)&qe[(size_t)n * 200 + 4 * t] = o;
    }
  }
}

// ---------------- fused attention v7: writes a_norm (msgb) + normalized arbn ----------------
// arbn ALIASES the qe buffer: qe[n] is read in the prologue, arbn[n] written in the
// epilogue by the same wave -> no hazard. The radial matvec moved into the Wo GEMM.

__device__ __forceinline__ float rbf_fill(float d, int j) {
  const float step = CUTF / (NRAD - 1);
  const float gamma = (NRAD / CUTF) * (NRAD / CUTF);
  float mu = j * step;
  float dm = d - mu;
  float env = 0.5f * (__cosf(PI_F * d / CUTF) + 1.0f);
  return __expf(-gamma * dm * dm) * env;
}

#define SCALE_QK 0.17677669529663687f

__global__ __launch_bounds__(256) void k_attn7(
    const ushort* __restrict__ qnb, const ushort* __restrict__ knb,
    const ushort* __restrict__ vnb, ushort* __restrict__ qe,
    const int2* __restrict__ er, const int* __restrict__ rowptr,
    const int* __restrict__ nearend, ushort* __restrict__ msgb) {
  __shared__ float qel[4][64][4];   // [wave][j][head]
  __shared__ float rbl[4][64];
  __shared__ float aml[4][128];     // far-accumulator remap buffer (per wave)
  const int tid = threadIdx.x;

  const int w = tid >> 6, t = tid & 63;
  const int n = blockIdx.x * 4 + w;
  const int h = t >> 4;       // near-layout head (16-lane groups)
  const int j0 = t & 15;
  const int hw = t >> 5;      // half-wave id (far loop)
  const int c = t & 31;       // lane in half; owns dims 4c..4c+3 (far loop)
  uint qu = *(const uint*)&qnb[(size_t)n * DDIM + 2 * t];
  const float q0 = bfl(qu), q1 = bfh(qu);
  uint2 qp = *(const uint2*)&qnb[(size_t)n * DDIM + 4 * c];
  const float fq0 = bfl(qp.x), fq1 = bfh(qp.x), fq2 = bfl(qp.y), fq3 = bfh(qp.y);
  if (t < NRAD) {
    ushort4 qv = *(const ushort4*)&qe[(size_t)n * 200 + 4 * t];
    qel[w][t][0] = bfl(qv.x);
    qel[w][t][1] = bfl(qv.y);
    qel[w][t][2] = bfl(qv.z);
    qel[w][t][3] = bfl(qv.w);
  } else {
    qel[w][t][0] = 0.f; qel[w][t][1] = 0.f; qel[w][t][2] = 0.f; qel[w][t][3] = 0.f;
  }
  const int start = rowptr[n], nend = nearend[n], end = rowptr[n + 1];

  float s = 0.f, a0 = 0.f, a1 = 0.f;
  float4 arb = {0.f, 0.f, 0.f, 0.f};

  // ---- near loop (radial features active), full wave per edge ----
  for (int cb = start; cb < nend; cb += 64) {
    int cnt = min(nend - cb, 64);
    int2 e_t = make_int2(0, 0);
    if (t < cnt) e_t = er[cb + t];
    for (int i = 0; i < cnt; ++i) {
      int src = __shfl(e_t.x, i);
      float dd = __shfl(__int_as_float(e_t.y), i);
      uint ku = *(const uint*)&knb[(size_t)src * DDIM + 2 * t];
      uint vu = *(const uint*)&vnb[(size_t)src * DDIM + 2 * t];
      float pr = q0 * bfl(ku) + q1 * bfh(ku);
      float rb = (t < NRAD) ? rbf_fill(dd, t) : 0.f;
      rbl[w][t] = rb;
      pr = fmaf(rbl[w][j0], qel[w][j0][h], pr);
      pr = fmaf(rbl[w][j0 + 16], qel[w][j0 + 16][h], pr);
      pr = fmaf(rbl[w][j0 + 32], qel[w][j0 + 32][h], pr);
      pr = fmaf(rbl[w][j0 + 48], qel[w][j0 + 48][h], pr);
      pr = red16(pr);
      float ae = __expf(fminf(pr * SCALE_QK, 60.f));
      s += ae;
      a0 = fmaf(ae, bfl(vu), a0);
      a1 = fmaf(ae, bfh(vu), a1);
      float aex = __shfl(ae, 0);
      float aey = __shfl(ae, 16);
      float aez = __shfl(ae, 32);
      float aew = __shfl(ae, 48);
      arb.x = fmaf(rb, aex, arb.x);
      arb.y = fmaf(rb, aey, arb.y);
      arb.z = fmaf(rb, aez, arb.z);
      arb.w = fmaf(rb, aew, arb.w);
    }
  }

  // ---- far loop: 2 edges per wave (one per 32-lane half), 4 dims/lane ----
  float sf = 0.f, af0 = 0.f, af1 = 0.f, af2 = 0.f, af3 = 0.f;
  for (int cb = nend; cb < end; cb += 64) {
    int cnt = min(end - cb, 64);
    int src_t = 0;
    if (t < cnt) src_t = er[cb + t].x;
    for (int i = hw; i < cnt; i += 2) {
      int src = __shfl(src_t, i);
      uint2 ku = *(const uint2*)&knb[(size_t)src * DDIM + 4 * c];
      uint2 vu = *(const uint2*)&vnb[(size_t)src * DDIM + 4 * c];
      float pr = fq0 * bfl(ku.x) + fq1 * bfh(ku.x);
      pr = fmaf(fq2, bfl(ku.y), pr);
      pr = fmaf(fq3, bfh(ku.y), pr);
      pr = red8(pr);
      float ae = __expf(fminf(pr * SCALE_QK, 60.f));
      sf += ae;
      af0 = fmaf(ae, bfl(vu.x), af0);
      af1 = fmaf(ae, bfh(vu.x), af1);
      af2 = fmaf(ae, bfl(vu.y), af2);
      af3 = fmaf(ae, bfh(vu.y), af3);
    }
  }
  // combine the two halves (same dims, different edge subsets)
  sf += __shfl_xor(sf, 32);
  af0 += __shfl_xor(af0, 32);
  af1 += __shfl_xor(af1, 32);
  af2 += __shfl_xor(af2, 32);
  af3 += __shfl_xor(af3, 32);
  // remap far accumulators (4 dims/lane) into near layout (2 dims/lane) via LDS
  aml[w][4 * c + 0] = af0;
  aml[w][4 * c + 1] = af1;
  aml[w][4 * c + 2] = af2;
  aml[w][4 * c + 3] = af3;
  a0 += aml[w][2 * t];
  a1 += aml[w][2 * t + 1];

  // ---- finalize: normalize; store a_norm (msgb) and arbn (into qe buffer) ----
  float4 s4;
  s4.x = __shfl(s, 0) + __shfl(sf, 0);
  s4.y = __shfl(s, 16) + __shfl(sf, 8);
  s4.z = __shfl(s, 32) + __shfl(sf, 16);
  s4.w = __shfl(s, 48) + __shfl(sf, 24);
  float4 inv4 = {1.f / (s4.x + 1e-9f), 1.f / (s4.y + 1e-9f),
                 1.f / (s4.z + 1e-9f), 1.f / (s4.w + 1e-9f)};
  float invo = (h == 0) ? inv4.x : (h == 1) ? inv4.y : (h == 2) ? inv4.z : inv4.w;
  if (t < NRAD) {
    ushort4 o = {f2bf(arb.x * inv4.x), f2bf(arb.y * inv4.y),
                 f2bf(arb.z * inv4.z), f2bf(arb.w * inv4.w)};
    *(ushort4*)&qe[(size_t)n * 200 + 4 * t] = o;
  }
  a0 *= invo;
  a1 *= invo;
  uint pk = (uint)f2bf(a0) | ((uint)f2bf(a1) << 16);
  *(uint*)&msgb[(size_t)n * DDIM + 2 * t] = pk;
}

// ---------------- graph sum (batch is sorted): 32 nodes/block, boundary atomics ----------------

#define GS_NODES 32
__global__ void k_graphsum(const float* __restrict__ x, const int* __restrict__ batch,
                           float* __restrict__ g) {
  int t = threadIdx.x;  // 128 dims
  int n0 = blockIdx.x * GS_NODES;
  int nend = n0 + GS_NODES;
  if (nend > NN) nend = NN;
  if (n0 >= NN) return;
  float acc = 0.f;
  int cur = batch[n0];
  for (int n = n0; n < nend; ++n) {
    int bb = batch[n];
    if (bb != cur) {
      atomicAdd(&g[(size_t)cur * DDIM + t], acc);
      acc = 0.f;
      cur = bb;
    }
    acc += x[(size_t)n * DDIM + t];
  }
  atomicAdd(&g[(size_t)cur * DDIM + t], acc);
}

// ---------------- output projection ----------------

__global__ void k_out(const float* __restrict__ g, const float* __restrict__ W,
                      const float* __restrict__ b, float* __restrict__ out) {
  int idx = blockIdx.x * blockDim.x + threadIdx.x;
  if (idx >= NGRAPH * DOUT) return;
  int r = idx / DOUT, c = idx % DOUT;
  float acc = b[c];
#pragma unroll 8
  for (int k = 0; k < DDIM; ++k) acc = fmaf(g[r * DDIM + k], W[k * DOUT + c], acc);
  out[idx] = acc;
}

// ---------------- launch ----------------

extern "C" void kernel_launch(void* const* d_in, const int* in_sizes, int n_in,
                              void* d_out, int out_size, void* d_ws, size_t ws_size,
                              hipStream_t stream) {
  const float* pos = (const float*)d_in[0];
  const int* at = (const int*)d_in[1];
  const int* ei = (const int*)d_in[2];
  const int* batch = (const int*)d_in[3];
  const float* emb = (const float*)d_in[4];
  const float* W_init = (const float*)d_in[5];
  const float* b_init = (const float*)d_in[6];
  const float* Wq = (const float*)d_in[7];
  const float* Wk = (const float*)d_in[8];
  const float* Wv = (const float*)d_in[9];
  const float* We = (const float*)d_in[10];
  const float* Wo = (const float*)d_in[11];
  const float* Wm1 = (const float*)d_in[12];
  const float* bm1 = (const float*)d_in[13];
  const float* Wm2 = (const float*)d_in[14];
  const float* bm2 = (const float*)d_in[15];
  const float* ln_g = (const float*)d_in[16];
  const float* ln_b = (const float*)d_in[17];
  const float* W_out = (const float*)d_in[18];
  const float* b_out = (const float*)d_in[19];
  float* out = (float*)d_out;

  const size_t ND = (size_t)NN * DDIM;  // 6.4M
  float* x = (float*)d_ws;              // f32 ND
  ushort* qnb = (ushort*)(x + ND);      // bf16 ND (alias hb)
  ushort* knb = qnb + ND;               // bf16 ND (alias h2)
  ushort* vnb = knb + ND;               // bf16 ND
  ushort* msgb = vnb + ND;              // bf16 ND
  ushort* qe = msgb + ND;               // bf16 NN*200 (doubles as arbn)
  ushort* Wtb = qe + (size_t)NN * 200;  // bf16 12*16384
  ushort* WW = Wtb + 12 * 16384;        // bf16 2*128*256 (WeWo)
  float* de = (float*)(WW + 2 * 32768); // f32 NE
  int* deg = (int*)(de + NE);
  int* cnear = deg + NN;
  int* cfar = cnear + NN;
  int* rowptr = cfar + NN;
  int2* er = (int2*)(rowptr + NN + 64);  // NE int2
  float* gb = (float*)(er + NE);         // NG*DDIM
  int* bsum = (int*)(gb + NGRAPH * DDIM);  // SCAN_N
  // total ~96.5 MB

  ushort* hb = qnb;
  ushort* h2 = knb;

  k_wconv<<<12 * 16384 / 256, 256, 0, stream>>>(Wq, Wk, Wv, Wo, Wm1, Wm2, Wtb);
  k_wewo<<<2 * 32768 / 256, 256, 0, stream>>>(We, Wo, WW);
  k_fill_i<<<(NN + 255) / 256, 256, 0, stream>>>(deg, 0, NN);
  k_init<<<(NN * DDIM + 255) / 256, 256, 0, stream>>>(pos, at, emb, W_init, b_init, x);
  k_edge<<<(NE + 255) / 256, 256, 0, stream>>>(pos, ei, de, deg);
  k_scan1<<<SCAN_N, 256, 0, stream>>>(deg, bsum);
  k_scan2<<<1, 256, 0, stream>>>(bsum);
  k_scan3<<<SCAN_N, 256, 0, stream>>>(deg, bsum, rowptr, cnear, cfar);
  k_scatter<<<(NE + 255) / 256, 256, 0, stream>>>(ei, de, cnear, cfar, er);

  const int gg = (NN + 127) / 128;  // 391
  for (int l = 0; l < 2; ++l) {
    const ushort* Wt_l = Wtb + (size_t)l * 6 * 16384;
    const float* We_l = We + (size_t)l * NRAD * DDIM;
    const ushort* WW_l = WW + (size_t)l * 32768;

    k_qkv<<<gg, 256, 0, stream>>>(x, Wt_l, qnb, knb, vnb);
    k_qe<<<NN / 8, 256, 0, stream>>>(qnb, We_l, qe);
    k_attn7<<<NN / 4, 256, 0, stream>>>(qnb, knb, vnb, qe, er, rowptr, cnear, msgb);

    // x += msg@Wo + arbn@WeWo, fused layernorm -> hb
    k_gemm2<false, false, true, true, true><<<gg, 256, 0, stream>>>(
        msgb, Wt_l + 3 * 16384, nullptr, x, x,
        ln_g + (size_t)l * DDIM, ln_b + (size_t)l * DDIM, hb, qe, WW_l);
    // h2 = gelu(hb@Wm1 + bm1)
    k_gemm2<true, true, false, false, false><<<gg, 256, 0, stream>>>(
        hb, Wt_l + 4 * 16384, bm1 + (size_t)l * DDIM, nullptr, h2,
        nullptr, nullptr, nullptr, nullptr, nullptr);
    // x += h2@Wm2 + bm2
    k_gemm2<true, false, true, false, false><<<gg, 256, 0, stream>>>(
        h2, Wt_l + 5 * 16384, bm2 + (size_t)l * DDIM, x, x,
        nullptr, nullptr, nullptr, nullptr, nullptr);
  }

  k_fill_f<<<(NGRAPH * DDIM + 255) / 256, 256, 0, stream>>>(gb, 0.f, NGRAPH * DDIM);
  k_graphsum<<<(NN + GS_NODES - 1) / GS_NODES, 128, 0, stream>>>(x, batch, gb);
  k_out<<<(NGRAPH * DOUT + 255) / 256, 256, 0, stream>>>(gb, W_out, b_out, out);
}

// Round 12
// 431.223 us; speedup vs baseline: 1.1497x; 1.0942x over previous
//
#include <hip/hip_runtime.h>
#include <math.h>

#define NN 50000
#define NE 400000
#define DDIM 128
#define NHEAD 4
#define NRAD 50
#define NGRAPH 100
#define NTYPE 100
#define TEMB 32
#define DOUT 512
#define CUTF 6.0f
#define PI_F 3.14159265358979323846f

#define SCAN_N ((NN + 255) / 256)  // 196 scan blocks

typedef unsigned int uint;
typedef unsigned short ushort;
typedef __attribute__((ext_vector_type(8))) short short8;
typedef __attribute__((ext_vector_type(4))) float f32x4;

// ---------------- helpers ----------------

__device__ __forceinline__ float gelu_tanh(float v) {
  float u = 0.7978845608028654f * (v + 0.044715f * v * v * v);
  return 0.5f * v * (1.0f + tanhf(u));
}

__device__ __forceinline__ ushort f2bf(float f) {  // RNE
  uint u = __float_as_uint(f);
  uint r = (u + 0x7fffu + ((u >> 16) & 1u)) >> 16;
  return (ushort)r;
}
__device__ __forceinline__ float bfl(uint u) { return __uint_as_float(u << 16); }
__device__ __forceinline__ float bfh(uint u) { return __uint_as_float(u & 0xffff0000u); }

// DPP sum reductions on the VALU (no ds_bpermute).
__device__ __forceinline__ float red16(float v) {
  v += __int_as_float(__builtin_amdgcn_update_dpp(0, __float_as_int(v), 0xB1, 0xF, 0xF, true));
  v += __int_as_float(__builtin_amdgcn_update_dpp(0, __float_as_int(v), 0x4E, 0xF, 0xF, true));
  v += __int_as_float(__builtin_amdgcn_update_dpp(0, __float_as_int(v), 0x141, 0xF, 0xF, true));
  v += __int_as_float(__builtin_amdgcn_update_dpp(0, __float_as_int(v), 0x140, 0xF, 0xF, true));
  return v;
}
__device__ __forceinline__ float red8(float v) {
  v += __int_as_float(__builtin_amdgcn_update_dpp(0, __float_as_int(v), 0xB1, 0xF, 0xF, true));
  v += __int_as_float(__builtin_amdgcn_update_dpp(0, __float_as_int(v), 0x4E, 0xF, 0xF, true));
  v += __int_as_float(__builtin_amdgcn_update_dpp(0, __float_as_int(v), 0x141, 0xF, 0xF, true));
  return v;
}

__global__ void k_fill_f(float* p, float v, int n) {
  int i = blockIdx.x * blockDim.x + threadIdx.x;
  if (i < n) p[i] = v;
}
__global__ void k_fill_i(int* p, int v, int n) {
  int i = blockIdx.x * blockDim.x + threadIdx.x;
  if (i < n) p[i] = v;
}

// ---------------- weight pre-convert + transpose: Wtb[l][fam][c][k] bf16 ----------------

__global__ void k_wconv(const float* __restrict__ Wq, const float* __restrict__ Wk,
                        const float* __restrict__ Wv, const float* __restrict__ Wo,
                        const float* __restrict__ Wm1, const float* __restrict__ Wm2,
                        ushort* __restrict__ Wtb) {
  int idx = blockIdx.x * 256 + threadIdx.x;  // 12*16384
  int m = idx >> 14;
  int r = idx & 16383;
  int c = r >> 7, k = r & 127;
  int l = m / 6, fam = m % 6;
  const float* src = fam == 0 ? Wq : fam == 1 ? Wk : fam == 2 ? Wv
                   : fam == 3 ? Wo : fam == 4 ? Wm1 : Wm2;
  Wtb[idx] = f2bf(src[l * 16384 + k * 128 + c]);
}

// ---------------- WeWo precompute: WW[l][c][k256], k256=4j+h ----------------

__global__ void k_wewo(const float* __restrict__ We, const float* __restrict__ Wo,
                       ushort* __restrict__ WW) {
  int idx = blockIdx.x * 256 + threadIdx.x;  // 2*128*256
  int l = idx >> 15;
  int r = idx & 32767;
  int c = r >> 8, k = r & 255;
  float acc = 0.f;
  if (k < 200) {
    int j = k >> 2, h = k & 3;
    const float* we = We + (size_t)l * NRAD * DDIM + j * DDIM + 32 * h;
    const float* wo = Wo + (size_t)l * DDIM * DDIM + (size_t)(32 * h) * DDIM + c;
#pragma unroll 8
    for (int dk = 0; dk < 32; ++dk) acc = fmaf(we[dk], wo[(size_t)dk * DDIM], acc);
  }
  WW[idx] = f2bf(acc);
}

// ---------------- embW precompute: embW[a][c] = emb[a]@W_init[0:32] + b ----------------

__global__ void k_embw(const float* __restrict__ emb, const float* __restrict__ W,
                       const float* __restrict__ b, float* __restrict__ embW) {
  int idx = blockIdx.x * 256 + threadIdx.x;  // NTYPE*DDIM = 12800
  if (idx >= NTYPE * DDIM) return;
  int a = idx >> 7, c = idx & 127;
  const float* er = emb + (size_t)a * TEMB;
  float acc = b[c];
#pragma unroll
  for (int t = 0; t < TEMB; ++t) acc = fmaf(er[t], W[t * DDIM + c], acc);
  embW[idx] = acc;
}

// ---------------- init v2: x[n] = embW[at[n]] + pos[n]@W_init[32:35] ----------------

__global__ void k_init2(const float* __restrict__ pos, const int* __restrict__ at,
                        const float* __restrict__ embW, const float* __restrict__ W,
                        float* __restrict__ x) {
  int idx = blockIdx.x * blockDim.x + threadIdx.x;  // NN*32
  if (idx >= NN * 32) return;
  int n = idx >> 5, c4 = (idx & 31) << 2;
  float4 e = *(const float4*)&embW[(size_t)at[n] * DDIM + c4];
  float px = pos[n * 3 + 0], py = pos[n * 3 + 1], pz = pos[n * 3 + 2];
  float4 wx = *(const float4*)&W[(TEMB + 0) * DDIM + c4];
  float4 wy = *(const float4*)&W[(TEMB + 1) * DDIM + c4];
  float4 wz = *(const float4*)&W[(TEMB + 2) * DDIM + c4];
  float4 o;
  o.x = e.x + px * wx.x + py * wy.x + pz * wz.x;
  o.y = e.y + px * wx.y + py * wy.y + pz * wz.y;
  o.z = e.z + px * wx.z + py * wy.z + pz * wz.z;
  o.w = e.w + px * wx.w + py * wy.w + pz * wz.w;
  *(float4*)&x[(size_t)n * DDIM + c4] = o;
}

// ---------------- per-edge distance + degree histogram (fused) ----------------

__global__ void k_edge(const float* __restrict__ pos, const int* __restrict__ ei,
                       float* __restrict__ de, int* __restrict__ deg) {
  int e = blockIdx.x * blockDim.x + threadIdx.x;
  if (e >= NE) return;
  int s = ei[e], t = ei[NE + e];
  float dx = pos[s * 3 + 0] - pos[t * 3 + 0] + 1e-8f;
  float dy = pos[s * 3 + 1] - pos[t * 3 + 1] + 1e-8f;
  float dz = pos[s * 3 + 2] - pos[t * 3 + 2] + 1e-8f;
  de[e] = sqrtf(dx * dx + dy * dy + dz * dz);
  atomicAdd(&deg[t], 1);
}

// ---------------- CSR build: parallel 3-pass exclusive scan ----------------

__global__ void k_scan1(const int* __restrict__ deg, int* __restrict__ bsum) {
  __shared__ int red[256];
  int i = blockIdx.x * 256 + threadIdx.x;
  red[threadIdx.x] = (i < NN) ? deg[i] : 0;
  __syncthreads();
  for (int off = 128; off > 0; off >>= 1) {
    if (threadIdx.x < off) red[threadIdx.x] += red[threadIdx.x + off];
    __syncthreads();
  }
  if (threadIdx.x == 0) bsum[blockIdx.x] = red[0];
}

__global__ void k_scan2(int* __restrict__ bsum) {  // 1 block, 256 threads >= SCAN_N
  __shared__ int sh[256];
  int t = threadIdx.x;
  int v = (t < SCAN_N) ? bsum[t] : 0;
  sh[t] = v;
  __syncthreads();
  for (int off = 1; off < 256; off <<= 1) {
    int u = (t >= off) ? sh[t - off] : 0;
    __syncthreads();
    sh[t] += u;
    __syncthreads();
  }
  if (t < SCAN_N) bsum[t] = (t == 0) ? 0 : sh[t - 1];
}

__global__ void k_scan3(const int* __restrict__ deg, const int* __restrict__ bsum,
                        int* __restrict__ rowptr, int* __restrict__ cnear,
                        int* __restrict__ cfar) {
  __shared__ int sh[256];
  int t = threadIdx.x;
  int i = blockIdx.x * 256 + t;
  int v = (i < NN) ? deg[i] : 0;
  sh[t] = v;
  __syncthreads();
  for (int off = 1; off < 256; off <<= 1) {
    int u = (t >= off) ? sh[t - off] : 0;
    __syncthreads();
    sh[t] += u;
    __syncthreads();
  }
  int excl = bsum[blockIdx.x] + sh[t] - v;
  if (i < NN) {
    rowptr[i] = excl;
    cnear[i] = excl;
    cfar[i] = excl + v;  // = rowptr[i+1]
    if (i == NN - 1) rowptr[NN] = excl + v;
  }
}

// scatter into near-first / far-last segmented CSR, packed records {src, d}
__global__ void k_scatter(const int* __restrict__ ei, const float* __restrict__ de,
                          int* __restrict__ cnear, int* __restrict__ cfar,
                          int2* __restrict__ er) {
  int e = blockIdx.x * blockDim.x + threadIdx.x;
  if (e >= NE) return;
  int src = ei[e], dst = ei[NE + e];
  float d = de[e];
  int idx;
  if (d < CUTF)
    idx = atomicAdd(&cnear[dst], 1);
  else
    idx = atomicSub(&cfar[dst], 1) - 1;
  er[idx] = make_int2(src, __float_as_int(d));
}

// ---------------- fused QKV GEMM: stage x once, 3 weights ----------------

__global__ __launch_bounds__(256) void k_qkv(
    const float* __restrict__ x, const ushort* __restrict__ Wt3,
    ushort* __restrict__ qo, ushort* __restrict__ ko, ushort* __restrict__ vo) {
  __shared__ ushort Al[128 * 128];
  __shared__ ushort Wl[128 * 128];
  const int tid = threadIdx.x;
  const int r0 = blockIdx.x * 128;

  for (int i = tid; i < 128 * 16; i += 256) {
    int r = i >> 4, g = i & 15;
    int gr = r0 + r;
    float4 f0 = {0, 0, 0, 0}, f1 = {0, 0, 0, 0};
    if (gr < NN) {
      f0 = *(const float4*)&x[(size_t)gr * 128 + g * 8];
      f1 = *(const float4*)&x[(size_t)gr * 128 + g * 8 + 4];
    }
    int gs = g ^ (r & 7);
    ushort4 u0 = {f2bf(f0.x), f2bf(f0.y), f2bf(f0.z), f2bf(f0.w)};
    ushort4 u1 = {f2bf(f1.x), f2bf(f1.y), f2bf(f1.z), f2bf(f1.w)};
    *(ushort4*)&Al[r * 128 + gs * 8] = u0;
    *(ushort4*)&Al[r * 128 + gs * 8 + 4] = u1;
  }

  const int w = tid >> 6, l = tid & 63;
  const int lg = l >> 4, lr = l & 15;

  for (int m = 0; m < 3; ++m) {
    for (int i = tid; i < 128 * 16; i += 256) {
      int c = i >> 4, g = i & 15;
      ushort4 w0 = *(const ushort4*)&Wt3[m * 16384 + c * 128 + g * 8];
      ushort4 w1 = *(const ushort4*)&Wt3[m * 16384 + c * 128 + g * 8 + 4];
      int gs = g ^ (c & 7);
      *(ushort4*)&Wl[c * 128 + gs * 8] = w0;
      *(ushort4*)&Wl[c * 128 + gs * 8 + 4] = w1;
    }
    __syncthreads();

    f32x4 acc[2][8];
#pragma unroll
    for (int rt = 0; rt < 2; ++rt)
#pragma unroll
      for (int ct = 0; ct < 8; ++ct) acc[rt][ct] = (f32x4){0.f, 0.f, 0.f, 0.f};

#pragma unroll
    for (int ks = 0; ks < 4; ++ks) {
      short8 af[2];
#pragma unroll
      for (int rt = 0; rt < 2; ++rt) {
        int arow = w * 32 + rt * 16 + lr;
        int ga = (ks * 4 + lg) ^ (arow & 7);
        af[rt] = *(const short8*)&Al[arow * 128 + ga * 8];
      }
#pragma unroll
      for (int ct = 0; ct < 8; ++ct) {
        int col = ct * 16 + lr;
        int gb = (ks * 4 + lg) ^ (col & 7);
        short8 bf = *(const short8*)&Wl[col * 128 + gb * 8];
#pragma unroll
        for (int rt = 0; rt < 2; ++rt)
          acc[rt][ct] = __builtin_amdgcn_mfma_f32_16x16x32_bf16(af[rt], bf, acc[rt][ct], 0, 0, 0);
      }
    }

    ushort* o = (m == 0) ? qo : (m == 1) ? ko : vo;
#pragma unroll
    for (int rt = 0; rt < 2; ++rt)
#pragma unroll
      for (int ct = 0; ct < 8; ++ct) {
        int col = ct * 16 + lr;
#pragma unroll
        for (int r = 0; r < 4; ++r) {
          int row = r0 + w * 32 + rt * 16 + lg * 4 + r;
          if (row < NN) o[(size_t)row * 128 + col] = f2bf(acc[rt][ct][r]);
        }
      }
    __syncthreads();
  }
}

// ---------------- general GEMM: out = act(A@W + bias) (+resid) (+fused LN)
// EXTK: additionally accumulate arbn[NN,200] @ WW[256,128] (2 chunked passes).

template <bool BIAS, bool GELU, bool RESID, bool LNF, bool EXTK>
__global__ __launch_bounds__(256) void k_gemm2(
    const ushort* __restrict__ A, const ushort* __restrict__ Wt,
    const float* __restrict__ bias, const float* __restrict__ resid,
    void* __restrict__ outp, const float* __restrict__ lng,
    const float* __restrict__ lnb, ushort* __restrict__ lnout,
    const ushort* __restrict__ arbn, const ushort* __restrict__ WW) {
  __shared__ ushort Al[128 * 128];
  __shared__ ushort Wl[128 * 128];
  const int tid = threadIdx.x;
  const int r0 = blockIdx.x * 128;

  for (int i = tid; i < 128 * 16; i += 256) {
    int r = i >> 4, g = i & 15;
    int gr = r0 + r;
    ushort4 v0 = {0, 0, 0, 0}, v1 = {0, 0, 0, 0};
    if (gr < NN) {
      v0 = *(const ushort4*)&A[(size_t)gr * 128 + g * 8];
      v1 = *(const ushort4*)&A[(size_t)gr * 128 + g * 8 + 4];
    }
    int gs = g ^ (r & 7);
    *(ushort4*)&Al[r * 128 + gs * 8] = v0;
    *(ushort4*)&Al[r * 128 + gs * 8 + 4] = v1;
  }
  for (int i = tid; i < 128 * 16; i += 256) {
    int c = i >> 4, g = i & 15;
    ushort4 w0 = *(const ushort4*)&Wt[c * 128 + g * 8];
    ushort4 w1 = *(const ushort4*)&Wt[c * 128 + g * 8 + 4];
    int gs = g ^ (c & 7);
    *(ushort4*)&Wl[c * 128 + gs * 8] = w0;
    *(ushort4*)&Wl[c * 128 + gs * 8 + 4] = w1;
  }
  __syncthreads();

  const int w = tid >> 6, l = tid & 63;
  const int lg = l >> 4, lr = l & 15;
  f32x4 acc[2][8];
#pragma unroll
  for (int rt = 0; rt < 2; ++rt)
#pragma unroll
    for (int ct = 0; ct < 8; ++ct) acc[rt][ct] = (f32x4){0.f, 0.f, 0.f, 0.f};

#pragma unroll
  for (int ks = 0; ks < 4; ++ks) {
    short8 af[2];
#pragma unroll
    for (int rt = 0; rt < 2; ++rt) {
      int arow = w * 32 + rt * 16 + lr;
      int ga = (ks * 4 + lg) ^ (arow & 7);
      af[rt] = *(const short8*)&Al[arow * 128 + ga * 8];
    }
#pragma unroll
    for (int ct = 0; ct < 8; ++ct) {
      int col = ct * 16 + lr;
      int gb = (ks * 4 + lg) ^ (col & 7);
      short8 bf = *(const short8*)&Wl[col * 128 + gb * 8];
#pragma unroll
      for (int rt = 0; rt < 2; ++rt)
        acc[rt][ct] = __builtin_amdgcn_mfma_f32_16x16x32_bf16(af[rt], bf, acc[rt][ct], 0, 0, 0);
    }
  }

  if (EXTK) {
    for (int q = 0; q < 2; ++q) {
      __syncthreads();  // prior mfma reads done
      for (int i = tid; i < 128 * 16; i += 256) {
        int r = i >> 4, g = i & 15;
        int gr = r0 + r;
        ushort4 v0 = {0, 0, 0, 0}, v1 = {0, 0, 0, 0};
        if (gr < NN && (q == 0 || g < 9)) {
          v0 = *(const ushort4*)&arbn[(size_t)gr * 200 + q * 128 + g * 8];
          v1 = *(const ushort4*)&arbn[(size_t)gr * 200 + q * 128 + g * 8 + 4];
        }
        int gs = g ^ (r & 7);
        *(ushort4*)&Al[r * 128 + gs * 8] = v0;
        *(ushort4*)&Al[r * 128 + gs * 8 + 4] = v1;
      }
      for (int i = tid; i < 128 * 16; i += 256) {
        int c = i >> 4, g = i & 15;
        ushort4 w0 = *(const ushort4*)&WW[c * 256 + q * 128 + g * 8];
        ushort4 w1 = *(const ushort4*)&WW[c * 256 + q * 128 + g * 8 + 4];
        int gs = g ^ (c & 7);
        *(ushort4*)&Wl[c * 128 + gs * 8] = w0;
        *(ushort4*)&Wl[c * 128 + gs * 8 + 4] = w1;
      }
      __syncthreads();
#pragma unroll
      for (int ks = 0; ks < 4; ++ks) {
        short8 af[2];
#pragma unroll
        for (int rt = 0; rt < 2; ++rt) {
          int arow = w * 32 + rt * 16 + lr;
          int ga = (ks * 4 + lg) ^ (arow & 7);
          af[rt] = *(const short8*)&Al[arow * 128 + ga * 8];
        }
#pragma unroll
        for (int ct = 0; ct < 8; ++ct) {
          int col = ct * 16 + lr;
          int gb = (ks * 4 + lg) ^ (col & 7);
          short8 bf = *(const short8*)&Wl[col * 128 + gb * 8];
#pragma unroll
          for (int rt = 0; rt < 2; ++rt)
            acc[rt][ct] = __builtin_amdgcn_mfma_f32_16x16x32_bf16(af[rt], bf, acc[rt][ct], 0, 0, 0);
        }
      }
    }
  }

#pragma unroll
  for (int rt = 0; rt < 2; ++rt)
#pragma unroll
    for (int r = 0; r < 4; ++r) {
      int row = r0 + w * 32 + rt * 16 + lg * 4 + r;
      bool ok = row < NN;  // uniform across the 16-lane lr group
      float v[8];
#pragma unroll
      for (int ct = 0; ct < 8; ++ct) {
        int col = ct * 16 + lr;
        float vv = acc[rt][ct][r];
        if (BIAS) vv += bias[col];
        if (GELU) vv = gelu_tanh(vv);
        if (RESID) vv += ok ? resid[(size_t)row * 128 + col] : 0.f;
        v[ct] = vv;
      }
      if (RESID || LNF) {
        if (ok)
#pragma unroll
          for (int ct = 0; ct < 8; ++ct)
            ((float*)outp)[(size_t)row * 128 + ct * 16 + lr] = v[ct];
      } else {
        if (ok)
#pragma unroll
          for (int ct = 0; ct < 8; ++ct)
            ((ushort*)outp)[(size_t)row * 128 + ct * 16 + lr] = f2bf(v[ct]);
      }
      if (LNF) {
        float s = 0.f, ss = 0.f;
#pragma unroll
        for (int ct = 0; ct < 8; ++ct) {
          s += v[ct];
          ss = fmaf(v[ct], v[ct], ss);
        }
#pragma unroll
        for (int msk = 8; msk >= 1; msk >>= 1) {
          s += __shfl_xor(s, msk);
          ss += __shfl_xor(ss, msk);
        }
        float mean = s * (1.0f / DDIM);
        float var = ss * (1.0f / DDIM) - mean * mean;
        float inv = rsqrtf(var + 1e-5f);
        if (ok)
#pragma unroll
          for (int ct = 0; ct < 8; ++ct) {
            int col = ct * 16 + lr;
            lnout[(size_t)row * 128 + col] =
                f2bf((v[ct] - mean) * inv * lng[col] + lnb[col]);
          }
      }
    }
}

// ---------------- qe precompute: qe[n][4j+h] ----------------

__global__ __launch_bounds__(256) void k_qe(const ushort* __restrict__ qnb,
                                            const float* __restrict__ We,
                                            ushort* __restrict__ qe) {
  __shared__ float Wlds[NRAD][DDIM + 1];
  __shared__ float qlds[4][DDIM];
  int tid = threadIdx.x;
  for (int i = tid; i < NRAD * DDIM; i += 256) Wlds[i / DDIM][i % DDIM] = We[i];
  __syncthreads();
  int w = tid >> 6, t = tid & 63;
  for (int rep = 0; rep < 2; ++rep) {
    int n = blockIdx.x * 8 + rep * 4 + w;
    uint qu = *(const uint*)&qnb[(size_t)n * DDIM + 2 * t];
    qlds[w][2 * t] = bfl(qu);
    qlds[w][2 * t + 1] = bfh(qu);
    if (t < NRAD) {
      float e0 = 0.f, e1 = 0.f, e2 = 0.f, e3 = 0.f;
#pragma unroll
      for (int d = 0; d < 32; ++d) e0 = fmaf(Wlds[t][d], qlds[w][d], e0);
#pragma unroll
      for (int d = 32; d < 64; ++d) e1 = fmaf(Wlds[t][d], qlds[w][d], e1);
#pragma unroll
      for (int d = 64; d < 96; ++d) e2 = fmaf(Wlds[t][d], qlds[w][d], e2);
#pragma unroll
      for (int d = 96; d < 128; ++d) e3 = fmaf(Wlds[t][d], qlds[w][d], e3);
      ushort4 o = {f2bf(e0), f2bf(e1), f2bf(e2), f2bf(e3)};
      *(ushort4*)&qe[(size_t)n * 200 + 4 * t] = o;
    }
  }
}

// ---------------- fused attention v7: writes a_norm (msgb) + normalized arbn ----------------

__device__ __forceinline__ float rbf_fill(float d, int j) {
  const float step = CUTF / (NRAD - 1);
  const float gamma = (NRAD / CUTF) * (NRAD / CUTF);
  float mu = j * step;
  float dm = d - mu;
  float env = 0.5f * (__cosf(PI_F * d / CUTF) + 1.0f);
  return __expf(-gamma * dm * dm) * env;
}

#define SCALE_QK 0.17677669529663687f

__global__ __launch_bounds__(256) void k_attn7(
    const ushort* __restrict__ qnb, const ushort* __restrict__ knb,
    const ushort* __restrict__ vnb, ushort* __restrict__ qe,
    const int2* __restrict__ er, const int* __restrict__ rowptr,
    const int* __restrict__ nearend, ushort* __restrict__ msgb) {
  __shared__ float qel[4][64][4];   // [wave][j][head]
  __shared__ float rbl[4][64];
  __shared__ float aml[4][128];     // far-accumulator remap buffer (per wave)
  const int tid = threadIdx.x;

  const int w = tid >> 6, t = tid & 63;
  const int n = blockIdx.x * 4 + w;
  const int h = t >> 4;       // near-layout head (16-lane groups)
  const int j0 = t & 15;
  const int hw = t >> 5;      // half-wave id (far loop)
  const int c = t & 31;       // lane in half; owns dims 4c..4c+3 (far loop)
  uint qu = *(const uint*)&qnb[(size_t)n * DDIM + 2 * t];
  const float q0 = bfl(qu), q1 = bfh(qu);
  uint2 qp = *(const uint2*)&qnb[(size_t)n * DDIM + 4 * c];
  const float fq0 = bfl(qp.x), fq1 = bfh(qp.x), fq2 = bfl(qp.y), fq3 = bfh(qp.y);
  if (t < NRAD) {
    ushort4 qv = *(const ushort4*)&qe[(size_t)n * 200 + 4 * t];
    qel[w][t][0] = bfl(qv.x);
    qel[w][t][1] = bfl(qv.y);
    qel[w][t][2] = bfl(qv.z);
    qel[w][t][3] = bfl(qv.w);
  } else {
    qel[w][t][0] = 0.f; qel[w][t][1] = 0.f; qel[w][t][2] = 0.f; qel[w][t][3] = 0.f;
  }
  const int start = rowptr[n], nend = nearend[n], end = rowptr[n + 1];

  float s = 0.f, a0 = 0.f, a1 = 0.f;
  float4 arb = {0.f, 0.f, 0.f, 0.f};

  // ---- near loop (radial features active), full wave per edge ----
  for (int cb = start; cb < nend; cb += 64) {
    int cnt = min(nend - cb, 64);
    int2 e_t = make_int2(0, 0);
    if (t < cnt) e_t = er[cb + t];
    for (int i = 0; i < cnt; ++i) {
      int src = __shfl(e_t.x, i);
      float dd = __shfl(__int_as_float(e_t.y), i);
      uint ku = *(const uint*)&knb[(size_t)src * DDIM + 2 * t];
      uint vu = *(const uint*)&vnb[(size_t)src * DDIM + 2 * t];
      float pr = q0 * bfl(ku) + q1 * bfh(ku);
      float rb = (t < NRAD) ? rbf_fill(dd, t) : 0.f;
      rbl[w][t] = rb;
      pr = fmaf(rbl[w][j0], qel[w][j0][h], pr);
      pr = fmaf(rbl[w][j0 + 16], qel[w][j0 + 16][h], pr);
      pr = fmaf(rbl[w][j0 + 32], qel[w][j0 + 32][h], pr);
      pr = fmaf(rbl[w][j0 + 48], qel[w][j0 + 48][h], pr);
      pr = red16(pr);
      float ae = __expf(fminf(pr * SCALE_QK, 60.f));
      s += ae;
      a0 = fmaf(ae, bfl(vu), a0);
      a1 = fmaf(ae, bfh(vu), a1);
      float aex = __shfl(ae, 0);
      float aey = __shfl(ae, 16);
      float aez = __shfl(ae, 32);
      float aew = __shfl(ae, 48);
      arb.x = fmaf(rb, aex, arb.x);
      arb.y = fmaf(rb, aey, arb.y);
      arb.z = fmaf(rb, aez, arb.z);
      arb.w = fmaf(rb, aew, arb.w);
    }
  }

  // ---- far loop: 2 edges per wave (one per 32-lane half), 4 dims/lane ----
  float sf = 0.f, af0 = 0.f, af1 = 0.f, af2 = 0.f, af3 = 0.f;
  for (int cb = nend; cb < end; cb += 64) {
    int cnt = min(end - cb, 64);
    int src_t = 0;
    if (t < cnt) src_t = er[cb + t].x;
    for (int i = hw; i < cnt; i += 2) {
      int src = __shfl(src_t, i);
      uint2 ku = *(const uint2*)&knb[(size_t)src * DDIM + 4 * c];
      uint2 vu = *(const uint2*)&vnb[(size_t)src * DDIM + 4 * c];
      float pr = fq0 * bfl(ku.x) + fq1 * bfh(ku.x);
      pr = fmaf(fq2, bfl(ku.y), pr);
      pr = fmaf(fq3, bfh(ku.y), pr);
      pr = red8(pr);
      float ae = __expf(fminf(pr * SCALE_QK, 60.f));
      sf += ae;
      af0 = fmaf(ae, bfl(vu.x), af0);
      af1 = fmaf(ae, bfh(vu.x), af1);
      af2 = fmaf(ae, bfl(vu.y), af2);
      af3 = fmaf(ae, bfh(vu.y), af3);
    }
  }
  // combine the two halves (same dims, different edge subsets)
  sf += __shfl_xor(sf, 32);
  af0 += __shfl_xor(af0, 32);
  af1 += __shfl_xor(af1, 32);
  af2 += __shfl_xor(af2, 32);
  af3 += __shfl_xor(af3, 32);
  // remap far accumulators (4 dims/lane) into near layout (2 dims/lane) via LDS
  aml[w][4 * c + 0] = af0;
  aml[w][4 * c + 1] = af1;
  aml[w][4 * c + 2] = af2;
  aml[w][4 * c + 3] = af3;
  a0 += aml[w][2 * t];
  a1 += aml[w][2 * t + 1];

  // ---- finalize: normalize; store a_norm (msgb) and arbn (into qe buffer) ----
  float4 s4;
  s4.x = __shfl(s, 0) + __shfl(sf, 0);
  s4.y = __shfl(s, 16) + __shfl(sf, 8);
  s4.z = __shfl(s, 32) + __shfl(sf, 16);
  s4.w = __shfl(s, 48) + __shfl(sf, 24);
  float4 inv4 = {1.f / (s4.x + 1e-9f), 1.f / (s4.y + 1e-9f),
                 1.f / (s4.z + 1e-9f), 1.f / (s4.w + 1e-9f)};
  float invo = (h == 0) ? inv4.x : (h == 1) ? inv4.y : (h == 2) ? inv4.z : inv4.w;
  if (t < NRAD) {
    ushort4 o = {f2bf(arb.x * inv4.x), f2bf(arb.y * inv4.y),
                 f2bf(arb.z * inv4.z), f2bf(arb.w * inv4.w)};
    *(ushort4*)&qe[(size_t)n * 200 + 4 * t] = o;
  }
  a0 *= invo;
  a1 *= invo;
  uint pk = (uint)f2bf(a0) | ((uint)f2bf(a1) << 16);
  *(uint*)&msgb[(size_t)n * DDIM + 2 * t] = pk;
}

// ---------------- graph sum (batch is sorted): 32 nodes/block, boundary atomics ----------------

#define GS_NODES 32
__global__ void k_graphsum(const float* __restrict__ x, const int* __restrict__ batch,
                           float* __restrict__ g) {
  int t = threadIdx.x;  // 128 dims
  int n0 = blockIdx.x * GS_NODES;
  int nend = n0 + GS_NODES;
  if (nend > NN) nend = NN;
  if (n0 >= NN) return;
  float acc = 0.f;
  int cur = batch[n0];
  for (int n = n0; n < nend; ++n) {
    int bb = batch[n];
    if (bb != cur) {
      atomicAdd(&g[(size_t)cur * DDIM + t], acc);
      acc = 0.f;
      cur = bb;
    }
    acc += x[(size_t)n * DDIM + t];
  }
  atomicAdd(&g[(size_t)cur * DDIM + t], acc);
}

// ---------------- output projection ----------------

__global__ void k_out(const float* __restrict__ g, const float* __restrict__ W,
                      const float* __restrict__ b, float* __restrict__ out) {
  int idx = blockIdx.x * blockDim.x + threadIdx.x;
  if (idx >= NGRAPH * DOUT) return;
  int r = idx / DOUT, c = idx % DOUT;
  float acc = b[c];
#pragma unroll 8
  for (int k = 0; k < DDIM; ++k) acc = fmaf(g[r * DDIM + k], W[k * DOUT + c], acc);
  out[idx] = acc;
}

// ---------------- launch ----------------

extern "C" void kernel_launch(void* const* d_in, const int* in_sizes, int n_in,
                              void* d_out, int out_size, void* d_ws, size_t ws_size,
                              hipStream_t stream) {
  const float* pos = (const float*)d_in[0];
  const int* at = (const int*)d_in[1];
  const int* ei = (const int*)d_in[2];
  const int* batch = (const int*)d_in[3];
  const float* emb = (const float*)d_in[4];
  const float* W_init = (const float*)d_in[5];
  const float* b_init = (const float*)d_in[6];
  const float* Wq = (const float*)d_in[7];
  const float* Wk = (const float*)d_in[8];
  const float* Wv = (const float*)d_in[9];
  const float* We = (const float*)d_in[10];
  const float* Wo = (const float*)d_in[11];
  const float* Wm1 = (const float*)d_in[12];
  const float* bm1 = (const float*)d_in[13];
  const float* Wm2 = (const float*)d_in[14];
  const float* bm2 = (const float*)d_in[15];
  const float* ln_g = (const float*)d_in[16];
  const float* ln_b = (const float*)d_in[17];
  const float* W_out = (const float*)d_in[18];
  const float* b_out = (const float*)d_in[19];
  float* out = (float*)d_out;

  const size_t ND = (size_t)NN * DDIM;  // 6.4M
  float* x = (float*)d_ws;              // f32 ND
  ushort* qnb = (ushort*)(x + ND);      // bf16 ND (alias hb)
  ushort* knb = qnb + ND;               // bf16 ND (alias h2)
  ushort* vnb = knb + ND;               // bf16 ND
  ushort* msgb = vnb + ND;              // bf16 ND
  ushort* qe = msgb + ND;               // bf16 NN*200 (doubles as arbn)
  ushort* Wtb = qe + (size_t)NN * 200;  // bf16 12*16384
  ushort* WW = Wtb + 12 * 16384;        // bf16 2*128*256 (WeWo)
  float* embW = (float*)(WW + 2 * 32768);  // f32 NTYPE*DDIM
  float* de = embW + NTYPE * DDIM;      // f32 NE
  int* deg = (int*)(de + NE);
  int* cnear = deg + NN;
  int* cfar = cnear + NN;
  int* rowptr = cfar + NN;
  int2* er = (int2*)(rowptr + NN + 64);  // NE int2
  float* gb = (float*)(er + NE);         // NG*DDIM
  int* bsum = (int*)(gb + NGRAPH * DDIM);  // SCAN_N
  // total ~96.5 MB

  ushort* hb = qnb;
  ushort* h2 = knb;

  k_wconv<<<12 * 16384 / 256, 256, 0, stream>>>(Wq, Wk, Wv, Wo, Wm1, Wm2, Wtb);
  k_wewo<<<2 * 32768 / 256, 256, 0, stream>>>(We, Wo, WW);
  k_embw<<<(NTYPE * DDIM + 255) / 256, 256, 0, stream>>>(emb, W_init, b_init, embW);
  k_fill_i<<<(NN + 255) / 256, 256, 0, stream>>>(deg, 0, NN);
  k_init2<<<(NN * 32 + 255) / 256, 256, 0, stream>>>(pos, at, embW, W_init, x);
  k_edge<<<(NE + 255) / 256, 256, 0, stream>>>(pos, ei, de, deg);
  k_scan1<<<SCAN_N, 256, 0, stream>>>(deg, bsum);
  k_scan2<<<1, 256, 0, stream>>>(bsum);
  k_scan3<<<SCAN_N, 256, 0, stream>>>(deg, bsum, rowptr, cnear, cfar);
  k_scatter<<<(NE + 255) / 256, 256, 0, stream>>>(ei, de, cnear, cfar, er);

  const int gg = (NN + 127) / 128;  // 391
  for (int l = 0; l < 2; ++l) {
    const ushort* Wt_l = Wtb + (size_t)l * 6 * 16384;
    const float* We_l = We + (size_t)l * NRAD * DDIM;
    const ushort* WW_l = WW + (size_t)l * 32768;

    k_qkv<<<gg, 256, 0, stream>>>(x, Wt_l, qnb, knb, vnb);
    k_qe<<<NN / 8, 256, 0, stream>>>(qnb, We_l, qe);
    k_attn7<<<NN / 4, 256, 0, stream>>>(qnb, knb, vnb, qe, er, rowptr, cnear, msgb);

    // x += msg@Wo + arbn@WeWo, fused layernorm -> hb
    k_gemm2<false, false, true, true, true><<<gg, 256, 0, stream>>>(
        msgb, Wt_l + 3 * 16384, nullptr, x, x,
        ln_g + (size_t)l * DDIM, ln_b + (size_t)l * DDIM, hb, qe, WW_l);
    // h2 = gelu(hb@Wm1 + bm1)
    k_gemm2<true, true, false, false, false><<<gg, 256, 0, stream>>>(
        hb, Wt_l + 4 * 16384, bm1 + (size_t)l * DDIM, nullptr, h2,
        nullptr, nullptr, nullptr, nullptr, nullptr);
    // x += h2@Wm2 + bm2
    k_gemm2<true, false, true, false, false><<<gg, 256, 0, stream>>>(
        h2, Wt_l + 5 * 16384, bm2 + (size_t)l * DDIM, x, x,
        nullptr, nullptr, nullptr, nullptr, nullptr);
  }

  k_fill_f<<<(NGRAPH * DDIM + 255) / 256, 256, 0, stream>>>(gb, 0.f, NGRAPH * DDIM);
  k_graphsum<<<(NN + GS_NODES - 1) / GS_NODES, 128, 0, stream>>>(x, batch, gb);
  k_out<<<(NGRAPH * DOUT + 255) / 256, 256, 0, stream>>>(gb, W_out, b_out, out);
}

// Round 13
// 357.305 us; speedup vs baseline: 1.3876x; 1.2069x over previous
//
#include <hip/hip_runtime.h>
#include <math.h>

#define NN 50000
#define NE 400000
#define DDIM 128
#define NHEAD 4
#define NRAD 50
#define NGRAPH 100
#define NTYPE 100
#define TEMB 32
#define DOUT 512
#define CUTF 6.0f
#define PI_F 3.14159265358979323846f

#define SCAN_N ((NN + 255) / 256)  // 196 scan blocks

typedef unsigned int uint;
typedef unsigned short ushort;
typedef __attribute__((ext_vector_type(8))) short short8;
typedef __attribute__((ext_vector_type(4))) float f32x4;

// ---------------- helpers ----------------

__device__ __forceinline__ float gelu_tanh(float v) {
  float u = 0.7978845608028654f * (v + 0.044715f * v * v * v);
  return 0.5f * v * (1.0f + tanhf(u));
}

__device__ __forceinline__ ushort f2bf(float f) {  // RNE
  uint u = __float_as_uint(f);
  uint r = (u + 0x7fffu + ((u >> 16) & 1u)) >> 16;
  return (ushort)r;
}
__device__ __forceinline__ float bfl(uint u) { return __uint_as_float(u << 16); }
__device__ __forceinline__ float bfh(uint u) { return __uint_as_float(u & 0xffff0000u); }

// DPP sum reductions on the VALU (no ds_bpermute).
__device__ __forceinline__ float red16(float v) {
  v += __int_as_float(__builtin_amdgcn_update_dpp(0, __float_as_int(v), 0xB1, 0xF, 0xF, true));
  v += __int_as_float(__builtin_amdgcn_update_dpp(0, __float_as_int(v), 0x4E, 0xF, 0xF, true));
  v += __int_as_float(__builtin_amdgcn_update_dpp(0, __float_as_int(v), 0x141, 0xF, 0xF, true));
  v += __int_as_float(__builtin_amdgcn_update_dpp(0, __float_as_int(v), 0x140, 0xF, 0xF, true));
  return v;
}
__device__ __forceinline__ float red8(float v) {
  v += __int_as_float(__builtin_amdgcn_update_dpp(0, __float_as_int(v), 0xB1, 0xF, 0xF, true));
  v += __int_as_float(__builtin_amdgcn_update_dpp(0, __float_as_int(v), 0x4E, 0xF, 0xF, true));
  v += __int_as_float(__builtin_amdgcn_update_dpp(0, __float_as_int(v), 0x141, 0xF, 0xF, true));
  return v;
}

__global__ void k_fill_f(float* p, float v, int n) {
  int i = blockIdx.x * blockDim.x + threadIdx.x;
  if (i < n) p[i] = v;
}
__global__ void k_fill_i(int* p, int v, int n) {
  int i = blockIdx.x * blockDim.x + threadIdx.x;
  if (i < n) p[i] = v;
}

// ---------------- weight pre-convert + transpose: Wtb[l][fam][c][k] bf16 ----------------

__global__ void k_wconv(const float* __restrict__ Wq, const float* __restrict__ Wk,
                        const float* __restrict__ Wv, const float* __restrict__ Wo,
                        const float* __restrict__ Wm1, const float* __restrict__ Wm2,
                        ushort* __restrict__ Wtb) {
  int idx = blockIdx.x * 256 + threadIdx.x;  // 12*16384
  int m = idx >> 14;
  int r = idx & 16383;
  int c = r >> 7, k = r & 127;
  int l = m / 6, fam = m % 6;
  const float* src = fam == 0 ? Wq : fam == 1 ? Wk : fam == 2 ? Wv
                   : fam == 3 ? Wo : fam == 4 ? Wm1 : Wm2;
  Wtb[idx] = f2bf(src[l * 16384 + k * 128 + c]);
}

// ---------------- WeWo precompute: WW[l][c][k256], k256=4j+h ----------------

__global__ void k_wewo(const float* __restrict__ We, const float* __restrict__ Wo,
                       ushort* __restrict__ WW) {
  int idx = blockIdx.x * 256 + threadIdx.x;  // 2*128*256
  int l = idx >> 15;
  int r = idx & 32767;
  int c = r >> 8, k = r & 255;
  float acc = 0.f;
  if (k < 200) {
    int j = k >> 2, h = k & 3;
    const float* we = We + (size_t)l * NRAD * DDIM + j * DDIM + 32 * h;
    const float* wo = Wo + (size_t)l * DDIM * DDIM + (size_t)(32 * h) * DDIM + c;
#pragma unroll 8
    for (int dk = 0; dk < 32; ++dk) acc = fmaf(we[dk], wo[(size_t)dk * DDIM], acc);
  }
  WW[idx] = f2bf(acc);
}

// ---------------- WQE precompute: WQET[l][col256][d], col256=4j+h ----------------
// WQET[col][d] = sum_{u<32} Wq[d][32h+u] * We[j][32h+u]  (transposed for GEMM B-staging)

__global__ void k_wqe(const float* __restrict__ Wq, const float* __restrict__ We,
                      ushort* __restrict__ WQET) {
  int idx = blockIdx.x * 256 + threadIdx.x;  // 2*256*128
  int l = idx >> 15;
  int r = idx & 32767;
  int col = r >> 7, d = r & 127;
  float acc = 0.f;
  if (col < 200) {
    int j = col >> 2, h = col & 3;
    const float* wq = Wq + (size_t)l * 16384 + (size_t)d * 128 + 32 * h;
    const float* we = We + (size_t)l * NRAD * DDIM + j * DDIM + 32 * h;
#pragma unroll 8
    for (int u = 0; u < 32; ++u) acc = fmaf(wq[u], we[u], acc);
  }
  WQET[idx] = f2bf(acc);
}

// ---------------- embW precompute: embW[a][c] = emb[a]@W_init[0:32] + b ----------------

__global__ void k_embw(const float* __restrict__ emb, const float* __restrict__ W,
                       const float* __restrict__ b, float* __restrict__ embW) {
  int idx = blockIdx.x * 256 + threadIdx.x;  // NTYPE*DDIM = 12800
  if (idx >= NTYPE * DDIM) return;
  int a = idx >> 7, c = idx & 127;
  const float* er = emb + (size_t)a * TEMB;
  float acc = b[c];
#pragma unroll
  for (int t = 0; t < TEMB; ++t) acc = fmaf(er[t], W[t * DDIM + c], acc);
  embW[idx] = acc;
}

// ---------------- init v2: x[n] = embW[at[n]] + pos[n]@W_init[32:35] ----------------

__global__ void k_init2(const float* __restrict__ pos, const int* __restrict__ at,
                        const float* __restrict__ embW, const float* __restrict__ W,
                        float* __restrict__ x) {
  int idx = blockIdx.x * blockDim.x + threadIdx.x;  // NN*32
  if (idx >= NN * 32) return;
  int n = idx >> 5, c4 = (idx & 31) << 2;
  float4 e = *(const float4*)&embW[(size_t)at[n] * DDIM + c4];
  float px = pos[n * 3 + 0], py = pos[n * 3 + 1], pz = pos[n * 3 + 2];
  float4 wx = *(const float4*)&W[(TEMB + 0) * DDIM + c4];
  float4 wy = *(const float4*)&W[(TEMB + 1) * DDIM + c4];
  float4 wz = *(const float4*)&W[(TEMB + 2) * DDIM + c4];
  float4 o;
  o.x = e.x + px * wx.x + py * wy.x + pz * wz.x;
  o.y = e.y + px * wx.y + py * wy.y + pz * wz.y;
  o.z = e.z + px * wx.z + py * wy.z + pz * wz.z;
  o.w = e.w + px * wx.w + py * wy.w + pz * wz.w;
  *(float4*)&x[(size_t)n * DDIM + c4] = o;
}

// ---------------- per-edge distance + degree histogram (fused) ----------------

__global__ void k_edge(const float* __restrict__ pos, const int* __restrict__ ei,
                       float* __restrict__ de, int* __restrict__ deg) {
  int e = blockIdx.x * blockDim.x + threadIdx.x;
  if (e >= NE) return;
  int s = ei[e], t = ei[NE + e];
  float dx = pos[s * 3 + 0] - pos[t * 3 + 0] + 1e-8f;
  float dy = pos[s * 3 + 1] - pos[t * 3 + 1] + 1e-8f;
  float dz = pos[s * 3 + 2] - pos[t * 3 + 2] + 1e-8f;
  de[e] = sqrtf(dx * dx + dy * dy + dz * dz);
  atomicAdd(&deg[t], 1);
}

// ---------------- CSR build: parallel 3-pass exclusive scan ----------------

__global__ void k_scan1(const int* __restrict__ deg, int* __restrict__ bsum) {
  __shared__ int red[256];
  int i = blockIdx.x * 256 + threadIdx.x;
  red[threadIdx.x] = (i < NN) ? deg[i] : 0;
  __syncthreads();
  for (int off = 128; off > 0; off >>= 1) {
    if (threadIdx.x < off) red[threadIdx.x] += red[threadIdx.x + off];
    __syncthreads();
  }
  if (threadIdx.x == 0) bsum[blockIdx.x] = red[0];
}

__global__ void k_scan2(int* __restrict__ bsum) {  // 1 block, 256 threads >= SCAN_N
  __shared__ int sh[256];
  int t = threadIdx.x;
  int v = (t < SCAN_N) ? bsum[t] : 0;
  sh[t] = v;
  __syncthreads();
  for (int off = 1; off < 256; off <<= 1) {
    int u = (t >= off) ? sh[t - off] : 0;
    __syncthreads();
    sh[t] += u;
    __syncthreads();
  }
  if (t < SCAN_N) bsum[t] = (t == 0) ? 0 : sh[t - 1];
}

__global__ void k_scan3(const int* __restrict__ deg, const int* __restrict__ bsum,
                        int* __restrict__ rowptr, int* __restrict__ cnear,
                        int* __restrict__ cfar) {
  __shared__ int sh[256];
  int t = threadIdx.x;
  int i = blockIdx.x * 256 + t;
  int v = (i < NN) ? deg[i] : 0;
  sh[t] = v;
  __syncthreads();
  for (int off = 1; off < 256; off <<= 1) {
    int u = (t >= off) ? sh[t - off] : 0;
    __syncthreads();
    sh[t] += u;
    __syncthreads();
  }
  int excl = bsum[blockIdx.x] + sh[t] - v;
  if (i < NN) {
    rowptr[i] = excl;
    cnear[i] = excl;
    cfar[i] = excl + v;  // = rowptr[i+1]
    if (i == NN - 1) rowptr[NN] = excl + v;
  }
}

// scatter into near-first / far-last segmented CSR, packed records {src, d}
__global__ void k_scatter(const int* __restrict__ ei, const float* __restrict__ de,
                          int* __restrict__ cnear, int* __restrict__ cfar,
                          int2* __restrict__ er) {
  int e = blockIdx.x * blockDim.x + threadIdx.x;
  if (e >= NE) return;
  int src = ei[e], dst = ei[NE + e];
  float d = de[e];
  int idx;
  if (d < CUTF)
    idx = atomicAdd(&cnear[dst], 1);
  else
    idx = atomicSub(&cfar[dst], 1) - 1;
  er[idx] = make_int2(src, __float_as_int(d));
}

// ---------------- fused QKV+QE GEMM: stage x once, 5 weight passes ----------------
// m=0..2: q/k/v (128 cols). m=3,4: qe = x @ WQE chunks (cols 0..127 / 128..199).

__global__ __launch_bounds__(256) void k_qkv(
    const float* __restrict__ x, const ushort* __restrict__ Wt3,
    const ushort* __restrict__ WQET, ushort* __restrict__ qo,
    ushort* __restrict__ ko, ushort* __restrict__ vo, ushort* __restrict__ qe) {
  __shared__ ushort Al[128 * 128];
  __shared__ ushort Wl[128 * 128];
  const int tid = threadIdx.x;
  const int r0 = blockIdx.x * 128;

  for (int i = tid; i < 128 * 16; i += 256) {
    int r = i >> 4, g = i & 15;
    int gr = r0 + r;
    float4 f0 = {0, 0, 0, 0}, f1 = {0, 0, 0, 0};
    if (gr < NN) {
      f0 = *(const float4*)&x[(size_t)gr * 128 + g * 8];
      f1 = *(const float4*)&x[(size_t)gr * 128 + g * 8 + 4];
    }
    int gs = g ^ (r & 7);
    ushort4 u0 = {f2bf(f0.x), f2bf(f0.y), f2bf(f0.z), f2bf(f0.w)};
    ushort4 u1 = {f2bf(f1.x), f2bf(f1.y), f2bf(f1.z), f2bf(f1.w)};
    *(ushort4*)&Al[r * 128 + gs * 8] = u0;
    *(ushort4*)&Al[r * 128 + gs * 8 + 4] = u1;
  }

  const int w = tid >> 6, l = tid & 63;
  const int lg = l >> 4, lr = l & 15;

  for (int m = 0; m < 5; ++m) {
    const ushort* wsrc = (m < 3) ? (Wt3 + m * 16384) : (WQET + (m - 3) * 16384);
    for (int i = tid; i < 128 * 16; i += 256) {
      int c = i >> 4, g = i & 15;
      ushort4 w0 = *(const ushort4*)&wsrc[c * 128 + g * 8];
      ushort4 w1 = *(const ushort4*)&wsrc[c * 128 + g * 8 + 4];
      int gs = g ^ (c & 7);
      *(ushort4*)&Wl[c * 128 + gs * 8] = w0;
      *(ushort4*)&Wl[c * 128 + gs * 8 + 4] = w1;
    }
    __syncthreads();

    f32x4 acc[2][8];
#pragma unroll
    for (int rt = 0; rt < 2; ++rt)
#pragma unroll
      for (int ct = 0; ct < 8; ++ct) acc[rt][ct] = (f32x4){0.f, 0.f, 0.f, 0.f};

#pragma unroll
    for (int ks = 0; ks < 4; ++ks) {
      short8 af[2];
#pragma unroll
      for (int rt = 0; rt < 2; ++rt) {
        int arow = w * 32 + rt * 16 + lr;
        int ga = (ks * 4 + lg) ^ (arow & 7);
        af[rt] = *(const short8*)&Al[arow * 128 + ga * 8];
      }
#pragma unroll
      for (int ct = 0; ct < 8; ++ct) {
        int col = ct * 16 + lr;
        int gb = (ks * 4 + lg) ^ (col & 7);
        short8 bf = *(const short8*)&Wl[col * 128 + gb * 8];
#pragma unroll
        for (int rt = 0; rt < 2; ++rt)
          acc[rt][ct] = __builtin_amdgcn_mfma_f32_16x16x32_bf16(af[rt], bf, acc[rt][ct], 0, 0, 0);
      }
    }

    if (m < 3) {
      ushort* o = (m == 0) ? qo : (m == 1) ? ko : vo;
#pragma unroll
      for (int rt = 0; rt < 2; ++rt)
#pragma unroll
        for (int ct = 0; ct < 8; ++ct) {
          int col = ct * 16 + lr;
#pragma unroll
          for (int r = 0; r < 4; ++r) {
            int row = r0 + w * 32 + rt * 16 + lg * 4 + r;
            if (row < NN) o[(size_t)row * 128 + col] = f2bf(acc[rt][ct][r]);
          }
        }
    } else {
      int cb = (m - 3) * 128;
#pragma unroll
      for (int rt = 0; rt < 2; ++rt)
#pragma unroll
        for (int ct = 0; ct < 8; ++ct) {
          int col = cb + ct * 16 + lr;
          if (col < 200) {
#pragma unroll
            for (int r = 0; r < 4; ++r) {
              int row = r0 + w * 32 + rt * 16 + lg * 4 + r;
              if (row < NN) qe[(size_t)row * 200 + col] = f2bf(acc[rt][ct][r]);
            }
          }
        }
    }
    __syncthreads();
  }
}

// ---------------- general GEMM: out = act(A@W + bias) (+resid) (+fused LN)
// EXTK: additionally accumulate arbn[NN,200] @ WW[256,128] (2 chunked passes).

template <bool BIAS, bool GELU, bool RESID, bool LNF, bool EXTK>
__global__ __launch_bounds__(256) void k_gemm2(
    const ushort* __restrict__ A, const ushort* __restrict__ Wt,
    const float* __restrict__ bias, const float* __restrict__ resid,
    void* __restrict__ outp, const float* __restrict__ lng,
    const float* __restrict__ lnb, ushort* __restrict__ lnout,
    const ushort* __restrict__ arbn, const ushort* __restrict__ WW) {
  __shared__ ushort Al[128 * 128];
  __shared__ ushort Wl[128 * 128];
  const int tid = threadIdx.x;
  const int r0 = blockIdx.x * 128;

  for (int i = tid; i < 128 * 16; i += 256) {
    int r = i >> 4, g = i & 15;
    int gr = r0 + r;
    ushort4 v0 = {0, 0, 0, 0}, v1 = {0, 0, 0, 0};
    if (gr < NN) {
      v0 = *(const ushort4*)&A[(size_t)gr * 128 + g * 8];
      v1 = *(const ushort4*)&A[(size_t)gr * 128 + g * 8 + 4];
    }
    int gs = g ^ (r & 7);
    *(ushort4*)&Al[r * 128 + gs * 8] = v0;
    *(ushort4*)&Al[r * 128 + gs * 8 + 4] = v1;
  }
  for (int i = tid; i < 128 * 16; i += 256) {
    int c = i >> 4, g = i & 15;
    ushort4 w0 = *(const ushort4*)&Wt[c * 128 + g * 8];
    ushort4 w1 = *(const ushort4*)&Wt[c * 128 + g * 8 + 4];
    int gs = g ^ (c & 7);
    *(ushort4*)&Wl[c * 128 + gs * 8] = w0;
    *(ushort4*)&Wl[c * 128 + gs * 8 + 4] = w1;
  }
  __syncthreads();

  const int w = tid >> 6, l = tid & 63;
  const int lg = l >> 4, lr = l & 15;
  f32x4 acc[2][8];
#pragma unroll
  for (int rt = 0; rt < 2; ++rt)
#pragma unroll
    for (int ct = 0; ct < 8; ++ct) acc[rt][ct] = (f32x4){0.f, 0.f, 0.f, 0.f};

#pragma unroll
  for (int ks = 0; ks < 4; ++ks) {
    short8 af[2];
#pragma unroll
    for (int rt = 0; rt < 2; ++rt) {
      int arow = w * 32 + rt * 16 + lr;
      int ga = (ks * 4 + lg) ^ (arow & 7);
      af[rt] = *(const short8*)&Al[arow * 128 + ga * 8];
    }
#pragma unroll
    for (int ct = 0; ct < 8; ++ct) {
      int col = ct * 16 + lr;
      int gb = (ks * 4 + lg) ^ (col & 7);
      short8 bf = *(const short8*)&Wl[col * 128 + gb * 8];
#pragma unroll
      for (int rt = 0; rt < 2; ++rt)
        acc[rt][ct] = __builtin_amdgcn_mfma_f32_16x16x32_bf16(af[rt], bf, acc[rt][ct], 0, 0, 0);
    }
  }

  if (EXTK) {
    for (int q = 0; q < 2; ++q) {
      __syncthreads();  // prior mfma reads done
      for (int i = tid; i < 128 * 16; i += 256) {
        int r = i >> 4, g = i & 15;
        int gr = r0 + r;
        ushort4 v0 = {0, 0, 0, 0}, v1 = {0, 0, 0, 0};
        if (gr < NN && (q == 0 || g < 9)) {
          v0 = *(const ushort4*)&arbn[(size_t)gr * 200 + q * 128 + g * 8];
          v1 = *(const ushort4*)&arbn[(size_t)gr * 200 + q * 128 + g * 8 + 4];
        }
        int gs = g ^ (r & 7);
        *(ushort4*)&Al[r * 128 + gs * 8] = v0;
        *(ushort4*)&Al[r * 128 + gs * 8 + 4] = v1;
      }
      for (int i = tid; i < 128 * 16; i += 256) {
        int c = i >> 4, g = i & 15;
        ushort4 w0 = *(const ushort4*)&WW[c * 256 + q * 128 + g * 8];
        ushort4 w1 = *(const ushort4*)&WW[c * 256 + q * 128 + g * 8 + 4];
        int gs = g ^ (c & 7);
        *(ushort4*)&Wl[c * 128 + gs * 8] = w0;
        *(ushort4*)&Wl[c * 128 + gs * 8 + 4] = w1;
      }
      __syncthreads();
#pragma unroll
      for (int ks = 0; ks < 4; ++ks) {
        short8 af[2];
#pragma unroll
        for (int rt = 0; rt < 2; ++rt) {
          int arow = w * 32 + rt * 16 + lr;
          int ga = (ks * 4 + lg) ^ (arow & 7);
          af[rt] = *(const short8*)&Al[arow * 128 + ga * 8];
        }
#pragma unroll
        for (int ct = 0; ct < 8; ++ct) {
          int col = ct * 16 + lr;
          int gb = (ks * 4 + lg) ^ (col & 7);
          short8 bf = *(const short8*)&Wl[col * 128 + gb * 8];
#pragma unroll
          for (int rt = 0; rt < 2; ++rt)
            acc[rt][ct] = __builtin_amdgcn_mfma_f32_16x16x32_bf16(af[rt], bf, acc[rt][ct], 0, 0, 0);
        }
      }
    }
  }

#pragma unroll
  for (int rt = 0; rt < 2; ++rt)
#pragma unroll
    for (int r = 0; r < 4; ++r) {
      int row = r0 + w * 32 + rt * 16 + lg * 4 + r;
      bool ok = row < NN;  // uniform across the 16-lane lr group
      float v[8];
#pragma unroll
      for (int ct = 0; ct < 8; ++ct) {
        int col = ct * 16 + lr;
        float vv = acc[rt][ct][r];
        if (BIAS) vv += bias[col];
        if (GELU) vv = gelu_tanh(vv);
        if (RESID) vv += ok ? resid[(size_t)row * 128 + col] : 0.f;
        v[ct] = vv;
      }
      if (RESID || LNF) {
        if (ok)
#pragma unroll
          for (int ct = 0; ct < 8; ++ct)
            ((float*)outp)[(size_t)row * 128 + ct * 16 + lr] = v[ct];
      } else {
        if (ok)
#pragma unroll
          for (int ct = 0; ct < 8; ++ct)
            ((ushort*)outp)[(size_t)row * 128 + ct * 16 + lr] = f2bf(v[ct]);
      }
      if (LNF) {
        float s = 0.f, ss = 0.f;
#pragma unroll
        for (int ct = 0; ct < 8; ++ct) {
          s += v[ct];
          ss = fmaf(v[ct], v[ct], ss);
        }
#pragma unroll
        for (int msk = 8; msk >= 1; msk >>= 1) {
          s += __shfl_xor(s, msk);
          ss += __shfl_xor(ss, msk);
        }
        float mean = s * (1.0f / DDIM);
        float var = ss * (1.0f / DDIM) - mean * mean;
        float inv = rsqrtf(var + 1e-5f);
        if (ok)
#pragma unroll
          for (int ct = 0; ct < 8; ++ct) {
            int col = ct * 16 + lr;
            lnout[(size_t)row * 128 + col] =
                f2bf((v[ct] - mean) * inv * lng[col] + lnb[col]);
          }
      }
    }
}

// ---------------- fused attention v7: writes a_norm (msgb) + normalized arbn ----------------

__device__ __forceinline__ float rbf_fill(float d, int j) {
  const float step = CUTF / (NRAD - 1);
  const float gamma = (NRAD / CUTF) * (NRAD / CUTF);
  float mu = j * step;
  float dm = d - mu;
  float env = 0.5f * (__cosf(PI_F * d / CUTF) + 1.0f);
  return __expf(-gamma * dm * dm) * env;
}

#define SCALE_QK 0.17677669529663687f

__global__ __launch_bounds__(256) void k_attn7(
    const ushort* __restrict__ qnb, const ushort* __restrict__ knb,
    const ushort* __restrict__ vnb, ushort* __restrict__ qe,
    const int2* __restrict__ er, const int* __restrict__ rowptr,
    const int* __restrict__ nearend, ushort* __restrict__ msgb) {
  __shared__ float qel[4][64][4];   // [wave][j][head]
  __shared__ float rbl[4][64];
  __shared__ float aml[4][128];     // far-accumulator remap buffer (per wave)
  const int tid = threadIdx.x;

  const int w = tid >> 6, t = tid & 63;
  const int n = blockIdx.x * 4 + w;
  const int h = t >> 4;       // near-layout head (16-lane groups)
  const int j0 = t & 15;
  const int hw = t >> 5;      // half-wave id (far loop)
  const int c = t & 31;       // lane in half; owns dims 4c..4c+3 (far loop)
  uint qu = *(const uint*)&qnb[(size_t)n * DDIM + 2 * t];
  const float q0 = bfl(qu), q1 = bfh(qu);
  uint2 qp = *(const uint2*)&qnb[(size_t)n * DDIM + 4 * c];
  const float fq0 = bfl(qp.x), fq1 = bfh(qp.x), fq2 = bfl(qp.y), fq3 = bfh(qp.y);
  if (t < NRAD) {
    ushort4 qv = *(const ushort4*)&qe[(size_t)n * 200 + 4 * t];
    qel[w][t][0] = bfl(qv.x);
    qel[w][t][1] = bfl(qv.y);
    qel[w][t][2] = bfl(qv.z);
    qel[w][t][3] = bfl(qv.w);
  } else {
    qel[w][t][0] = 0.f; qel[w][t][1] = 0.f; qel[w][t][2] = 0.f; qel[w][t][3] = 0.f;
  }
  const int start = rowptr[n], nend = nearend[n], end = rowptr[n + 1];

  float s = 0.f, a0 = 0.f, a1 = 0.f;
  float4 arb = {0.f, 0.f, 0.f, 0.f};

  // ---- near loop (radial features active), full wave per edge ----
  for (int cb = start; cb < nend; cb += 64) {
    int cnt = min(nend - cb, 64);
    int2 e_t = make_int2(0, 0);
    if (t < cnt) e_t = er[cb + t];
    for (int i = 0; i < cnt; ++i) {
      int src = __shfl(e_t.x, i);
      float dd = __shfl(__int_as_float(e_t.y), i);
      uint ku = *(const uint*)&knb[(size_t)src * DDIM + 2 * t];
      uint vu = *(const uint*)&vnb[(size_t)src * DDIM + 2 * t];
      float pr = q0 * bfl(ku) + q1 * bfh(ku);
      float rb = (t < NRAD) ? rbf_fill(dd, t) : 0.f;
      rbl[w][t] = rb;
      pr = fmaf(rbl[w][j0], qel[w][j0][h], pr);
      pr = fmaf(rbl[w][j0 + 16], qel[w][j0 + 16][h], pr);
      pr = fmaf(rbl[w][j0 + 32], qel[w][j0 + 32][h], pr);
      pr = fmaf(rbl[w][j0 + 48], qel[w][j0 + 48][h], pr);
      pr = red16(pr);
      float ae = __expf(fminf(pr * SCALE_QK, 60.f));
      s += ae;
      a0 = fmaf(ae, bfl(vu), a0);
      a1 = fmaf(ae, bfh(vu), a1);
      float aex = __shfl(ae, 0);
      float aey = __shfl(ae, 16);
      float aez = __shfl(ae, 32);
      float aew = __shfl(ae, 48);
      arb.x = fmaf(rb, aex, arb.x);
      arb.y = fmaf(rb, aey, arb.y);
      arb.z = fmaf(rb, aez, arb.z);
      arb.w = fmaf(rb, aew, arb.w);
    }
  }

  // ---- far loop: 2 edges per wave (one per 32-lane half), 4 dims/lane ----
  float sf = 0.f, af0 = 0.f, af1 = 0.f, af2 = 0.f, af3 = 0.f;
  for (int cb = nend; cb < end; cb += 64) {
    int cnt = min(end - cb, 64);
    int src_t = 0;
    if (t < cnt) src_t = er[cb + t].x;
    for (int i = hw; i < cnt; i += 2) {
      int src = __shfl(src_t, i);
      uint2 ku = *(const uint2*)&knb[(size_t)src * DDIM + 4 * c];
      uint2 vu = *(const uint2*)&vnb[(size_t)src * DDIM + 4 * c];
      float pr = fq0 * bfl(ku.x) + fq1 * bfh(ku.x);
      pr = fmaf(fq2, bfl(ku.y), pr);
      pr = fmaf(fq3, bfh(ku.y), pr);
      pr = red8(pr);
      float ae = __expf(fminf(pr * SCALE_QK, 60.f));
      sf += ae;
      af0 = fmaf(ae, bfl(vu.x), af0);
      af1 = fmaf(ae, bfh(vu.x), af1);
      af2 = fmaf(ae, bfl(vu.y), af2);
      af3 = fmaf(ae, bfh(vu.y), af3);
    }
  }
  // combine the two halves (same dims, different edge subsets)
  sf += __shfl_xor(sf, 32);
  af0 += __shfl_xor(af0, 32);
  af1 += __shfl_xor(af1, 32);
  af2 += __shfl_xor(af2, 32);
  af3 += __shfl_xor(af3, 32);
  // remap far accumulators (4 dims/lane) into near layout (2 dims/lane) via LDS
  aml[w][4 * c + 0] = af0;
  aml[w][4 * c + 1] = af1;
  aml[w][4 * c + 2] = af2;
  aml[w][4 * c + 3] = af3;
  a0 += aml[w][2 * t];
  a1 += aml[w][2 * t + 1];

  // ---- finalize: normalize; store a_norm (msgb) and arbn (into qe buffer) ----
  float4 s4;
  s4.x = __shfl(s, 0) + __shfl(sf, 0);
  s4.y = __shfl(s, 16) + __shfl(sf, 8);
  s4.z = __shfl(s, 32) + __shfl(sf, 16);
  s4.w = __shfl(s, 48) + __shfl(sf, 24);
  float4 inv4 = {1.f / (s4.x + 1e-9f), 1.f / (s4.y + 1e-9f),
                 1.f / (s4.z + 1e-9f), 1.f / (s4.w + 1e-9f)};
  float invo = (h == 0) ? inv4.x : (h == 1) ? inv4.y : (h == 2) ? inv4.z : inv4.w;
  if (t < NRAD) {
    ushort4 o = {f2bf(arb.x * inv4.x), f2bf(arb.y * inv4.y),
                 f2bf(arb.z * inv4.z), f2bf(arb.w * inv4.w)};
    *(ushort4*)&qe[(size_t)n * 200 + 4 * t] = o;
  }
  a0 *= invo;
  a1 *= invo;
  uint pk = (uint)f2bf(a0) | ((uint)f2bf(a1) << 16);
  *(uint*)&msgb[(size_t)n * DDIM + 2 * t] = pk;
}

// ---------------- graph sum (batch is sorted): 32 nodes/block, boundary atomics ----------------

#define GS_NODES 32
__global__ void k_graphsum(const float* __restrict__ x, const int* __restrict__ batch,
                           float* __restrict__ g) {
  int t = threadIdx.x;  // 128 dims
  int n0 = blockIdx.x * GS_NODES;
  int nend = n0 + GS_NODES;
  if (nend > NN) nend = NN;
  if (n0 >= NN) return;
  float acc = 0.f;
  int cur = batch[n0];
  for (int n = n0; n < nend; ++n) {
    int bb = batch[n];
    if (bb != cur) {
      atomicAdd(&g[(size_t)cur * DDIM + t], acc);
      acc = 0.f;
      cur = bb;
    }
    acc += x[(size_t)n * DDIM + t];
  }
  atomicAdd(&g[(size_t)cur * DDIM + t], acc);
}

// ---------------- output projection ----------------

__global__ void k_out(const float* __restrict__ g, const float* __restrict__ W,
                      const float* __restrict__ b, float* __restrict__ out) {
  int idx = blockIdx.x * blockDim.x + threadIdx.x;
  if (idx >= NGRAPH * DOUT) return;
  int r = idx / DOUT, c = idx % DOUT;
  float acc = b[c];
#pragma unroll 8
  for (int k = 0; k < DDIM; ++k) acc = fmaf(g[r * DDIM + k], W[k * DOUT + c], acc);
  out[idx] = acc;
}

// ---------------- launch ----------------

extern "C" void kernel_launch(void* const* d_in, const int* in_sizes, int n_in,
                              void* d_out, int out_size, void* d_ws, size_t ws_size,
                              hipStream_t stream) {
  const float* pos = (const float*)d_in[0];
  const int* at = (const int*)d_in[1];
  const int* ei = (const int*)d_in[2];
  const int* batch = (const int*)d_in[3];
  const float* emb = (const float*)d_in[4];
  const float* W_init = (const float*)d_in[5];
  const float* b_init = (const float*)d_in[6];
  const float* Wq = (const float*)d_in[7];
  const float* Wk = (const float*)d_in[8];
  const float* Wv = (const float*)d_in[9];
  const float* We = (const float*)d_in[10];
  const float* Wo = (const float*)d_in[11];
  const float* Wm1 = (const float*)d_in[12];
  const float* bm1 = (const float*)d_in[13];
  const float* Wm2 = (const float*)d_in[14];
  const float* bm2 = (const float*)d_in[15];
  const float* ln_g = (const float*)d_in[16];
  const float* ln_b = (const float*)d_in[17];
  const float* W_out = (const float*)d_in[18];
  const float* b_out = (const float*)d_in[19];
  float* out = (float*)d_out;

  const size_t ND = (size_t)NN * DDIM;  // 6.4M
  float* x = (float*)d_ws;              // f32 ND
  ushort* qnb = (ushort*)(x + ND);      // bf16 ND (alias hb)
  ushort* knb = qnb + ND;               // bf16 ND (alias h2)
  ushort* vnb = knb + ND;               // bf16 ND
  ushort* msgb = vnb + ND;              // bf16 ND
  ushort* qe = msgb + ND;               // bf16 NN*200 (doubles as arbn)
  ushort* Wtb = qe + (size_t)NN * 200;  // bf16 12*16384
  ushort* WW = Wtb + 12 * 16384;        // bf16 2*128*256 (WeWo)
  ushort* WQET = WW + 2 * 32768;        // bf16 2*256*128 (WqWe^T)
  float* embW = (float*)(WQET + 2 * 32768);  // f32 NTYPE*DDIM
  float* de = embW + NTYPE * DDIM;      // f32 NE
  int* deg = (int*)(de + NE);
  int* cnear = deg + NN;
  int* cfar = cnear + NN;
  int* rowptr = cfar + NN;
  int2* er = (int2*)(rowptr + NN + 64);  // NE int2
  float* gb = (float*)(er + NE);         // NG*DDIM
  int* bsum = (int*)(gb + NGRAPH * DDIM);  // SCAN_N
  // total ~96.6 MB

  ushort* hb = qnb;
  ushort* h2 = knb;

  k_wconv<<<12 * 16384 / 256, 256, 0, stream>>>(Wq, Wk, Wv, Wo, Wm1, Wm2, Wtb);
  k_wewo<<<2 * 32768 / 256, 256, 0, stream>>>(We, Wo, WW);
  k_wqe<<<2 * 32768 / 256, 256, 0, stream>>>(Wq, We, WQET);
  k_embw<<<(NTYPE * DDIM + 255) / 256, 256, 0, stream>>>(emb, W_init, b_init, embW);
  k_fill_i<<<(NN + 255) / 256, 256, 0, stream>>>(deg, 0, NN);
  k_init2<<<(NN * 32 + 255) / 256, 256, 0, stream>>>(pos, at, embW, W_init, x);
  k_edge<<<(NE + 255) / 256, 256, 0, stream>>>(pos, ei, de, deg);
  k_scan1<<<SCAN_N, 256, 0, stream>>>(deg, bsum);
  k_scan2<<<1, 256, 0, stream>>>(bsum);
  k_scan3<<<SCAN_N, 256, 0, stream>>>(deg, bsum, rowptr, cnear, cfar);
  k_scatter<<<(NE + 255) / 256, 256, 0, stream>>>(ei, de, cnear, cfar, er);

  const int gg = (NN + 127) / 128;  // 391
  for (int l = 0; l < 2; ++l) {
    const ushort* Wt_l = Wtb + (size_t)l * 6 * 16384;
    const ushort* WQET_l = WQET + (size_t)l * 32768;
    const ushort* WW_l = WW + (size_t)l * 32768;

    k_qkv<<<gg, 256, 0, stream>>>(x, Wt_l, WQET_l, qnb, knb, vnb, qe);
    k_attn7<<<NN / 4, 256, 0, stream>>>(qnb, knb, vnb, qe, er, rowptr, cnear, msgb);

    // x += msg@Wo + arbn@WeWo, fused layernorm -> hb
    k_gemm2<false, false, true, true, true><<<gg, 256, 0, stream>>>(
        msgb, Wt_l + 3 * 16384, nullptr, x, x,
        ln_g + (size_t)l * DDIM, ln_b + (size_t)l * DDIM, hb, qe, WW_l);
    // h2 = gelu(hb@Wm1 + bm1)
    k_gemm2<true, true, false, false, false><<<gg, 256, 0, stream>>>(
        hb, Wt_l + 4 * 16384, bm1 + (size_t)l * DDIM, nullptr, h2,
        nullptr, nullptr, nullptr, nullptr, nullptr);
    // x += h2@Wm2 + bm2
    k_gemm2<true, false, true, false, false><<<gg, 256, 0, stream>>>(
        h2, Wt_l + 5 * 16384, bm2 + (size_t)l * DDIM, x, x,
        nullptr, nullptr, nullptr, nullptr, nullptr);
  }

  k_fill_f<<<(NGRAPH * DDIM + 255) / 256, 256, 0, stream>>>(gb, 0.f, NGRAPH * DDIM);
  k_graphsum<<<(NN + GS_NODES - 1) / GS_NODES, 128, 0, stream>>>(x, batch, gb);
  k_out<<<(NGRAPH * DOUT + 255) / 256, 256, 0, stream>>>(gb, W_out, b_out, out);
}

// Round 14
// 352.355 us; speedup vs baseline: 1.4071x; 1.0140x over previous
//
#include <hip/hip_runtime.h>
#include <math.h>

#define NN 50000
#define NE 400000
#define DDIM 128
#define NHEAD 4
#define NRAD 50
#define NGRAPH 100
#define NTYPE 100
#define TEMB 32
#define DOUT 512
#define CUTF 6.0f
#define PI_F 3.14159265358979323846f

#define SCAN_N ((NN + 255) / 256)  // 196 scan blocks

typedef unsigned int uint;
typedef unsigned short ushort;
typedef __attribute__((ext_vector_type(8))) short short8;
typedef __attribute__((ext_vector_type(4))) float f32x4;

// ---------------- helpers ----------------

__device__ __forceinline__ float gelu_tanh(float v) {
  float u = 0.7978845608028654f * (v + 0.044715f * v * v * v);
  return 0.5f * v * (1.0f + tanhf(u));
}

__device__ __forceinline__ ushort f2bf(float f) {  // RNE
  uint u = __float_as_uint(f);
  uint r = (u + 0x7fffu + ((u >> 16) & 1u)) >> 16;
  return (ushort)r;
}
__device__ __forceinline__ float bfl(uint u) { return __uint_as_float(u << 16); }
__device__ __forceinline__ float bfh(uint u) { return __uint_as_float(u & 0xffff0000u); }

// DPP sum reductions on the VALU (no ds_bpermute).
__device__ __forceinline__ float red16(float v) {
  v += __int_as_float(__builtin_amdgcn_update_dpp(0, __float_as_int(v), 0xB1, 0xF, 0xF, true));
  v += __int_as_float(__builtin_amdgcn_update_dpp(0, __float_as_int(v), 0x4E, 0xF, 0xF, true));
  v += __int_as_float(__builtin_amdgcn_update_dpp(0, __float_as_int(v), 0x141, 0xF, 0xF, true));
  v += __int_as_float(__builtin_amdgcn_update_dpp(0, __float_as_int(v), 0x140, 0xF, 0xF, true));
  return v;
}
__device__ __forceinline__ float red8(float v) {
  v += __int_as_float(__builtin_amdgcn_update_dpp(0, __float_as_int(v), 0xB1, 0xF, 0xF, true));
  v += __int_as_float(__builtin_amdgcn_update_dpp(0, __float_as_int(v), 0x4E, 0xF, 0xF, true));
  v += __int_as_float(__builtin_amdgcn_update_dpp(0, __float_as_int(v), 0x141, 0xF, 0xF, true));
  return v;
}

__global__ void k_fill_f(float* p, float v, int n) {
  int i = blockIdx.x * blockDim.x + threadIdx.x;
  if (i < n) p[i] = v;
}

// ---------------- fused prologue: wconv | wewo | wqe | embw | deg=0 ----------------
// blockIdx ranges: [0,768) wconv, [768,1024) wewo, [1024,1280) wqe,
// [1280,1330) embw, [1330,1526) deg zero.

__global__ void k_pre(const float* __restrict__ Wq, const float* __restrict__ Wk,
                      const float* __restrict__ Wv, const float* __restrict__ Wo,
                      const float* __restrict__ Wm1, const float* __restrict__ Wm2,
                      const float* __restrict__ We, const float* __restrict__ emb,
                      const float* __restrict__ Wi, const float* __restrict__ bi,
                      ushort* __restrict__ Wtb, ushort* __restrict__ WW,
                      ushort* __restrict__ WQET, float* __restrict__ embW,
                      int* __restrict__ deg) {
  int b = blockIdx.x;
  if (b < 768) {  // wconv: 12*16384
    int idx = b * 256 + threadIdx.x;
    int m = idx >> 14;
    int r = idx & 16383;
    int c = r >> 7, k = r & 127;
    int l = m / 6, fam = m % 6;
    const float* src = fam == 0 ? Wq : fam == 1 ? Wk : fam == 2 ? Wv
                     : fam == 3 ? Wo : fam == 4 ? Wm1 : Wm2;
    Wtb[idx] = f2bf(src[l * 16384 + k * 128 + c]);
  } else if (b < 1024) {  // wewo: 2*128*256
    int idx = (b - 768) * 256 + threadIdx.x;
    int l = idx >> 15;
    int r = idx & 32767;
    int c = r >> 8, k = r & 255;
    float acc = 0.f;
    if (k < 200) {
      int j = k >> 2, h = k & 3;
      const float* we = We + (size_t)l * NRAD * DDIM + j * DDIM + 32 * h;
      const float* wo = Wo + (size_t)l * DDIM * DDIM + (size_t)(32 * h) * DDIM + c;
#pragma unroll 8
      for (int dk = 0; dk < 32; ++dk) acc = fmaf(we[dk], wo[(size_t)dk * DDIM], acc);
    }
    WW[idx] = f2bf(acc);
  } else if (b < 1280) {  // wqe: 2*256*128
    int idx = (b - 1024) * 256 + threadIdx.x;
    int l = idx >> 15;
    int r = idx & 32767;
    int col = r >> 7, d = r & 127;
    float acc = 0.f;
    if (col < 200) {
      int j = col >> 2, h = col & 3;
      const float* wq = Wq + (size_t)l * 16384 + (size_t)d * 128 + 32 * h;
      const float* we = We + (size_t)l * NRAD * DDIM + j * DDIM + 32 * h;
#pragma unroll 8
      for (int u = 0; u < 32; ++u) acc = fmaf(wq[u], we[u], acc);
    }
    WQET[idx] = f2bf(acc);
  } else if (b < 1330) {  // embw: NTYPE*DDIM = 12800
    int idx = (b - 1280) * 256 + threadIdx.x;
    if (idx < NTYPE * DDIM) {
      int a = idx >> 7, c = idx & 127;
      const float* er = emb + (size_t)a * TEMB;
      float acc = bi[c];
#pragma unroll
      for (int t = 0; t < TEMB; ++t) acc = fmaf(er[t], Wi[t * DDIM + c], acc);
      embW[idx] = acc;
    }
  } else {  // deg zero
    int idx = (b - 1330) * 256 + threadIdx.x;
    if (idx < NN) deg[idx] = 0;
  }
}

// ---------------- init v2: x[n] = embW[at[n]] + pos[n]@W_init[32:35] ----------------

__global__ void k_init2(const float* __restrict__ pos, const int* __restrict__ at,
                        const float* __restrict__ embW, const float* __restrict__ W,
                        float* __restrict__ x) {
  int idx = blockIdx.x * blockDim.x + threadIdx.x;  // NN*32
  if (idx >= NN * 32) return;
  int n = idx >> 5, c4 = (idx & 31) << 2;
  float4 e = *(const float4*)&embW[(size_t)at[n] * DDIM + c4];
  float px = pos[n * 3 + 0], py = pos[n * 3 + 1], pz = pos[n * 3 + 2];
  float4 wx = *(const float4*)&W[(TEMB + 0) * DDIM + c4];
  float4 wy = *(const float4*)&W[(TEMB + 1) * DDIM + c4];
  float4 wz = *(const float4*)&W[(TEMB + 2) * DDIM + c4];
  float4 o;
  o.x = e.x + px * wx.x + py * wy.x + pz * wz.x;
  o.y = e.y + px * wx.y + py * wy.y + pz * wz.y;
  o.z = e.z + px * wx.z + py * wy.z + pz * wz.z;
  o.w = e.w + px * wx.w + py * wy.w + pz * wz.w;
  *(float4*)&x[(size_t)n * DDIM + c4] = o;
}

// ---------------- per-edge distance + degree histogram (fused) ----------------

__global__ void k_edge(const float* __restrict__ pos, const int* __restrict__ ei,
                       float* __restrict__ de, int* __restrict__ deg) {
  int e = blockIdx.x * blockDim.x + threadIdx.x;
  if (e >= NE) return;
  int s = ei[e], t = ei[NE + e];
  float dx = pos[s * 3 + 0] - pos[t * 3 + 0] + 1e-8f;
  float dy = pos[s * 3 + 1] - pos[t * 3 + 1] + 1e-8f;
  float dz = pos[s * 3 + 2] - pos[t * 3 + 2] + 1e-8f;
  de[e] = sqrtf(dx * dx + dy * dy + dz * dz);
  atomicAdd(&deg[t], 1);
}

// ---------------- CSR build: parallel 3-pass exclusive scan ----------------

__global__ void k_scan1(const int* __restrict__ deg, int* __restrict__ bsum) {
  __shared__ int red[256];
  int i = blockIdx.x * 256 + threadIdx.x;
  red[threadIdx.x] = (i < NN) ? deg[i] : 0;
  __syncthreads();
  for (int off = 128; off > 0; off >>= 1) {
    if (threadIdx.x < off) red[threadIdx.x] += red[threadIdx.x + off];
    __syncthreads();
  }
  if (threadIdx.x == 0) bsum[blockIdx.x] = red[0];
}

__global__ void k_scan2(int* __restrict__ bsum) {  // 1 block, 256 threads >= SCAN_N
  __shared__ int sh[256];
  int t = threadIdx.x;
  int v = (t < SCAN_N) ? bsum[t] : 0;
  sh[t] = v;
  __syncthreads();
  for (int off = 1; off < 256; off <<= 1) {
    int u = (t >= off) ? sh[t - off] : 0;
    __syncthreads();
    sh[t] += u;
    __syncthreads();
  }
  if (t < SCAN_N) bsum[t] = (t == 0) ? 0 : sh[t - 1];
}

__global__ void k_scan3(const int* __restrict__ deg, const int* __restrict__ bsum,
                        int* __restrict__ rowptr, int* __restrict__ cnear,
                        int* __restrict__ cfar) {
  __shared__ int sh[256];
  int t = threadIdx.x;
  int i = blockIdx.x * 256 + t;
  int v = (i < NN) ? deg[i] : 0;
  sh[t] = v;
  __syncthreads();
  for (int off = 1; off < 256; off <<= 1) {
    int u = (t >= off) ? sh[t - off] : 0;
    __syncthreads();
    sh[t] += u;
    __syncthreads();
  }
  int excl = bsum[blockIdx.x] + sh[t] - v;
  if (i < NN) {
    rowptr[i] = excl;
    cnear[i] = excl;
    cfar[i] = excl + v;  // = rowptr[i+1]
    if (i == NN - 1) rowptr[NN] = excl + v;
  }
}

// scatter into near-first / far-last segmented CSR, packed records {src, d}
__global__ void k_scatter(const int* __restrict__ ei, const float* __restrict__ de,
                          int* __restrict__ cnear, int* __restrict__ cfar,
                          int2* __restrict__ er) {
  int e = blockIdx.x * blockDim.x + threadIdx.x;
  if (e >= NE) return;
  int src = ei[e], dst = ei[NE + e];
  float d = de[e];
  int idx;
  if (d < CUTF)
    idx = atomicAdd(&cnear[dst], 1);
  else
    idx = atomicSub(&cfar[dst], 1) - 1;
  er[idx] = make_int2(src, __float_as_int(d));
}

// ---------------- fused QKV+QE GEMM: stage x once, 5 weight passes ----------------
// m=0: q -> qnb. m=1,2: k/v interleaved -> kvb[n][2d+{0,1}]. m=3,4: qe chunks.

__global__ __launch_bounds__(256) void k_qkv(
    const float* __restrict__ x, const ushort* __restrict__ Wt3,
    const ushort* __restrict__ WQET, ushort* __restrict__ qo,
    ushort* __restrict__ kvb, ushort* __restrict__ qe) {
  __shared__ ushort Al[128 * 128];
  __shared__ ushort Wl[128 * 128];
  const int tid = threadIdx.x;
  const int r0 = blockIdx.x * 128;

  for (int i = tid; i < 128 * 16; i += 256) {
    int r = i >> 4, g = i & 15;
    int gr = r0 + r;
    float4 f0 = {0, 0, 0, 0}, f1 = {0, 0, 0, 0};
    if (gr < NN) {
      f0 = *(const float4*)&x[(size_t)gr * 128 + g * 8];
      f1 = *(const float4*)&x[(size_t)gr * 128 + g * 8 + 4];
    }
    int gs = g ^ (r & 7);
    ushort4 u0 = {f2bf(f0.x), f2bf(f0.y), f2bf(f0.z), f2bf(f0.w)};
    ushort4 u1 = {f2bf(f1.x), f2bf(f1.y), f2bf(f1.z), f2bf(f1.w)};
    *(ushort4*)&Al[r * 128 + gs * 8] = u0;
    *(ushort4*)&Al[r * 128 + gs * 8 + 4] = u1;
  }

  const int w = tid >> 6, l = tid & 63;
  const int lg = l >> 4, lr = l & 15;

  for (int m = 0; m < 5; ++m) {
    const ushort* wsrc = (m < 3) ? (Wt3 + m * 16384) : (WQET + (m - 3) * 16384);
    for (int i = tid; i < 128 * 16; i += 256) {
      int c = i >> 4, g = i & 15;
      ushort4 w0 = *(const ushort4*)&wsrc[c * 128 + g * 8];
      ushort4 w1 = *(const ushort4*)&wsrc[c * 128 + g * 8 + 4];
      int gs = g ^ (c & 7);
      *(ushort4*)&Wl[c * 128 + gs * 8] = w0;
      *(ushort4*)&Wl[c * 128 + gs * 8 + 4] = w1;
    }
    __syncthreads();

    f32x4 acc[2][8];
#pragma unroll
    for (int rt = 0; rt < 2; ++rt)
#pragma unroll
      for (int ct = 0; ct < 8; ++ct) acc[rt][ct] = (f32x4){0.f, 0.f, 0.f, 0.f};

#pragma unroll
    for (int ks = 0; ks < 4; ++ks) {
      short8 af[2];
#pragma unroll
      for (int rt = 0; rt < 2; ++rt) {
        int arow = w * 32 + rt * 16 + lr;
        int ga = (ks * 4 + lg) ^ (arow & 7);
        af[rt] = *(const short8*)&Al[arow * 128 + ga * 8];
      }
#pragma unroll
      for (int ct = 0; ct < 8; ++ct) {
        int col = ct * 16 + lr;
        int gb = (ks * 4 + lg) ^ (col & 7);
        short8 bf = *(const short8*)&Wl[col * 128 + gb * 8];
#pragma unroll
        for (int rt = 0; rt < 2; ++rt)
          acc[rt][ct] = __builtin_amdgcn_mfma_f32_16x16x32_bf16(af[rt], bf, acc[rt][ct], 0, 0, 0);
      }
    }

    if (m == 0) {
#pragma unroll
      for (int rt = 0; rt < 2; ++rt)
#pragma unroll
        for (int ct = 0; ct < 8; ++ct) {
          int col = ct * 16 + lr;
#pragma unroll
          for (int r = 0; r < 4; ++r) {
            int row = r0 + w * 32 + rt * 16 + lg * 4 + r;
            if (row < NN) qo[(size_t)row * 128 + col] = f2bf(acc[rt][ct][r]);
          }
        }
    } else if (m < 3) {
      int off = m - 1;  // 0 for k, 1 for v
#pragma unroll
      for (int rt = 0; rt < 2; ++rt)
#pragma unroll
        for (int ct = 0; ct < 8; ++ct) {
          int col = ct * 16 + lr;
#pragma unroll
          for (int r = 0; r < 4; ++r) {
            int row = r0 + w * 32 + rt * 16 + lg * 4 + r;
            if (row < NN) kvb[(size_t)row * 256 + 2 * col + off] = f2bf(acc[rt][ct][r]);
          }
        }
    } else {
      int cb = (m - 3) * 128;
#pragma unroll
      for (int rt = 0; rt < 2; ++rt)
#pragma unroll
        for (int ct = 0; ct < 8; ++ct) {
          int col = cb + ct * 16 + lr;
          if (col < 200) {
#pragma unroll
            for (int r = 0; r < 4; ++r) {
              int row = r0 + w * 32 + rt * 16 + lg * 4 + r;
              if (row < NN) qe[(size_t)row * 200 + col] = f2bf(acc[rt][ct][r]);
            }
          }
        }
    }
    __syncthreads();
  }
}

// ---------------- general GEMM: out = act(A@W + bias) (+resid) (+fused LN)
// EXTK: additionally accumulate arbn[NN,200] @ WW[256,128] (2 chunked passes).

template <bool BIAS, bool GELU, bool RESID, bool LNF, bool EXTK>
__global__ __launch_bounds__(256) void k_gemm2(
    const ushort* __restrict__ A, const ushort* __restrict__ Wt,
    const float* __restrict__ bias, const float* __restrict__ resid,
    void* __restrict__ outp, const float* __restrict__ lng,
    const float* __restrict__ lnb, ushort* __restrict__ lnout,
    const ushort* __restrict__ arbn, const ushort* __restrict__ WW) {
  __shared__ ushort Al[128 * 128];
  __shared__ ushort Wl[128 * 128];
  const int tid = threadIdx.x;
  const int r0 = blockIdx.x * 128;

  for (int i = tid; i < 128 * 16; i += 256) {
    int r = i >> 4, g = i & 15;
    int gr = r0 + r;
    ushort4 v0 = {0, 0, 0, 0}, v1 = {0, 0, 0, 0};
    if (gr < NN) {
      v0 = *(const ushort4*)&A[(size_t)gr * 128 + g * 8];
      v1 = *(const ushort4*)&A[(size_t)gr * 128 + g * 8 + 4];
    }
    int gs = g ^ (r & 7);
    *(ushort4*)&Al[r * 128 + gs * 8] = v0;
    *(ushort4*)&Al[r * 128 + gs * 8 + 4] = v1;
  }
  for (int i = tid; i < 128 * 16; i += 256) {
    int c = i >> 4, g = i & 15;
    ushort4 w0 = *(const ushort4*)&Wt[c * 128 + g * 8];
    ushort4 w1 = *(const ushort4*)&Wt[c * 128 + g * 8 + 4];
    int gs = g ^ (c & 7);
    *(ushort4*)&Wl[c * 128 + gs * 8] = w0;
    *(ushort4*)&Wl[c * 128 + gs * 8 + 4] = w1;
  }
  __syncthreads();

  const int w = tid >> 6, l = tid & 63;
  const int lg = l >> 4, lr = l & 15;
  f32x4 acc[2][8];
#pragma unroll
  for (int rt = 0; rt < 2; ++rt)
#pragma unroll
    for (int ct = 0; ct < 8; ++ct) acc[rt][ct] = (f32x4){0.f, 0.f, 0.f, 0.f};

#pragma unroll
  for (int ks = 0; ks < 4; ++ks) {
    short8 af[2];
#pragma unroll
    for (int rt = 0; rt < 2; ++rt) {
      int arow = w * 32 + rt * 16 + lr;
      int ga = (ks * 4 + lg) ^ (arow & 7);
      af[rt] = *(const short8*)&Al[arow * 128 + ga * 8];
    }
#pragma unroll
    for (int ct = 0; ct < 8; ++ct) {
      int col = ct * 16 + lr;
      int gb = (ks * 4 + lg) ^ (col & 7);
      short8 bf = *(const short8*)&Wl[col * 128 + gb * 8];
#pragma unroll
      for (int rt = 0; rt < 2; ++rt)
        acc[rt][ct] = __builtin_amdgcn_mfma_f32_16x16x32_bf16(af[rt], bf, acc[rt][ct], 0, 0, 0);
    }
  }

  if (EXTK) {
    for (int q = 0; q < 2; ++q) {
      __syncthreads();  // prior mfma reads done
      for (int i = tid; i < 128 * 16; i += 256) {
        int r = i >> 4, g = i & 15;
        int gr = r0 + r;
        ushort4 v0 = {0, 0, 0, 0}, v1 = {0, 0, 0, 0};
        if (gr < NN && (q == 0 || g < 9)) {
          v0 = *(const ushort4*)&arbn[(size_t)gr * 200 + q * 128 + g * 8];
          v1 = *(const ushort4*)&arbn[(size_t)gr * 200 + q * 128 + g * 8 + 4];
        }
        int gs = g ^ (r & 7);
        *(ushort4*)&Al[r * 128 + gs * 8] = v0;
        *(ushort4*)&Al[r * 128 + gs * 8 + 4] = v1;
      }
      for (int i = tid; i < 128 * 16; i += 256) {
        int c = i >> 4, g = i & 15;
        ushort4 w0 = *(const ushort4*)&WW[c * 256 + q * 128 + g * 8];
        ushort4 w1 = *(const ushort4*)&WW[c * 256 + q * 128 + g * 8 + 4];
        int gs = g ^ (c & 7);
        *(ushort4*)&Wl[c * 128 + gs * 8] = w0;
        *(ushort4*)&Wl[c * 128 + gs * 8 + 4] = w1;
      }
      __syncthreads();
#pragma unroll
      for (int ks = 0; ks < 4; ++ks) {
        short8 af[2];
#pragma unroll
        for (int rt = 0; rt < 2; ++rt) {
          int arow = w * 32 + rt * 16 + lr;
          int ga = (ks * 4 + lg) ^ (arow & 7);
          af[rt] = *(const short8*)&Al[arow * 128 + ga * 8];
        }
#pragma unroll
        for (int ct = 0; ct < 8; ++ct) {
          int col = ct * 16 + lr;
          int gb = (ks * 4 + lg) ^ (col & 7);
          short8 bf = *(const short8*)&Wl[col * 128 + gb * 8];
#pragma unroll
          for (int rt = 0; rt < 2; ++rt)
            acc[rt][ct] = __builtin_amdgcn_mfma_f32_16x16x32_bf16(af[rt], bf, acc[rt][ct], 0, 0, 0);
        }
      }
    }
  }

#pragma unroll
  for (int rt = 0; rt < 2; ++rt)
#pragma unroll
    for (int r = 0; r < 4; ++r) {
      int row = r0 + w * 32 + rt * 16 + lg * 4 + r;
      bool ok = row < NN;  // uniform across the 16-lane lr group
      float v[8];
#pragma unroll
      for (int ct = 0; ct < 8; ++ct) {
        int col = ct * 16 + lr;
        float vv = acc[rt][ct][r];
        if (BIAS) vv += bias[col];
        if (GELU) vv = gelu_tanh(vv);
        if (RESID) vv += ok ? resid[(size_t)row * 128 + col] : 0.f;
        v[ct] = vv;
      }
      if (RESID || LNF) {
        if (ok)
#pragma unroll
          for (int ct = 0; ct < 8; ++ct)
            ((float*)outp)[(size_t)row * 128 + ct * 16 + lr] = v[ct];
      } else {
        if (ok)
#pragma unroll
          for (int ct = 0; ct < 8; ++ct)
            ((ushort*)outp)[(size_t)row * 128 + ct * 16 + lr] = f2bf(v[ct]);
      }
      if (LNF) {
        float s = 0.f, ss = 0.f;
#pragma unroll
        for (int ct = 0; ct < 8; ++ct) {
          s += v[ct];
          ss = fmaf(v[ct], v[ct], ss);
        }
#pragma unroll
        for (int msk = 8; msk >= 1; msk >>= 1) {
          s += __shfl_xor(s, msk);
          ss += __shfl_xor(ss, msk);
        }
        float mean = s * (1.0f / DDIM);
        float var = ss * (1.0f / DDIM) - mean * mean;
        float inv = rsqrtf(var + 1e-5f);
        if (ok)
#pragma unroll
          for (int ct = 0; ct < 8; ++ct) {
            int col = ct * 16 + lr;
            lnout[(size_t)row * 128 + col] =
                f2bf((v[ct] - mean) * inv * lng[col] + lnb[col]);
          }
      }
    }
}

// ---------------- fused attention v8: interleaved KV, near/far split ----------------

__device__ __forceinline__ float rbf_fill(float d, int j) {
  const float step = CUTF / (NRAD - 1);
  const float gamma = (NRAD / CUTF) * (NRAD / CUTF);
  float mu = j * step;
  float dm = d - mu;
  float env = 0.5f * (__cosf(PI_F * d / CUTF) + 1.0f);
  return __expf(-gamma * dm * dm) * env;
}

#define SCALE_QK 0.17677669529663687f

__global__ __launch_bounds__(256) void k_attn8(
    const ushort* __restrict__ qnb, const ushort* __restrict__ kvb,
    ushort* __restrict__ qe, const int2* __restrict__ er,
    const int* __restrict__ rowptr, const int* __restrict__ nearend,
    ushort* __restrict__ msgb) {
  __shared__ float qel[4][64][4];   // [wave][j][head]
  __shared__ float rbl[4][64];
  __shared__ float aml[4][128];     // far-accumulator remap buffer (per wave)
  const int tid = threadIdx.x;

  const int w = tid >> 6, t = tid & 63;
  const int n = blockIdx.x * 4 + w;
  const int h = t >> 4;       // near-layout head (16-lane groups)
  const int j0 = t & 15;
  const int hw = t >> 5;      // half-wave id (far loop)
  const int c = t & 31;       // lane in half; owns dims 4c..4c+3 (far loop)
  uint qu = *(const uint*)&qnb[(size_t)n * DDIM + 2 * t];
  const float q0 = bfl(qu), q1 = bfh(qu);
  uint2 qp = *(const uint2*)&qnb[(size_t)n * DDIM + 4 * c];
  const float fq0 = bfl(qp.x), fq1 = bfh(qp.x), fq2 = bfl(qp.y), fq3 = bfh(qp.y);
  if (t < NRAD) {
    ushort4 qv = *(const ushort4*)&qe[(size_t)n * 200 + 4 * t];
    qel[w][t][0] = bfl(qv.x);
    qel[w][t][1] = bfl(qv.y);
    qel[w][t][2] = bfl(qv.z);
    qel[w][t][3] = bfl(qv.w);
  } else {
    qel[w][t][0] = 0.f; qel[w][t][1] = 0.f; qel[w][t][2] = 0.f; qel[w][t][3] = 0.f;
  }
  const int start = rowptr[n], nend = nearend[n], end = rowptr[n + 1];

  float s = 0.f, a0 = 0.f, a1 = 0.f;
  float4 arb = {0.f, 0.f, 0.f, 0.f};

  // ---- near loop (radial features active), full wave per edge ----
  // lane t owns dims 2t,2t+1: kv pairs at kvb[src*256 + 4t .. 4t+3]
  for (int cb = start; cb < nend; cb += 64) {
    int cnt = min(nend - cb, 64);
    int2 e_t = make_int2(0, 0);
    if (t < cnt) e_t = er[cb + t];
    for (int i = 0; i < cnt; ++i) {
      int src = __shfl(e_t.x, i);
      float dd = __shfl(__int_as_float(e_t.y), i);
      uint2 kv = *(const uint2*)&kvb[(size_t)src * 256 + 4 * t];
      float pr = q0 * bfl(kv.x) + q1 * bfl(kv.y);
      float rb = (t < NRAD) ? rbf_fill(dd, t) : 0.f;
      rbl[w][t] = rb;
      pr = fmaf(rbl[w][j0], qel[w][j0][h], pr);
      pr = fmaf(rbl[w][j0 + 16], qel[w][j0 + 16][h], pr);
      pr = fmaf(rbl[w][j0 + 32], qel[w][j0 + 32][h], pr);
      pr = fmaf(rbl[w][j0 + 48], qel[w][j0 + 48][h], pr);
      pr = red16(pr);
      float ae = __expf(fminf(pr * SCALE_QK, 60.f));
      s += ae;
      a0 = fmaf(ae, bfh(kv.x), a0);
      a1 = fmaf(ae, bfh(kv.y), a1);
      float aex = __shfl(ae, 0);
      float aey = __shfl(ae, 16);
      float aez = __shfl(ae, 32);
      float aew = __shfl(ae, 48);
      arb.x = fmaf(rb, aex, arb.x);
      arb.y = fmaf(rb, aey, arb.y);
      arb.z = fmaf(rb, aez, arb.z);
      arb.w = fmaf(rb, aew, arb.w);
    }
  }

  // ---- far loop: 2 edges per wave (one per 32-lane half), 4 dims/lane ----
  // lane c owns dims 4c..4c+3: one uint4 = {k0v0,k1v1,k2v2,k3v3}
  float sf = 0.f, af0 = 0.f, af1 = 0.f, af2 = 0.f, af3 = 0.f;
  for (int cb = nend; cb < end; cb += 64) {
    int cnt = min(end - cb, 64);
    int src_t = 0;
    if (t < cnt) src_t = er[cb + t].x;
    for (int i = hw; i < cnt; i += 2) {
      int src = __shfl(src_t, i);
      uint4 kv = *(const uint4*)&kvb[(size_t)src * 256 + 8 * c];
      float pr = fq0 * bfl(kv.x) + fq1 * bfl(kv.y);
      pr = fmaf(fq2, bfl(kv.z), pr);
      pr = fmaf(fq3, bfl(kv.w), pr);
      pr = red8(pr);
      float ae = __expf(fminf(pr * SCALE_QK, 60.f));
      sf += ae;
      af0 = fmaf(ae, bfh(kv.x), af0);
      af1 = fmaf(ae, bfh(kv.y), af1);
      af2 = fmaf(ae, bfh(kv.z), af2);
      af3 = fmaf(ae, bfh(kv.w), af3);
    }
  }
  // combine the two halves (same dims, different edge subsets)
  sf += __shfl_xor(sf, 32);
  af0 += __shfl_xor(af0, 32);
  af1 += __shfl_xor(af1, 32);
  af2 += __shfl_xor(af2, 32);
  af3 += __shfl_xor(af3, 32);
  // remap far accumulators (4 dims/lane) into near layout (2 dims/lane) via LDS
  aml[w][4 * c + 0] = af0;
  aml[w][4 * c + 1] = af1;
  aml[w][4 * c + 2] = af2;
  aml[w][4 * c + 3] = af3;
  a0 += aml[w][2 * t];
  a1 += aml[w][2 * t + 1];

  // ---- finalize: normalize; store a_norm (msgb) and arbn (into qe buffer) ----
  float4 s4;
  s4.x = __shfl(s, 0) + __shfl(sf, 0);
  s4.y = __shfl(s, 16) + __shfl(sf, 8);
  s4.z = __shfl(s, 32) + __shfl(sf, 16);
  s4.w = __shfl(s, 48) + __shfl(sf, 24);
  float4 inv4 = {1.f / (s4.x + 1e-9f), 1.f / (s4.y + 1e-9f),
                 1.f / (s4.z + 1e-9f), 1.f / (s4.w + 1e-9f)};
  float invo = (h == 0) ? inv4.x : (h == 1) ? inv4.y : (h == 2) ? inv4.z : inv4.w;
  if (t < NRAD) {
    ushort4 o = {f2bf(arb.x * inv4.x), f2bf(arb.y * inv4.y),
                 f2bf(arb.z * inv4.z), f2bf(arb.w * inv4.w)};
    *(ushort4*)&qe[(size_t)n * 200 + 4 * t] = o;
  }
  a0 *= invo;
  a1 *= invo;
  uint pk = (uint)f2bf(a0) | ((uint)f2bf(a1) << 16);
  *(uint*)&msgb[(size_t)n * DDIM + 2 * t] = pk;
}

// ---------------- graph sum (batch is sorted): 32 nodes/block, boundary atomics ----------------

#define GS_NODES 32
__global__ void k_graphsum(const float* __restrict__ x, const int* __restrict__ batch,
                           float* __restrict__ g) {
  int t = threadIdx.x;  // 128 dims
  int n0 = blockIdx.x * GS_NODES;
  int nend = n0 + GS_NODES;
  if (nend > NN) nend = NN;
  if (n0 >= NN) return;
  float acc = 0.f;
  int cur = batch[n0];
  for (int n = n0; n < nend; ++n) {
    int bb = batch[n];
    if (bb != cur) {
      atomicAdd(&g[(size_t)cur * DDIM + t], acc);
      acc = 0.f;
      cur = bb;
    }
    acc += x[(size_t)n * DDIM + t];
  }
  atomicAdd(&g[(size_t)cur * DDIM + t], acc);
}

// ---------------- output projection ----------------

__global__ void k_out(const float* __restrict__ g, const float* __restrict__ W,
                      const float* __restrict__ b, float* __restrict__ out) {
  int idx = blockIdx.x * blockDim.x + threadIdx.x;
  if (idx >= NGRAPH * DOUT) return;
  int r = idx / DOUT, c = idx % DOUT;
  float acc = b[c];
#pragma unroll 8
  for (int k = 0; k < DDIM; ++k) acc = fmaf(g[r * DDIM + k], W[k * DOUT + c], acc);
  out[idx] = acc;
}

// ---------------- launch ----------------

extern "C" void kernel_launch(void* const* d_in, const int* in_sizes, int n_in,
                              void* d_out, int out_size, void* d_ws, size_t ws_size,
                              hipStream_t stream) {
  const float* pos = (const float*)d_in[0];
  const int* at = (const int*)d_in[1];
  const int* ei = (const int*)d_in[2];
  const int* batch = (const int*)d_in[3];
  const float* emb = (const float*)d_in[4];
  const float* W_init = (const float*)d_in[5];
  const float* b_init = (const float*)d_in[6];
  const float* Wq = (const float*)d_in[7];
  const float* Wk = (const float*)d_in[8];
  const float* Wv = (const float*)d_in[9];
  const float* We = (const float*)d_in[10];
  const float* Wo = (const float*)d_in[11];
  const float* Wm1 = (const float*)d_in[12];
  const float* bm1 = (const float*)d_in[13];
  const float* Wm2 = (const float*)d_in[14];
  const float* bm2 = (const float*)d_in[15];
  const float* ln_g = (const float*)d_in[16];
  const float* ln_b = (const float*)d_in[17];
  const float* W_out = (const float*)d_in[18];
  const float* b_out = (const float*)d_in[19];
  float* out = (float*)d_out;

  const size_t ND = (size_t)NN * DDIM;  // 6.4M
  float* x = (float*)d_ws;              // f32 ND
  ushort* qnb = (ushort*)(x + ND);      // bf16 ND (alias hb)
  ushort* kvb = qnb + ND;               // bf16 2*ND interleaved k/v (alias h2 first half)
  ushort* msgb = kvb + 2 * ND;          // bf16 ND
  ushort* qe = msgb + ND;               // bf16 NN*200 (doubles as arbn)
  ushort* Wtb = qe + (size_t)NN * 200;  // bf16 12*16384
  ushort* WW = Wtb + 12 * 16384;        // bf16 2*128*256 (WeWo)
  ushort* WQET = WW + 2 * 32768;        // bf16 2*256*128 (WqWe^T)
  float* embW = (float*)(WQET + 2 * 32768);  // f32 NTYPE*DDIM
  float* de = embW + NTYPE * DDIM;      // f32 NE
  int* deg = (int*)(de + NE);
  int* cnear = deg + NN;
  int* cfar = cnear + NN;
  int* rowptr = cfar + NN;
  int2* er = (int2*)(rowptr + NN + 64);  // NE int2
  float* gb = (float*)(er + NE);         // NG*DDIM
  int* bsum = (int*)(gb + NGRAPH * DDIM);  // SCAN_N
  // total ~96.6 MB

  ushort* hb = qnb;
  ushort* h2 = kvb;  // kvb dead after attn within a layer; reused as h2

  k_pre<<<1526, 256, 0, stream>>>(Wq, Wk, Wv, Wo, Wm1, Wm2, We, emb, W_init, b_init,
                                  Wtb, WW, WQET, embW, deg);
  k_init2<<<(NN * 32 + 255) / 256, 256, 0, stream>>>(pos, at, embW, W_init, x);
  k_edge<<<(NE + 255) / 256, 256, 0, stream>>>(pos, ei, de, deg);
  k_scan1<<<SCAN_N, 256, 0, stream>>>(deg, bsum);
  k_scan2<<<1, 256, 0, stream>>>(bsum);
  k_scan3<<<SCAN_N, 256, 0, stream>>>(deg, bsum, rowptr, cnear, cfar);
  k_scatter<<<(NE + 255) / 256, 256, 0, stream>>>(ei, de, cnear, cfar, er);

  const int gg = (NN + 127) / 128;  // 391
  for (int l = 0; l < 2; ++l) {
    const ushort* Wt_l = Wtb + (size_t)l * 6 * 16384;
    const ushort* WQET_l = WQET + (size_t)l * 32768;
    const ushort* WW_l = WW + (size_t)l * 32768;

    k_qkv<<<gg, 256, 0, stream>>>(x, Wt_l, WQET_l, qnb, kvb, qe);
    k_attn8<<<NN / 4, 256, 0, stream>>>(qnb, kvb, qe, er, rowptr, cnear, msgb);

    // x += msg@Wo + arbn@WeWo, fused layernorm -> hb
    k_gemm2<false, false, true, true, true><<<gg, 256, 0, stream>>>(
        msgb, Wt_l + 3 * 16384, nullptr, x, x,
        ln_g + (size_t)l * DDIM, ln_b + (size_t)l * DDIM, hb, qe, WW_l);
    // h2 = gelu(hb@Wm1 + bm1)
    k_gemm2<true, true, false, false, false><<<gg, 256, 0, stream>>>(
        hb, Wt_l + 4 * 16384, bm1 + (size_t)l * DDIM, nullptr, h2,
        nullptr, nullptr, nullptr, nullptr, nullptr);
    // x += h2@Wm2 + bm2
    k_gemm2<true, false, true, false, false><<<gg, 256, 0, stream>>>(
        h2, Wt_l + 5 * 16384, bm2 + (size_t)l * DDIM, x, x,
        nullptr, nullptr, nullptr, nullptr, nullptr);
  }

  k_fill_f<<<(NGRAPH * DDIM + 255) / 256, 256, 0, stream>>>(gb, 0.f, NGRAPH * DDIM);
  k_graphsum<<<(NN + GS_NODES - 1) / GS_NODES, 128, 0, stream>>>(x, batch, gb);
  k_out<<<(NGRAPH * DOUT + 255) / 256, 256, 0, stream>>>(gb, W_out, b_out, out);
}

// Round 16
// 349.015 us; speedup vs baseline: 1.4206x; 1.0096x over previous
//
#include <hip/hip_runtime.h>
#include <math.h>

#define NN 50000
#define NE 400000
#define DDIM 128
#define NHEAD 4
#define NRAD 50
#define NGRAPH 100
#define NTYPE 100
#define TEMB 32
#define DOUT 512
#define CUTF 6.0f
#define PI_F 3.14159265358979323846f

#define SCAN_N ((NN + 255) / 256)  // 196 scan blocks

typedef unsigned int uint;
typedef unsigned short ushort;
typedef __attribute__((ext_vector_type(8))) short short8;
typedef __attribute__((ext_vector_type(4))) float f32x4;

// ---------------- helpers ----------------

__device__ __forceinline__ float gelu_tanh(float v) {
  float u = 0.7978845608028654f * (v + 0.044715f * v * v * v);
  return 0.5f * v * (1.0f + tanhf(u));
}

__device__ __forceinline__ ushort f2bf(float f) {  // RNE
  uint u = __float_as_uint(f);
  uint r = (u + 0x7fffu + ((u >> 16) & 1u)) >> 16;
  return (ushort)r;
}
__device__ __forceinline__ float bfl(uint u) { return __uint_as_float(u << 16); }
__device__ __forceinline__ float bfh(uint u) { return __uint_as_float(u & 0xffff0000u); }

// DPP sum reductions on the VALU (no ds_bpermute).
__device__ __forceinline__ float red16(float v) {
  v += __int_as_float(__builtin_amdgcn_update_dpp(0, __float_as_int(v), 0xB1, 0xF, 0xF, true));
  v += __int_as_float(__builtin_amdgcn_update_dpp(0, __float_as_int(v), 0x4E, 0xF, 0xF, true));
  v += __int_as_float(__builtin_amdgcn_update_dpp(0, __float_as_int(v), 0x141, 0xF, 0xF, true));
  v += __int_as_float(__builtin_amdgcn_update_dpp(0, __float_as_int(v), 0x140, 0xF, 0xF, true));
  return v;
}
__device__ __forceinline__ float red8(float v) {
  v += __int_as_float(__builtin_amdgcn_update_dpp(0, __float_as_int(v), 0xB1, 0xF, 0xF, true));
  v += __int_as_float(__builtin_amdgcn_update_dpp(0, __float_as_int(v), 0x4E, 0xF, 0xF, true));
  v += __int_as_float(__builtin_amdgcn_update_dpp(0, __float_as_int(v), 0x141, 0xF, 0xF, true));
  return v;
}

__global__ void k_fill_f(float* p, float v, int n) {
  int i = blockIdx.x * blockDim.x + threadIdx.x;
  if (i < n) p[i] = v;
}

// ---------------- fused prologue: wconv | wewo | wqe | embw | deg=0 ----------------

__global__ void k_pre(const float* __restrict__ Wq, const float* __restrict__ Wk,
                      const float* __restrict__ Wv, const float* __restrict__ Wo,
                      const float* __restrict__ Wm1, const float* __restrict__ Wm2,
                      const float* __restrict__ We, const float* __restrict__ emb,
                      const float* __restrict__ Wi, const float* __restrict__ bi,
                      ushort* __restrict__ Wtb, ushort* __restrict__ WW,
                      ushort* __restrict__ WQET, float* __restrict__ embW,
                      int* __restrict__ deg) {
  int b = blockIdx.x;
  if (b < 768) {  // wconv: 12*16384
    int idx = b * 256 + threadIdx.x;
    int m = idx >> 14;
    int r = idx & 16383;
    int c = r >> 7, k = r & 127;
    int l = m / 6, fam = m % 6;
    const float* src = fam == 0 ? Wq : fam == 1 ? Wk : fam == 2 ? Wv
                     : fam == 3 ? Wo : fam == 4 ? Wm1 : Wm2;
    Wtb[idx] = f2bf(src[l * 16384 + k * 128 + c]);
  } else if (b < 1024) {  // wewo: 2*128*256
    int idx = (b - 768) * 256 + threadIdx.x;
    int l = idx >> 15;
    int r = idx & 32767;
    int c = r >> 8, k = r & 255;
    float acc = 0.f;
    if (k < 200) {
      int j = k >> 2, h = k & 3;
      const float* we = We + (size_t)l * NRAD * DDIM + j * DDIM + 32 * h;
      const float* wo = Wo + (size_t)l * DDIM * DDIM + (size_t)(32 * h) * DDIM + c;
#pragma unroll 8
      for (int dk = 0; dk < 32; ++dk) acc = fmaf(we[dk], wo[(size_t)dk * DDIM], acc);
    }
    WW[idx] = f2bf(acc);
  } else if (b < 1280) {  // wqe: 2*256*128
    int idx = (b - 1024) * 256 + threadIdx.x;
    int l = idx >> 15;
    int r = idx & 32767;
    int col = r >> 7, d = r & 127;
    float acc = 0.f;
    if (col < 200) {
      int j = col >> 2, h = col & 3;
      const float* wq = Wq + (size_t)l * 16384 + (size_t)d * 128 + 32 * h;
      const float* we = We + (size_t)l * NRAD * DDIM + j * DDIM + 32 * h;
#pragma unroll 8
      for (int u = 0; u < 32; ++u) acc = fmaf(wq[u], we[u], acc);
    }
    WQET[idx] = f2bf(acc);
  } else if (b < 1330) {  // embw: NTYPE*DDIM = 12800
    int idx = (b - 1280) * 256 + threadIdx.x;
    if (idx < NTYPE * DDIM) {
      int a = idx >> 7, c = idx & 127;
      const float* er = emb + (size_t)a * TEMB;
      float acc = bi[c];
#pragma unroll
      for (int t = 0; t < TEMB; ++t) acc = fmaf(er[t], Wi[t * DDIM + c], acc);
      embW[idx] = acc;
    }
  } else {  // deg zero
    int idx = (b - 1330) * 256 + threadIdx.x;
    if (idx < NN) deg[idx] = 0;
  }
}

// ---------------- init v2: x[n] = embW[at[n]] + pos[n]@W_init[32:35] ----------------

__global__ void k_init2(const float* __restrict__ pos, const int* __restrict__ at,
                        const float* __restrict__ embW, const float* __restrict__ W,
                        float* __restrict__ x) {
  int idx = blockIdx.x * blockDim.x + threadIdx.x;  // NN*32
  if (idx >= NN * 32) return;
  int n = idx >> 5, c4 = (idx & 31) << 2;
  float4 e = *(const float4*)&embW[(size_t)at[n] * DDIM + c4];
  float px = pos[n * 3 + 0], py = pos[n * 3 + 1], pz = pos[n * 3 + 2];
  float4 wx = *(const float4*)&W[(TEMB + 0) * DDIM + c4];
  float4 wy = *(const float4*)&W[(TEMB + 1) * DDIM + c4];
  float4 wz = *(const float4*)&W[(TEMB + 2) * DDIM + c4];
  float4 o;
  o.x = e.x + px * wx.x + py * wy.x + pz * wz.x;
  o.y = e.y + px * wx.y + py * wy.y + pz * wz.y;
  o.z = e.z + px * wx.z + py * wy.z + pz * wz.z;
  o.w = e.w + px * wx.w + py * wy.w + pz * wz.w;
  *(float4*)&x[(size_t)n * DDIM + c4] = o;
}

// ---------------- per-edge distance + degree histogram (fused) ----------------

__global__ void k_edge(const float* __restrict__ pos, const int* __restrict__ ei,
                       float* __restrict__ de, int* __restrict__ deg) {
  int e = blockIdx.x * blockDim.x + threadIdx.x;
  if (e >= NE) return;
  int s = ei[e], t = ei[NE + e];
  float dx = pos[s * 3 + 0] - pos[t * 3 + 0] + 1e-8f;
  float dy = pos[s * 3 + 1] - pos[t * 3 + 1] + 1e-8f;
  float dz = pos[s * 3 + 2] - pos[t * 3 + 2] + 1e-8f;
  de[e] = sqrtf(dx * dx + dy * dy + dz * dz);
  atomicAdd(&deg[t], 1);
}

// ---------------- CSR build: parallel 3-pass exclusive scan ----------------

__global__ void k_scan1(const int* __restrict__ deg, int* __restrict__ bsum) {
  __shared__ int red[256];
  int i = blockIdx.x * 256 + threadIdx.x;
  red[threadIdx.x] = (i < NN) ? deg[i] : 0;
  __syncthreads();
  for (int off = 128; off > 0; off >>= 1) {
    if (threadIdx.x < off) red[threadIdx.x] += red[threadIdx.x + off];
    __syncthreads();
  }
  if (threadIdx.x == 0) bsum[blockIdx.x] = red[0];
}

__global__ void k_scan2(int* __restrict__ bsum) {  // 1 block, 256 threads >= SCAN_N
  __shared__ int sh[256];
  int t = threadIdx.x;
  int v = (t < SCAN_N) ? bsum[t] : 0;
  sh[t] = v;
  __syncthreads();
  for (int off = 1; off < 256; off <<= 1) {
    int u = (t >= off) ? sh[t - off] : 0;
    __syncthreads();
    sh[t] += u;
    __syncthreads();
  }
  if (t < SCAN_N) bsum[t] = (t == 0) ? 0 : sh[t - 1];
}

__global__ void k_scan3(const int* __restrict__ deg, const int* __restrict__ bsum,
                        int* __restrict__ rowptr, int* __restrict__ cnear,
                        int* __restrict__ cfar) {
  __shared__ int sh[256];
  int t = threadIdx.x;
  int i = blockIdx.x * 256 + t;
  int v = (i < NN) ? deg[i] : 0;
  sh[t] = v;
  __syncthreads();
  for (int off = 1; off < 256; off <<= 1) {
    int u = (t >= off) ? sh[t - off] : 0;
    __syncthreads();
    sh[t] += u;
    __syncthreads();
  }
  int excl = bsum[blockIdx.x] + sh[t] - v;
  if (i < NN) {
    rowptr[i] = excl;
    cnear[i] = excl;
    cfar[i] = excl + v;  // = rowptr[i+1]
    if (i == NN - 1) rowptr[NN] = excl + v;
  }
}

// scatter into near-first / far-last segmented CSR, packed records {src, d}
__global__ void k_scatter(const int* __restrict__ ei, const float* __restrict__ de,
                          int* __restrict__ cnear, int* __restrict__ cfar,
                          int2* __restrict__ er) {
  int e = blockIdx.x * blockDim.x + threadIdx.x;
  if (e >= NE) return;
  int src = ei[e], dst = ei[NE + e];
  float d = de[e];
  int idx;
  if (d < CUTF)
    idx = atomicAdd(&cnear[dst], 1);
  else
    idx = atomicSub(&cfar[dst], 1) - 1;
  er[idx] = make_int2(src, __float_as_int(d));
}

// ---------------- fused QKV+QE GEMM: stage x once, 5 weight passes ----------------

__global__ __launch_bounds__(256) void k_qkv(
    const float* __restrict__ x, const ushort* __restrict__ Wt3,
    const ushort* __restrict__ WQET, ushort* __restrict__ qo,
    ushort* __restrict__ kvb, ushort* __restrict__ qe) {
  __shared__ ushort Al[128 * 128];
  __shared__ ushort Wl[128 * 128];
  const int tid = threadIdx.x;
  const int r0 = blockIdx.x * 128;

  for (int i = tid; i < 128 * 16; i += 256) {
    int r = i >> 4, g = i & 15;
    int gr = r0 + r;
    float4 f0 = {0, 0, 0, 0}, f1 = {0, 0, 0, 0};
    if (gr < NN) {
      f0 = *(const float4*)&x[(size_t)gr * 128 + g * 8];
      f1 = *(const float4*)&x[(size_t)gr * 128 + g * 8 + 4];
    }
    int gs = g ^ (r & 7);
    ushort4 u0 = {f2bf(f0.x), f2bf(f0.y), f2bf(f0.z), f2bf(f0.w)};
    ushort4 u1 = {f2bf(f1.x), f2bf(f1.y), f2bf(f1.z), f2bf(f1.w)};
    *(ushort4*)&Al[r * 128 + gs * 8] = u0;
    *(ushort4*)&Al[r * 128 + gs * 8 + 4] = u1;
  }

  const int w = tid >> 6, l = tid & 63;
  const int lg = l >> 4, lr = l & 15;

  for (int m = 0; m < 5; ++m) {
    const ushort* wsrc = (m < 3) ? (Wt3 + m * 16384) : (WQET + (m - 3) * 16384);
    for (int i = tid; i < 128 * 16; i += 256) {
      int c = i >> 4, g = i & 15;
      ushort4 w0 = *(const ushort4*)&wsrc[c * 128 + g * 8];
      ushort4 w1 = *(const ushort4*)&wsrc[c * 128 + g * 8 + 4];
      int gs = g ^ (c & 7);
      *(ushort4*)&Wl[c * 128 + gs * 8] = w0;
      *(ushort4*)&Wl[c * 128 + gs * 8 + 4] = w1;
    }
    __syncthreads();

    f32x4 acc[2][8];
#pragma unroll
    for (int rt = 0; rt < 2; ++rt)
#pragma unroll
      for (int ct = 0; ct < 8; ++ct) acc[rt][ct] = (f32x4){0.f, 0.f, 0.f, 0.f};

#pragma unroll
    for (int ks = 0; ks < 4; ++ks) {
      short8 af[2];
#pragma unroll
      for (int rt = 0; rt < 2; ++rt) {
        int arow = w * 32 + rt * 16 + lr;
        int ga = (ks * 4 + lg) ^ (arow & 7);
        af[rt] = *(const short8*)&Al[arow * 128 + ga * 8];
      }
#pragma unroll
      for (int ct = 0; ct < 8; ++ct) {
        int col = ct * 16 + lr;
        int gb = (ks * 4 + lg) ^ (col & 7);
        short8 bf = *(const short8*)&Wl[col * 128 + gb * 8];
#pragma unroll
        for (int rt = 0; rt < 2; ++rt)
          acc[rt][ct] = __builtin_amdgcn_mfma_f32_16x16x32_bf16(af[rt], bf, acc[rt][ct], 0, 0, 0);
      }
    }

    if (m == 0) {
#pragma unroll
      for (int rt = 0; rt < 2; ++rt)
#pragma unroll
        for (int ct = 0; ct < 8; ++ct) {
          int col = ct * 16 + lr;
#pragma unroll
          for (int r = 0; r < 4; ++r) {
            int row = r0 + w * 32 + rt * 16 + lg * 4 + r;
            if (row < NN) qo[(size_t)row * 128 + col] = f2bf(acc[rt][ct][r]);
          }
        }
    } else if (m < 3) {
      int off = m - 1;  // 0 for k, 1 for v
#pragma unroll
      for (int rt = 0; rt < 2; ++rt)
#pragma unroll
        for (int ct = 0; ct < 8; ++ct) {
          int col = ct * 16 + lr;
#pragma unroll
          for (int r = 0; r < 4; ++r) {
            int row = r0 + w * 32 + rt * 16 + lg * 4 + r;
            if (row < NN) kvb[(size_t)row * 256 + 2 * col + off] = f2bf(acc[rt][ct][r]);
          }
        }
    } else {
      int cb = (m - 3) * 128;
#pragma unroll
      for (int rt = 0; rt < 2; ++rt)
#pragma unroll
        for (int ct = 0; ct < 8; ++ct) {
          int col = cb + ct * 16 + lr;
          if (col < 200) {
#pragma unroll
            for (int r = 0; r < 4; ++r) {
              int row = r0 + w * 32 + rt * 16 + lg * 4 + r;
              if (row < NN) qe[(size_t)row * 200 + col] = f2bf(acc[rt][ct][r]);
            }
          }
        }
    }
    __syncthreads();
  }
}

// ---------------- general GEMM: out = act(A@W + bias) (+resid) (+fused LN)

template <bool BIAS, bool GELU, bool RESID, bool LNF, bool EXTK>
__global__ __launch_bounds__(256) void k_gemm2(
    const ushort* __restrict__ A, const ushort* __restrict__ Wt,
    const float* __restrict__ bias, const float* __restrict__ resid,
    void* __restrict__ outp, const float* __restrict__ lng,
    const float* __restrict__ lnb, ushort* __restrict__ lnout,
    const ushort* __restrict__ arbn, const ushort* __restrict__ WW) {
  __shared__ ushort Al[128 * 128];
  __shared__ ushort Wl[128 * 128];
  const int tid = threadIdx.x;
  const int r0 = blockIdx.x * 128;

  for (int i = tid; i < 128 * 16; i += 256) {
    int r = i >> 4, g = i & 15;
    int gr = r0 + r;
    ushort4 v0 = {0, 0, 0, 0}, v1 = {0, 0, 0, 0};
    if (gr < NN) {
      v0 = *(const ushort4*)&A[(size_t)gr * 128 + g * 8];
      v1 = *(const ushort4*)&A[(size_t)gr * 128 + g * 8 + 4];
    }
    int gs = g ^ (r & 7);
    *(ushort4*)&Al[r * 128 + gs * 8] = v0;
    *(ushort4*)&Al[r * 128 + gs * 8 + 4] = v1;
  }
  for (int i = tid; i < 128 * 16; i += 256) {
    int c = i >> 4, g = i & 15;
    ushort4 w0 = *(const ushort4*)&Wt[c * 128 + g * 8];
    ushort4 w1 = *(const ushort4*)&Wt[c * 128 + g * 8 + 4];
    int gs = g ^ (c & 7);
    *(ushort4*)&Wl[c * 128 + gs * 8] = w0;
    *(ushort4*)&Wl[c * 128 + gs * 8 + 4] = w1;
  }
  __syncthreads();

  const int w = tid >> 6, l = tid & 63;
  const int lg = l >> 4, lr = l & 15;
  f32x4 acc[2][8];
#pragma unroll
  for (int rt = 0; rt < 2; ++rt)
#pragma unroll
    for (int ct = 0; ct < 8; ++ct) acc[rt][ct] = (f32x4){0.f, 0.f, 0.f, 0.f};

#pragma unroll
  for (int ks = 0; ks < 4; ++ks) {
    short8 af[2];
#pragma unroll
    for (int rt = 0; rt < 2; ++rt) {
      int arow = w * 32 + rt * 16 + lr;
      int ga = (ks * 4 + lg) ^ (arow & 7);
      af[rt] = *(const short8*)&Al[arow * 128 + ga * 8];
    }
#pragma unroll
    for (int ct = 0; ct < 8; ++ct) {
      int col = ct * 16 + lr;
      int gb = (ks * 4 + lg) ^ (col & 7);
      short8 bf = *(const short8*)&Wl[col * 128 + gb * 8];
#pragma unroll
      for (int rt = 0; rt < 2; ++rt)
        acc[rt][ct] = __builtin_amdgcn_mfma_f32_16x16x32_bf16(af[rt], bf, acc[rt][ct], 0, 0, 0);
    }
  }

  if (EXTK) {
    for (int q = 0; q < 2; ++q) {
      __syncthreads();  // prior mfma reads done
      for (int i = tid; i < 128 * 16; i += 256) {
        int r = i >> 4, g = i & 15;
        int gr = r0 + r;
        ushort4 v0 = {0, 0, 0, 0}, v1 = {0, 0, 0, 0};
        if (gr < NN && (q == 0 || g < 9)) {
          v0 = *(const ushort4*)&arbn[(size_t)gr * 200 + q * 128 + g * 8];
          v1 = *(const ushort4*)&arbn[(size_t)gr * 200 + q * 128 + g * 8 + 4];
        }
        int gs = g ^ (r & 7);
        *(ushort4*)&Al[r * 128 + gs * 8] = v0;
        *(ushort4*)&Al[r * 128 + gs * 8 + 4] = v1;
      }
      for (int i = tid; i < 128 * 16; i += 256) {
        int c = i >> 4, g = i & 15;
        ushort4 w0 = *(const ushort4*)&WW[c * 256 + q * 128 + g * 8];
        ushort4 w1 = *(const ushort4*)&WW[c * 256 + q * 128 + g * 8 + 4];
        int gs = g ^ (c & 7);
        *(ushort4*)&Wl[c * 128 + gs * 8] = w0;
        *(ushort4*)&Wl[c * 128 + gs * 8 + 4] = w1;
      }
      __syncthreads();
#pragma unroll
      for (int ks = 0; ks < 4; ++ks) {
        short8 af[2];
#pragma unroll
        for (int rt = 0; rt < 2; ++rt) {
          int arow = w * 32 + rt * 16 + lr;
          int ga = (ks * 4 + lg) ^ (arow & 7);
          af[rt] = *(const short8*)&Al[arow * 128 + ga * 8];
        }
#pragma unroll
        for (int ct = 0; ct < 8; ++ct) {
          int col = ct * 16 + lr;
          int gb = (ks * 4 + lg) ^ (col & 7);
          short8 bf = *(const short8*)&Wl[col * 128 + gb * 8];
#pragma unroll
          for (int rt = 0; rt < 2; ++rt)
            acc[rt][ct] = __builtin_amdgcn_mfma_f32_16x16x32_bf16(af[rt], bf, acc[rt][ct], 0, 0, 0);
        }
      }
    }
  }

#pragma unroll
  for (int rt = 0; rt < 2; ++rt)
#pragma unroll
    for (int r = 0; r < 4; ++r) {
      int row = r0 + w * 32 + rt * 16 + lg * 4 + r;
      bool ok = row < NN;  // uniform across the 16-lane lr group
      float v[8];
#pragma unroll
      for (int ct = 0; ct < 8; ++ct) {
        int col = ct * 16 + lr;
        float vv = acc[rt][ct][r];
        if (BIAS) vv += bias[col];
        if (GELU) vv = gelu_tanh(vv);
        if (RESID) vv += ok ? resid[(size_t)row * 128 + col] : 0.f;
        v[ct] = vv;
      }
      if (RESID || LNF) {
        if (ok)
#pragma unroll
          for (int ct = 0; ct < 8; ++ct)
            ((float*)outp)[(size_t)row * 128 + ct * 16 + lr] = v[ct];
      } else {
        if (ok)
#pragma unroll
          for (int ct = 0; ct < 8; ++ct)
            ((ushort*)outp)[(size_t)row * 128 + ct * 16 + lr] = f2bf(v[ct]);
      }
      if (LNF) {
        float s = 0.f, ss = 0.f;
#pragma unroll
        for (int ct = 0; ct < 8; ++ct) {
          s += v[ct];
          ss = fmaf(v[ct], v[ct], ss);
        }
#pragma unroll
        for (int msk = 8; msk >= 1; msk >>= 1) {
          s += __shfl_xor(s, msk);
          ss += __shfl_xor(ss, msk);
        }
        float mean = s * (1.0f / DDIM);
        float var = ss * (1.0f / DDIM) - mean * mean;
        float inv = rsqrtf(var + 1e-5f);
        if (ok)
#pragma unroll
          for (int ct = 0; ct < 8; ++ct) {
            int col = ct * 16 + lr;
            lnout[(size_t)row * 128 + col] =
                f2bf((v[ct] - mean) * inv * lng[col] + lnb[col]);
          }
      }
    }
}

// ---------------- fused attention v10: wave-uniform 2-deep pipelined far loop ----------------

__device__ __forceinline__ float rbf_fill(float d, int j) {
  const float step = CUTF / (NRAD - 1);
  const float gamma = (NRAD / CUTF) * (NRAD / CUTF);
  float mu = j * step;
  float dm = d - mu;
  float env = 0.5f * (__cosf(PI_F * d / CUTF) + 1.0f);
  return __expf(-gamma * dm * dm) * env;
}

#define SCALE_QK 0.17677669529663687f

__global__ __launch_bounds__(256) void k_attn10(
    const ushort* __restrict__ qnb, const ushort* __restrict__ kvb,
    ushort* __restrict__ qe, const int2* __restrict__ er,
    const int* __restrict__ rowptr, const int* __restrict__ nearend,
    ushort* __restrict__ msgb) {
  __shared__ float qel[4][64][4];   // [wave][j][head]
  __shared__ float rbl[4][64];
  __shared__ float aml[4][128];     // far-accumulator remap buffer (per wave)
  const int tid = threadIdx.x;

  const int w = tid >> 6, t = tid & 63;
  const int n = blockIdx.x * 4 + w;
  const int h = t >> 4;       // near-layout head (16-lane groups)
  const int j0 = t & 15;
  const int hw = t >> 5;      // half-wave id (far loop)
  const int c = t & 31;       // lane in half; owns dims 4c..4c+3 (far loop)
  uint qu = *(const uint*)&qnb[(size_t)n * DDIM + 2 * t];
  const float q0 = bfl(qu), q1 = bfh(qu);
  uint2 qp = *(const uint2*)&qnb[(size_t)n * DDIM + 4 * c];
  const float fq0 = bfl(qp.x), fq1 = bfh(qp.x), fq2 = bfl(qp.y), fq3 = bfh(qp.y);
  if (t < NRAD) {
    ushort4 qv = *(const ushort4*)&qe[(size_t)n * 200 + 4 * t];
    qel[w][t][0] = bfl(qv.x);
    qel[w][t][1] = bfl(qv.y);
    qel[w][t][2] = bfl(qv.z);
    qel[w][t][3] = bfl(qv.w);
  } else {
    qel[w][t][0] = 0.f; qel[w][t][1] = 0.f; qel[w][t][2] = 0.f; qel[w][t][3] = 0.f;
  }
  const int start = rowptr[n], nend = nearend[n], end = rowptr[n + 1];

  float s = 0.f, a0 = 0.f, a1 = 0.f;
  float4 arb = {0.f, 0.f, 0.f, 0.f};

  // ---- near loop (radial features active), full wave per edge ----
  for (int cb = start; cb < nend; cb += 64) {
    int cnt = min(nend - cb, 64);
    int2 e_t = make_int2(0, 0);
    if (t < cnt) e_t = er[cb + t];
    for (int i = 0; i < cnt; ++i) {
      int src = __shfl(e_t.x, i);
      float dd = __shfl(__int_as_float(e_t.y), i);
      uint2 kv = *(const uint2*)&kvb[(size_t)src * 256 + 4 * t];
      float pr = q0 * bfl(kv.x) + q1 * bfl(kv.y);
      float rb = (t < NRAD) ? rbf_fill(dd, t) : 0.f;
      rbl[w][t] = rb;
      pr = fmaf(rbl[w][j0], qel[w][j0][h], pr);
      pr = fmaf(rbl[w][j0 + 16], qel[w][j0 + 16][h], pr);
      pr = fmaf(rbl[w][j0 + 32], qel[w][j0 + 32][h], pr);
      pr = fmaf(rbl[w][j0 + 48], qel[w][j0 + 48][h], pr);
      pr = red16(pr);
      float ae = __expf(fminf(pr * SCALE_QK, 60.f));
      s += ae;
      a0 = fmaf(ae, bfh(kv.x), a0);
      a1 = fmaf(ae, bfh(kv.y), a1);
      float aex = __shfl(ae, 0);
      float aey = __shfl(ae, 16);
      float aez = __shfl(ae, 32);
      float aew = __shfl(ae, 48);
      arb.x = fmaf(rb, aex, arb.x);
      arb.y = fmaf(rb, aey, arb.y);
      arb.z = fmaf(rb, aez, arb.z);
      arb.w = fmaf(rb, aew, arb.w);
    }
  }

  // ---- far loop: wave-uniform trip count, 2 edges per half per iter, masked tails ----
  // All lanes execute every iteration (no divergence) so every __shfl source lane
  // is active; invalid slots clamp the shfl index to 0 and zero their ae weight.
  float sf = 0.f, af0 = 0.f, af1 = 0.f, af2 = 0.f, af3 = 0.f;
  float sg = 0.f, ag0 = 0.f, ag1 = 0.f, ag2 = 0.f, ag3 = 0.f;
  for (int cb = nend; cb < end; cb += 64) {
    int cnt = min(end - cb, 64);
    int src_t = 0;
    if (t < cnt) src_t = er[cb + t].x;
    int npair = (cnt + 3) >> 2;  // uniform across wave
    for (int k = 0; k < npair; ++k) {
      int iA = 4 * k + hw;
      int iB = iA + 2;
      bool vA = iA < cnt;
      bool vB = iB < cnt;
      int sA = __shfl(src_t, vA ? iA : 0);
      int sB = __shfl(src_t, vB ? iB : 0);
      uint4 kvA = *(const uint4*)&kvb[(size_t)sA * 256 + 8 * c];
      uint4 kvB = *(const uint4*)&kvb[(size_t)sB * 256 + 8 * c];
      float pA = fq0 * bfl(kvA.x) + fq1 * bfl(kvA.y);
      float pB = fq0 * bfl(kvB.x) + fq1 * bfl(kvB.y);
      pA = fmaf(fq2, bfl(kvA.z), pA);
      pB = fmaf(fq2, bfl(kvB.z), pB);
      pA = fmaf(fq3, bfl(kvA.w), pA);
      pB = fmaf(fq3, bfl(kvB.w), pB);
      pA = red8(pA);
      pB = red8(pB);
      float aeA = vA ? __expf(fminf(pA * SCALE_QK, 60.f)) : 0.f;
      float aeB = vB ? __expf(fminf(pB * SCALE_QK, 60.f)) : 0.f;
      sf += aeA;
      sg += aeB;
      af0 = fmaf(aeA, bfh(kvA.x), af0);
      ag0 = fmaf(aeB, bfh(kvB.x), ag0);
      af1 = fmaf(aeA, bfh(kvA.y), af1);
      ag1 = fmaf(aeB, bfh(kvB.y), ag1);
      af2 = fmaf(aeA, bfh(kvA.z), af2);
      ag2 = fmaf(aeB, bfh(kvB.z), ag2);
      af3 = fmaf(aeA, bfh(kvA.w), af3);
      ag3 = fmaf(aeB, bfh(kvB.w), ag3);
    }
  }
  sf += sg;
  af0 += ag0;
  af1 += ag1;
  af2 += ag2;
  af3 += ag3;
  // combine the two halves (same dims, different edge subsets)
  sf += __shfl_xor(sf, 32);
  af0 += __shfl_xor(af0, 32);
  af1 += __shfl_xor(af1, 32);
  af2 += __shfl_xor(af2, 32);
  af3 += __shfl_xor(af3, 32);
  // remap far accumulators (4 dims/lane) into near layout (2 dims/lane) via LDS
  aml[w][4 * c + 0] = af0;
  aml[w][4 * c + 1] = af1;
  aml[w][4 * c + 2] = af2;
  aml[w][4 * c + 3] = af3;
  a0 += aml[w][2 * t];
  a1 += aml[w][2 * t + 1];

  // ---- finalize: normalize; store a_norm (msgb) and arbn (into qe buffer) ----
  float4 s4;
  s4.x = __shfl(s, 0) + __shfl(sf, 0);
  s4.y = __shfl(s, 16) + __shfl(sf, 8);
  s4.z = __shfl(s, 32) + __shfl(sf, 16);
  s4.w = __shfl(s, 48) + __shfl(sf, 24);
  float4 inv4 = {1.f / (s4.x + 1e-9f), 1.f / (s4.y + 1e-9f),
                 1.f / (s4.z + 1e-9f), 1.f / (s4.w + 1e-9f)};
  float invo = (h == 0) ? inv4.x : (h == 1) ? inv4.y : (h == 2) ? inv4.z : inv4.w;
  if (t < NRAD) {
    ushort4 o = {f2bf(arb.x * inv4.x), f2bf(arb.y * inv4.y),
                 f2bf(arb.z * inv4.z), f2bf(arb.w * inv4.w)};
    *(ushort4*)&qe[(size_t)n * 200 + 4 * t] = o;
  }
  a0 *= invo;
  a1 *= invo;
  uint pk = (uint)f2bf(a0) | ((uint)f2bf(a1) << 16);
  *(uint*)&msgb[(size_t)n * DDIM + 2 * t] = pk;
}

// ---------------- graph sum (batch is sorted): 32 nodes/block, boundary atomics ----------------

#define GS_NODES 32
__global__ void k_graphsum(const float* __restrict__ x, const int* __restrict__ batch,
                           float* __restrict__ g) {
  int t = threadIdx.x;  // 128 dims
  int n0 = blockIdx.x * GS_NODES;
  int nend = n0 + GS_NODES;
  if (nend > NN) nend = NN;
  if (n0 >= NN) return;
  float acc = 0.f;
  int cur = batch[n0];
  for (int n = n0; n < nend; ++n) {
    int bb = batch[n];
    if (bb != cur) {
      atomicAdd(&g[(size_t)cur * DDIM + t], acc);
      acc = 0.f;
      cur = bb;
    }
    acc += x[(size_t)n * DDIM + t];
  }
  atomicAdd(&g[(size_t)cur * DDIM + t], acc);
}

// ---------------- output projection ----------------

__global__ void k_out(const float* __restrict__ g, const float* __restrict__ W,
                      const float* __restrict__ b, float* __restrict__ out) {
  int idx = blockIdx.x * blockDim.x + threadIdx.x;
  if (idx >= NGRAPH * DOUT) return;
  int r = idx / DOUT, c = idx % DOUT;
  float acc = b[c];
#pragma unroll 8
  for (int k = 0; k < DDIM; ++k) acc = fmaf(g[r * DDIM + k], W[k * DOUT + c], acc);
  out[idx] = acc;
}

// ---------------- launch ----------------

extern "C" void kernel_launch(void* const* d_in, const int* in_sizes, int n_in,
                              void* d_out, int out_size, void* d_ws, size_t ws_size,
                              hipStream_t stream) {
  const float* pos = (const float*)d_in[0];
  const int* at = (const int*)d_in[1];
  const int* ei = (const int*)d_in[2];
  const int* batch = (const int*)d_in[3];
  const float* emb = (const float*)d_in[4];
  const float* W_init = (const float*)d_in[5];
  const float* b_init = (const float*)d_in[6];
  const float* Wq = (const float*)d_in[7];
  const float* Wk = (const float*)d_in[8];
  const float* Wv = (const float*)d_in[9];
  const float* We = (const float*)d_in[10];
  const float* Wo = (const float*)d_in[11];
  const float* Wm1 = (const float*)d_in[12];
  const float* bm1 = (const float*)d_in[13];
  const float* Wm2 = (const float*)d_in[14];
  const float* bm2 = (const float*)d_in[15];
  const float* ln_g = (const float*)d_in[16];
  const float* ln_b = (const float*)d_in[17];
  const float* W_out = (const float*)d_in[18];
  const float* b_out = (const float*)d_in[19];
  float* out = (float*)d_out;

  const size_t ND = (size_t)NN * DDIM;  // 6.4M
  float* x = (float*)d_ws;              // f32 ND
  ushort* qnb = (ushort*)(x + ND);      // bf16 ND (alias hb)
  ushort* kvb = qnb + ND;               // bf16 2*ND interleaved k/v (alias h2 first half)
  ushort* msgb = kvb + 2 * ND;          // bf16 ND
  ushort* qe = msgb + ND;               // bf16 NN*200 (doubles as arbn)
  ushort* Wtb = qe + (size_t)NN * 200;  // bf16 12*16384
  ushort* WW = Wtb + 12 * 16384;        // bf16 2*128*256 (WeWo)
  ushort* WQET = WW + 2 * 32768;        // bf16 2*256*128 (WqWe^T)
  float* embW = (float*)(WQET + 2 * 32768);  // f32 NTYPE*DDIM
  float* de = embW + NTYPE * DDIM;      // f32 NE
  int* deg = (int*)(de + NE);
  int* cnear = deg + NN;
  int* cfar = cnear + NN;
  int* rowptr = cfar + NN;
  int2* er = (int2*)(rowptr + NN + 64);  // NE int2
  float* gb = (float*)(er + NE);         // NG*DDIM
  int* bsum = (int*)(gb + NGRAPH * DDIM);  // SCAN_N
  // total ~96.6 MB

  ushort* hb = qnb;
  ushort* h2 = kvb;  // kvb dead after attn within a layer; reused as h2

  k_pre<<<1526, 256, 0, stream>>>(Wq, Wk, Wv, Wo, Wm1, Wm2, We, emb, W_init, b_init,
                                  Wtb, WW, WQET, embW, deg);
  k_init2<<<(NN * 32 + 255) / 256, 256, 0, stream>>>(pos, at, embW, W_init, x);
  k_edge<<<(NE + 255) / 256, 256, 0, stream>>>(pos, ei, de, deg);
  k_scan1<<<SCAN_N, 256, 0, stream>>>(deg, bsum);
  k_scan2<<<1, 256, 0, stream>>>(bsum);
  k_scan3<<<SCAN_N, 256, 0, stream>>>(deg, bsum, rowptr, cnear, cfar);
  k_scatter<<<(NE + 255) / 256, 256, 0, stream>>>(ei, de, cnear, cfar, er);

  const int gg = (NN + 127) / 128;  // 391
  for (int l = 0; l < 2; ++l) {
    const ushort* Wt_l = Wtb + (size_t)l * 6 * 16384;
    const ushort* WQET_l = WQET + (size_t)l * 32768;
    const ushort* WW_l = WW + (size_t)l * 32768;

    k_qkv<<<gg, 256, 0, stream>>>(x, Wt_l, WQET_l, qnb, kvb, qe);
    k_attn10<<<NN / 4, 256, 0, stream>>>(qnb, kvb, qe, er, rowptr, cnear, msgb);

    // x += msg@Wo + arbn@WeWo, fused layernorm -> hb
    k_gemm2<false, false, true, true, true><<<gg, 256, 0, stream>>>(
        msgb, Wt_l + 3 * 16384, nullptr, x, x,
        ln_g + (size_t)l * DDIM, ln_b + (size_t)l * DDIM, hb, qe, WW_l);
    // h2 = gelu(hb@Wm1 + bm1)
    k_gemm2<true, true, false, false, false><<<gg, 256, 0, stream>>>(
        hb, Wt_l + 4 * 16384, bm1 + (size_t)l * DDIM, nullptr, h2,
        nullptr, nullptr, nullptr, nullptr, nullptr);
    // x += h2@Wm2 + bm2
    k_gemm2<true, false, true, false, false><<<gg, 256, 0, stream>>>(
        h2, Wt_l + 5 * 16384, bm2 + (size_t)l * DDIM, x, x,
        nullptr, nullptr, nullptr, nullptr, nullptr);
  }

  k_fill_f<<<(NGRAPH * DDIM + 255) / 256, 256, 0, stream>>>(gb, 0.f, NGRAPH * DDIM);
  k_graphsum<<<(NN + GS_NODES - 1) / GS_NODES, 128, 0, stream>>>(x, batch, gb);
  k_out<<<(NGRAPH * DOUT + 255) / 256, 256, 0, stream>>>(gb, W_out, b_out, out);
}

// Round 17
// 345.063 us; speedup vs baseline: 1.4368x; 1.0115x over previous
//
#include <hip/hip_runtime.h>
#include <math.h>

#define NN 50000
#define NE 400000
#define DDIM 128
#define NHEAD 4
#define NRAD 50
#define NGRAPH 100
#define NTYPE 100
#define TEMB 32
#define DOUT 512
#define CUTF 6.0f
#define PI_F 3.14159265358979323846f

#define SCAN_N ((NN + 255) / 256)  // 196 scan blocks

typedef unsigned int uint;
typedef unsigned short ushort;
typedef __attribute__((ext_vector_type(8))) short short8;
typedef __attribute__((ext_vector_type(4))) float f32x4;

// ---------------- helpers ----------------

__device__ __forceinline__ float gelu_tanh(float v) {
  float u = 0.7978845608028654f * (v + 0.044715f * v * v * v);
  return 0.5f * v * (1.0f + tanhf(u));
}

__device__ __forceinline__ ushort f2bf(float f) {  // RNE
  uint u = __float_as_uint(f);
  uint r = (u + 0x7fffu + ((u >> 16) & 1u)) >> 16;
  return (ushort)r;
}
__device__ __forceinline__ float bfl(uint u) { return __uint_as_float(u << 16); }
__device__ __forceinline__ float bfh(uint u) { return __uint_as_float(u & 0xffff0000u); }

// DPP sum reductions on the VALU (no ds_bpermute).
__device__ __forceinline__ float red16(float v) {
  v += __int_as_float(__builtin_amdgcn_update_dpp(0, __float_as_int(v), 0xB1, 0xF, 0xF, true));
  v += __int_as_float(__builtin_amdgcn_update_dpp(0, __float_as_int(v), 0x4E, 0xF, 0xF, true));
  v += __int_as_float(__builtin_amdgcn_update_dpp(0, __float_as_int(v), 0x141, 0xF, 0xF, true));
  v += __int_as_float(__builtin_amdgcn_update_dpp(0, __float_as_int(v), 0x140, 0xF, 0xF, true));
  return v;
}
__device__ __forceinline__ float red8(float v) {
  v += __int_as_float(__builtin_amdgcn_update_dpp(0, __float_as_int(v), 0xB1, 0xF, 0xF, true));
  v += __int_as_float(__builtin_amdgcn_update_dpp(0, __float_as_int(v), 0x4E, 0xF, 0xF, true));
  v += __int_as_float(__builtin_amdgcn_update_dpp(0, __float_as_int(v), 0x141, 0xF, 0xF, true));
  return v;
}

__global__ void k_fill_f(float* p, float v, int n) {
  int i = blockIdx.x * blockDim.x + threadIdx.x;
  if (i < n) p[i] = v;
}

// ---------------- fused prologue: wconv | wewo | wqe | embw | deg=0 ----------------

__global__ void k_pre(const float* __restrict__ Wq, const float* __restrict__ Wk,
                      const float* __restrict__ Wv, const float* __restrict__ Wo,
                      const float* __restrict__ Wm1, const float* __restrict__ Wm2,
                      const float* __restrict__ We, const float* __restrict__ emb,
                      const float* __restrict__ Wi, const float* __restrict__ bi,
                      ushort* __restrict__ Wtb, ushort* __restrict__ WW,
                      ushort* __restrict__ WQET, float* __restrict__ embW,
                      int* __restrict__ deg) {
  int b = blockIdx.x;
  if (b < 768) {  // wconv: 12*16384
    int idx = b * 256 + threadIdx.x;
    int m = idx >> 14;
    int r = idx & 16383;
    int c = r >> 7, k = r & 127;
    int l = m / 6, fam = m % 6;
    const float* src = fam == 0 ? Wq : fam == 1 ? Wk : fam == 2 ? Wv
                     : fam == 3 ? Wo : fam == 4 ? Wm1 : Wm2;
    Wtb[idx] = f2bf(src[l * 16384 + k * 128 + c]);
  } else if (b < 1024) {  // wewo: 2*128*256
    int idx = (b - 768) * 256 + threadIdx.x;
    int l = idx >> 15;
    int r = idx & 32767;
    int c = r >> 8, k = r & 255;
    float acc = 0.f;
    if (k < 200) {
      int j = k >> 2, h = k & 3;
      const float* we = We + (size_t)l * NRAD * DDIM + j * DDIM + 32 * h;
      const float* wo = Wo + (size_t)l * DDIM * DDIM + (size_t)(32 * h) * DDIM + c;
#pragma unroll 8
      for (int dk = 0; dk < 32; ++dk) acc = fmaf(we[dk], wo[(size_t)dk * DDIM], acc);
    }
    WW[idx] = f2bf(acc);
  } else if (b < 1280) {  // wqe: 2*256*128
    int idx = (b - 1024) * 256 + threadIdx.x;
    int l = idx >> 15;
    int r = idx & 32767;
    int col = r >> 7, d = r & 127;
    float acc = 0.f;
    if (col < 200) {
      int j = col >> 2, h = col & 3;
      const float* wq = Wq + (size_t)l * 16384 + (size_t)d * 128 + 32 * h;
      const float* we = We + (size_t)l * NRAD * DDIM + j * DDIM + 32 * h;
#pragma unroll 8
      for (int u = 0; u < 32; ++u) acc = fmaf(wq[u], we[u], acc);
    }
    WQET[idx] = f2bf(acc);
  } else if (b < 1330) {  // embw: NTYPE*DDIM = 12800
    int idx = (b - 1280) * 256 + threadIdx.x;
    if (idx < NTYPE * DDIM) {
      int a = idx >> 7, c = idx & 127;
      const float* er = emb + (size_t)a * TEMB;
      float acc = bi[c];
#pragma unroll
      for (int t = 0; t < TEMB; ++t) acc = fmaf(er[t], Wi[t * DDIM + c], acc);
      embW[idx] = acc;
    }
  } else {  // deg zero
    int idx = (b - 1330) * 256 + threadIdx.x;
    if (idx < NN) deg[idx] = 0;
  }
}

// ---------------- init v2: x[n] = embW[at[n]] + pos[n]@W_init[32:35] ----------------

__global__ void k_init2(const float* __restrict__ pos, const int* __restrict__ at,
                        const float* __restrict__ embW, const float* __restrict__ W,
                        float* __restrict__ x) {
  int idx = blockIdx.x * blockDim.x + threadIdx.x;  // NN*32
  if (idx >= NN * 32) return;
  int n = idx >> 5, c4 = (idx & 31) << 2;
  float4 e = *(const float4*)&embW[(size_t)at[n] * DDIM + c4];
  float px = pos[n * 3 + 0], py = pos[n * 3 + 1], pz = pos[n * 3 + 2];
  float4 wx = *(const float4*)&W[(TEMB + 0) * DDIM + c4];
  float4 wy = *(const float4*)&W[(TEMB + 1) * DDIM + c4];
  float4 wz = *(const float4*)&W[(TEMB + 2) * DDIM + c4];
  float4 o;
  o.x = e.x + px * wx.x + py * wy.x + pz * wz.x;
  o.y = e.y + px * wx.y + py * wy.y + pz * wz.y;
  o.z = e.z + px * wx.z + py * wy.z + pz * wz.z;
  o.w = e.w + px * wx.w + py * wy.w + pz * wz.w;
  *(float4*)&x[(size_t)n * DDIM + c4] = o;
}

// ---------------- per-edge distance + degree histogram (fused) ----------------

__global__ void k_edge(const float* __restrict__ pos, const int* __restrict__ ei,
                       float* __restrict__ de, int* __restrict__ deg) {
  int e = blockIdx.x * blockDim.x + threadIdx.x;
  if (e >= NE) return;
  int s = ei[e], t = ei[NE + e];
  float dx = pos[s * 3 + 0] - pos[t * 3 + 0] + 1e-8f;
  float dy = pos[s * 3 + 1] - pos[t * 3 + 1] + 1e-8f;
  float dz = pos[s * 3 + 2] - pos[t * 3 + 2] + 1e-8f;
  de[e] = sqrtf(dx * dx + dy * dy + dz * dz);
  atomicAdd(&deg[t], 1);
}

// ---------------- CSR build: parallel 3-pass exclusive scan ----------------

__global__ void k_scan1(const int* __restrict__ deg, int* __restrict__ bsum) {
  __shared__ int red[256];
  int i = blockIdx.x * 256 + threadIdx.x;
  red[threadIdx.x] = (i < NN) ? deg[i] : 0;
  __syncthreads();
  for (int off = 128; off > 0; off >>= 1) {
    if (threadIdx.x < off) red[threadIdx.x] += red[threadIdx.x + off];
    __syncthreads();
  }
  if (threadIdx.x == 0) bsum[blockIdx.x] = red[0];
}

__global__ void k_scan2(int* __restrict__ bsum) {  // 1 block, 256 threads >= SCAN_N
  __shared__ int sh[256];
  int t = threadIdx.x;
  int v = (t < SCAN_N) ? bsum[t] : 0;
  sh[t] = v;
  __syncthreads();
  for (int off = 1; off < 256; off <<= 1) {
    int u = (t >= off) ? sh[t - off] : 0;
    __syncthreads();
    sh[t] += u;
    __syncthreads();
  }
  if (t < SCAN_N) bsum[t] = (t == 0) ? 0 : sh[t - 1];
}

__global__ void k_scan3(const int* __restrict__ deg, const int* __restrict__ bsum,
                        int* __restrict__ rowptr, int* __restrict__ cnear,
                        int* __restrict__ cfar) {
  __shared__ int sh[256];
  int t = threadIdx.x;
  int i = blockIdx.x * 256 + t;
  int v = (i < NN) ? deg[i] : 0;
  sh[t] = v;
  __syncthreads();
  for (int off = 1; off < 256; off <<= 1) {
    int u = (t >= off) ? sh[t - off] : 0;
    __syncthreads();
    sh[t] += u;
    __syncthreads();
  }
  int excl = bsum[blockIdx.x] + sh[t] - v;
  if (i < NN) {
    rowptr[i] = excl;
    cnear[i] = excl;
    cfar[i] = excl + v;  // = rowptr[i+1]
    if (i == NN - 1) rowptr[NN] = excl + v;
  }
}

// scatter into near-first / far-last segmented CSR, packed records {src, d}
__global__ void k_scatter(const int* __restrict__ ei, const float* __restrict__ de,
                          int* __restrict__ cnear, int* __restrict__ cfar,
                          int2* __restrict__ er) {
  int e = blockIdx.x * blockDim.x + threadIdx.x;
  if (e >= NE) return;
  int src = ei[e], dst = ei[NE + e];
  float d = de[e];
  int idx;
  if (d < CUTF)
    idx = atomicAdd(&cnear[dst], 1);
  else
    idx = atomicSub(&cfar[dst], 1) - 1;
  er[idx] = make_int2(src, __float_as_int(d));
}

// ---------------- fused QKV+QE GEMM: stage x once, 5 weight passes ----------------
// m=0: q. m=1: k held in registers. m=2: coalesced ushort2 {k,v} -> kvb. m=3,4: qe.

__global__ __launch_bounds__(256) void k_qkv(
    const float* __restrict__ x, const ushort* __restrict__ Wt3,
    const ushort* __restrict__ WQET, ushort* __restrict__ qo,
    ushort* __restrict__ kvb, ushort* __restrict__ qe) {
  __shared__ ushort Al[128 * 128];
  __shared__ ushort Wl[128 * 128];
  const int tid = threadIdx.x;
  const int r0 = blockIdx.x * 128;
  ushort kreg[2][8][4];  // k results carried from m=1 to m=2

  for (int i = tid; i < 128 * 16; i += 256) {
    int r = i >> 4, g = i & 15;
    int gr = r0 + r;
    float4 f0 = {0, 0, 0, 0}, f1 = {0, 0, 0, 0};
    if (gr < NN) {
      f0 = *(const float4*)&x[(size_t)gr * 128 + g * 8];
      f1 = *(const float4*)&x[(size_t)gr * 128 + g * 8 + 4];
    }
    int gs = g ^ (r & 7);
    ushort4 u0 = {f2bf(f0.x), f2bf(f0.y), f2bf(f0.z), f2bf(f0.w)};
    ushort4 u1 = {f2bf(f1.x), f2bf(f1.y), f2bf(f1.z), f2bf(f1.w)};
    *(ushort4*)&Al[r * 128 + gs * 8] = u0;
    *(ushort4*)&Al[r * 128 + gs * 8 + 4] = u1;
  }

  const int w = tid >> 6, l = tid & 63;
  const int lg = l >> 4, lr = l & 15;

  for (int m = 0; m < 5; ++m) {
    const ushort* wsrc = (m < 3) ? (Wt3 + m * 16384) : (WQET + (m - 3) * 16384);
    for (int i = tid; i < 128 * 16; i += 256) {
      int c = i >> 4, g = i & 15;
      ushort4 w0 = *(const ushort4*)&wsrc[c * 128 + g * 8];
      ushort4 w1 = *(const ushort4*)&wsrc[c * 128 + g * 8 + 4];
      int gs = g ^ (c & 7);
      *(ushort4*)&Wl[c * 128 + gs * 8] = w0;
      *(ushort4*)&Wl[c * 128 + gs * 8 + 4] = w1;
    }
    __syncthreads();

    f32x4 acc[2][8];
#pragma unroll
    for (int rt = 0; rt < 2; ++rt)
#pragma unroll
      for (int ct = 0; ct < 8; ++ct) acc[rt][ct] = (f32x4){0.f, 0.f, 0.f, 0.f};

#pragma unroll
    for (int ks = 0; ks < 4; ++ks) {
      short8 af[2];
#pragma unroll
      for (int rt = 0; rt < 2; ++rt) {
        int arow = w * 32 + rt * 16 + lr;
        int ga = (ks * 4 + lg) ^ (arow & 7);
        af[rt] = *(const short8*)&Al[arow * 128 + ga * 8];
      }
#pragma unroll
      for (int ct = 0; ct < 8; ++ct) {
        int col = ct * 16 + lr;
        int gb = (ks * 4 + lg) ^ (col & 7);
        short8 bf = *(const short8*)&Wl[col * 128 + gb * 8];
#pragma unroll
        for (int rt = 0; rt < 2; ++rt)
          acc[rt][ct] = __builtin_amdgcn_mfma_f32_16x16x32_bf16(af[rt], bf, acc[rt][ct], 0, 0, 0);
      }
    }

    if (m == 0) {
#pragma unroll
      for (int rt = 0; rt < 2; ++rt)
#pragma unroll
        for (int ct = 0; ct < 8; ++ct) {
          int col = ct * 16 + lr;
#pragma unroll
          for (int r = 0; r < 4; ++r) {
            int row = r0 + w * 32 + rt * 16 + lg * 4 + r;
            if (row < NN) qo[(size_t)row * 128 + col] = f2bf(acc[rt][ct][r]);
          }
        }
    } else if (m == 1) {
      // hold k in registers until the v pass
#pragma unroll
      for (int rt = 0; rt < 2; ++rt)
#pragma unroll
        for (int ct = 0; ct < 8; ++ct)
#pragma unroll
          for (int r = 0; r < 4; ++r) kreg[rt][ct][r] = f2bf(acc[rt][ct][r]);
    } else if (m == 2) {
      // coalesced {k,v} pair stores: lanes lr=0..15 cover 64B contiguous per ct
#pragma unroll
      for (int rt = 0; rt < 2; ++rt)
#pragma unroll
        for (int ct = 0; ct < 8; ++ct) {
          int col = ct * 16 + lr;
#pragma unroll
          for (int r = 0; r < 4; ++r) {
            int row = r0 + w * 32 + rt * 16 + lg * 4 + r;
            if (row < NN) {
              ushort2 p = {kreg[rt][ct][r], f2bf(acc[rt][ct][r])};
              *(ushort2*)&kvb[(size_t)row * 256 + 2 * col] = p;
            }
          }
        }
    } else {
      int cb = (m - 3) * 128;
#pragma unroll
      for (int rt = 0; rt < 2; ++rt)
#pragma unroll
        for (int ct = 0; ct < 8; ++ct) {
          int col = cb + ct * 16 + lr;
          if (col < 200) {
#pragma unroll
            for (int r = 0; r < 4; ++r) {
              int row = r0 + w * 32 + rt * 16 + lg * 4 + r;
              if (row < NN) qe[(size_t)row * 200 + col] = f2bf(acc[rt][ct][r]);
            }
          }
        }
    }
    __syncthreads();
  }
}

// ---------------- general GEMM: out = act(A@W + bias) (+resid) (+fused LN)

template <bool BIAS, bool GELU, bool RESID, bool LNF, bool EXTK>
__global__ __launch_bounds__(256) void k_gemm2(
    const ushort* __restrict__ A, const ushort* __restrict__ Wt,
    const float* __restrict__ bias, const float* __restrict__ resid,
    void* __restrict__ outp, const float* __restrict__ lng,
    const float* __restrict__ lnb, ushort* __restrict__ lnout,
    const ushort* __restrict__ arbn, const ushort* __restrict__ WW) {
  __shared__ ushort Al[128 * 128];
  __shared__ ushort Wl[128 * 128];
  const int tid = threadIdx.x;
  const int r0 = blockIdx.x * 128;

  for (int i = tid; i < 128 * 16; i += 256) {
    int r = i >> 4, g = i & 15;
    int gr = r0 + r;
    ushort4 v0 = {0, 0, 0, 0}, v1 = {0, 0, 0, 0};
    if (gr < NN) {
      v0 = *(const ushort4*)&A[(size_t)gr * 128 + g * 8];
      v1 = *(const ushort4*)&A[(size_t)gr * 128 + g * 8 + 4];
    }
    int gs = g ^ (r & 7);
    *(ushort4*)&Al[r * 128 + gs * 8] = v0;
    *(ushort4*)&Al[r * 128 + gs * 8 + 4] = v1;
  }
  for (int i = tid; i < 128 * 16; i += 256) {
    int c = i >> 4, g = i & 15;
    ushort4 w0 = *(const ushort4*)&Wt[c * 128 + g * 8];
    ushort4 w1 = *(const ushort4*)&Wt[c * 128 + g * 8 + 4];
    int gs = g ^ (c & 7);
    *(ushort4*)&Wl[c * 128 + gs * 8] = w0;
    *(ushort4*)&Wl[c * 128 + gs * 8 + 4] = w1;
  }
  __syncthreads();

  const int w = tid >> 6, l = tid & 63;
  const int lg = l >> 4, lr = l & 15;
  f32x4 acc[2][8];
#pragma unroll
  for (int rt = 0; rt < 2; ++rt)
#pragma unroll
    for (int ct = 0; ct < 8; ++ct) acc[rt][ct] = (f32x4){0.f, 0.f, 0.f, 0.f};

#pragma unroll
  for (int ks = 0; ks < 4; ++ks) {
    short8 af[2];
#pragma unroll
    for (int rt = 0; rt < 2; ++rt) {
      int arow = w * 32 + rt * 16 + lr;
      int ga = (ks * 4 + lg) ^ (arow & 7);
      af[rt] = *(const short8*)&Al[arow * 128 + ga * 8];
    }
#pragma unroll
    for (int ct = 0; ct < 8; ++ct) {
      int col = ct * 16 + lr;
      int gb = (ks * 4 + lg) ^ (col & 7);
      short8 bf = *(const short8*)&Wl[col * 128 + gb * 8];
#pragma unroll
      for (int rt = 0; rt < 2; ++rt)
        acc[rt][ct] = __builtin_amdgcn_mfma_f32_16x16x32_bf16(af[rt], bf, acc[rt][ct], 0, 0, 0);
    }
  }

  if (EXTK) {
    for (int q = 0; q < 2; ++q) {
      __syncthreads();  // prior mfma reads done
      for (int i = tid; i < 128 * 16; i += 256) {
        int r = i >> 4, g = i & 15;
        int gr = r0 + r;
        ushort4 v0 = {0, 0, 0, 0}, v1 = {0, 0, 0, 0};
        if (gr < NN && (q == 0 || g < 9)) {
          v0 = *(const ushort4*)&arbn[(size_t)gr * 200 + q * 128 + g * 8];
          v1 = *(const ushort4*)&arbn[(size_t)gr * 200 + q * 128 + g * 8 + 4];
        }
        int gs = g ^ (r & 7);
        *(ushort4*)&Al[r * 128 + gs * 8] = v0;
        *(ushort4*)&Al[r * 128 + gs * 8 + 4] = v1;
      }
      for (int i = tid; i < 128 * 16; i += 256) {
        int c = i >> 4, g = i & 15;
        ushort4 w0 = *(const ushort4*)&WW[c * 256 + q * 128 + g * 8];
        ushort4 w1 = *(const ushort4*)&WW[c * 256 + q * 128 + g * 8 + 4];
        int gs = g ^ (c & 7);
        *(ushort4*)&Wl[c * 128 + gs * 8] = w0;
        *(ushort4*)&Wl[c * 128 + gs * 8 + 4] = w1;
      }
      __syncthreads();
#pragma unroll
      for (int ks = 0; ks < 4; ++ks) {
        short8 af[2];
#pragma unroll
        for (int rt = 0; rt < 2; ++rt) {
          int arow = w * 32 + rt * 16 + lr;
          int ga = (ks * 4 + lg) ^ (arow & 7);
          af[rt] = *(const short8*)&Al[arow * 128 + ga * 8];
        }
#pragma unroll
        for (int ct = 0; ct < 8; ++ct) {
          int col = ct * 16 + lr;
          int gb = (ks * 4 + lg) ^ (col & 7);
          short8 bf = *(const short8*)&Wl[col * 128 + gb * 8];
#pragma unroll
          for (int rt = 0; rt < 2; ++rt)
            acc[rt][ct] = __builtin_amdgcn_mfma_f32_16x16x32_bf16(af[rt], bf, acc[rt][ct], 0, 0, 0);
        }
      }
    }
  }

#pragma unroll
  for (int rt = 0; rt < 2; ++rt)
#pragma unroll
    for (int r = 0; r < 4; ++r) {
      int row = r0 + w * 32 + rt * 16 + lg * 4 + r;
      bool ok = row < NN;  // uniform across the 16-lane lr group
      float v[8];
#pragma unroll
      for (int ct = 0; ct < 8; ++ct) {
        int col = ct * 16 + lr;
        float vv = acc[rt][ct][r];
        if (BIAS) vv += bias[col];
        if (GELU) vv = gelu_tanh(vv);
        if (RESID) vv += ok ? resid[(size_t)row * 128 + col] : 0.f;
        v[ct] = vv;
      }
      if (RESID || LNF) {
        if (ok)
#pragma unroll
          for (int ct = 0; ct < 8; ++ct)
            ((float*)outp)[(size_t)row * 128 + ct * 16 + lr] = v[ct];
      } else {
        if (ok)
#pragma unroll
          for (int ct = 0; ct < 8; ++ct)
            ((ushort*)outp)[(size_t)row * 128 + ct * 16 + lr] = f2bf(v[ct]);
      }
      if (LNF) {
        float s = 0.f, ss = 0.f;
#pragma unroll
        for (int ct = 0; ct < 8; ++ct) {
          s += v[ct];
          ss = fmaf(v[ct], v[ct], ss);
        }
#pragma unroll
        for (int msk = 8; msk >= 1; msk >>= 1) {
          s += __shfl_xor(s, msk);
          ss += __shfl_xor(ss, msk);
        }
        float mean = s * (1.0f / DDIM);
        float var = ss * (1.0f / DDIM) - mean * mean;
        float inv = rsqrtf(var + 1e-5f);
        if (ok)
#pragma unroll
          for (int ct = 0; ct < 8; ++ct) {
            int col = ct * 16 + lr;
            lnout[(size_t)row * 128 + col] =
                f2bf((v[ct] - mean) * inv * lng[col] + lnb[col]);
          }
      }
    }
}

// ---------------- fused attention v10: wave-uniform 2-deep pipelined far loop ----------------

__device__ __forceinline__ float rbf_fill(float d, int j) {
  const float step = CUTF / (NRAD - 1);
  const float gamma = (NRAD / CUTF) * (NRAD / CUTF);
  float mu = j * step;
  float dm = d - mu;
  float env = 0.5f * (__cosf(PI_F * d / CUTF) + 1.0f);
  return __expf(-gamma * dm * dm) * env;
}

#define SCALE_QK 0.17677669529663687f

__global__ __launch_bounds__(256) void k_attn10(
    const ushort* __restrict__ qnb, const ushort* __restrict__ kvb,
    ushort* __restrict__ qe, const int2* __restrict__ er,
    const int* __restrict__ rowptr, const int* __restrict__ nearend,
    ushort* __restrict__ msgb) {
  __shared__ float qel[4][64][4];   // [wave][j][head]
  __shared__ float rbl[4][64];
  __shared__ float aml[4][128];     // far-accumulator remap buffer (per wave)
  const int tid = threadIdx.x;

  const int w = tid >> 6, t = tid & 63;
  const int n = blockIdx.x * 4 + w;
  const int h = t >> 4;       // near-layout head (16-lane groups)
  const int j0 = t & 15;
  const int hw = t >> 5;      // half-wave id (far loop)
  const int c = t & 31;       // lane in half; owns dims 4c..4c+3 (far loop)
  uint qu = *(const uint*)&qnb[(size_t)n * DDIM + 2 * t];
  const float q0 = bfl(qu), q1 = bfh(qu);
  uint2 qp = *(const uint2*)&qnb[(size_t)n * DDIM + 4 * c];
  const float fq0 = bfl(qp.x), fq1 = bfh(qp.x), fq2 = bfl(qp.y), fq3 = bfh(qp.y);
  if (t < NRAD) {
    ushort4 qv = *(const ushort4*)&qe[(size_t)n * 200 + 4 * t];
    qel[w][t][0] = bfl(qv.x);
    qel[w][t][1] = bfl(qv.y);
    qel[w][t][2] = bfl(qv.z);
    qel[w][t][3] = bfl(qv.w);
  } else {
    qel[w][t][0] = 0.f; qel[w][t][1] = 0.f; qel[w][t][2] = 0.f; qel[w][t][3] = 0.f;
  }
  const int start = rowptr[n], nend = nearend[n], end = rowptr[n + 1];

  float s = 0.f, a0 = 0.f, a1 = 0.f;
  float4 arb = {0.f, 0.f, 0.f, 0.f};

  // ---- near loop (radial features active), full wave per edge ----
  for (int cb = start; cb < nend; cb += 64) {
    int cnt = min(nend - cb, 64);
    int2 e_t = make_int2(0, 0);
    if (t < cnt) e_t = er[cb + t];
    for (int i = 0; i < cnt; ++i) {
      int src = __shfl(e_t.x, i);
      float dd = __shfl(__int_as_float(e_t.y), i);
      uint2 kv = *(const uint2*)&kvb[(size_t)src * 256 + 4 * t];
      float pr = q0 * bfl(kv.x) + q1 * bfl(kv.y);
      float rb = (t < NRAD) ? rbf_fill(dd, t) : 0.f;
      rbl[w][t] = rb;
      pr = fmaf(rbl[w][j0], qel[w][j0][h], pr);
      pr = fmaf(rbl[w][j0 + 16], qel[w][j0 + 16][h], pr);
      pr = fmaf(rbl[w][j0 + 32], qel[w][j0 + 32][h], pr);
      pr = fmaf(rbl[w][j0 + 48], qel[w][j0 + 48][h], pr);
      pr = red16(pr);
      float ae = __expf(fminf(pr * SCALE_QK, 60.f));
      s += ae;
      a0 = fmaf(ae, bfh(kv.x), a0);
      a1 = fmaf(ae, bfh(kv.y), a1);
      float aex = __shfl(ae, 0);
      float aey = __shfl(ae, 16);
      float aez = __shfl(ae, 32);
      float aew = __shfl(ae, 48);
      arb.x = fmaf(rb, aex, arb.x);
      arb.y = fmaf(rb, aey, arb.y);
      arb.z = fmaf(rb, aez, arb.z);
      arb.w = fmaf(rb, aew, arb.w);
    }
  }

  // ---- far loop: wave-uniform trip count, 2 edges per half per iter, masked tails ----
  float sf = 0.f, af0 = 0.f, af1 = 0.f, af2 = 0.f, af3 = 0.f;
  float sg = 0.f, ag0 = 0.f, ag1 = 0.f, ag2 = 0.f, ag3 = 0.f;
  for (int cb = nend; cb < end; cb += 64) {
    int cnt = min(end - cb, 64);
    int src_t = 0;
    if (t < cnt) src_t = er[cb + t].x;
    int npair = (cnt + 3) >> 2;  // uniform across wave
    for (int k = 0; k < npair; ++k) {
      int iA = 4 * k + hw;
      int iB = iA + 2;
      bool vA = iA < cnt;
      bool vB = iB < cnt;
      int sA = __shfl(src_t, vA ? iA : 0);
      int sB = __shfl(src_t, vB ? iB : 0);
      uint4 kvA = *(const uint4*)&kvb[(size_t)sA * 256 + 8 * c];
      uint4 kvB = *(const uint4*)&kvb[(size_t)sB * 256 + 8 * c];
      float pA = fq0 * bfl(kvA.x) + fq1 * bfl(kvA.y);
      float pB = fq0 * bfl(kvB.x) + fq1 * bfl(kvB.y);
      pA = fmaf(fq2, bfl(kvA.z), pA);
      pB = fmaf(fq2, bfl(kvB.z), pB);
      pA = fmaf(fq3, bfl(kvA.w), pA);
      pB = fmaf(fq3, bfl(kvB.w), pB);
      pA = red8(pA);
      pB = red8(pB);
      float aeA = vA ? __expf(fminf(pA * SCALE_QK, 60.f)) : 0.f;
      float aeB = vB ? __expf(fminf(pB * SCALE_QK, 60.f)) : 0.f;
      sf += aeA;
      sg += aeB;
      af0 = fmaf(aeA, bfh(kvA.x), af0);
      ag0 = fmaf(aeB, bfh(kvB.x), ag0);
      af1 = fmaf(aeA, bfh(kvA.y), af1);
      ag1 = fmaf(aeB, bfh(kvB.y), ag1);
      af2 = fmaf(aeA, bfh(kvA.z), af2);
      ag2 = fmaf(aeB, bfh(kvB.z), ag2);
      af3 = fmaf(aeA, bfh(kvA.w), af3);
      ag3 = fmaf(aeB, bfh(kvB.w), ag3);
    }
  }
  sf += sg;
  af0 += ag0;
  af1 += ag1;
  af2 += ag2;
  af3 += ag3;
  // combine the two halves (same dims, different edge subsets)
  sf += __shfl_xor(sf, 32);
  af0 += __shfl_xor(af0, 32);
  af1 += __shfl_xor(af1, 32);
  af2 += __shfl_xor(af2, 32);
  af3 += __shfl_xor(af3, 32);
  // remap far accumulators (4 dims/lane) into near layout (2 dims/lane) via LDS
  aml[w][4 * c + 0] = af0;
  aml[w][4 * c + 1] = af1;
  aml[w][4 * c + 2] = af2;
  aml[w][4 * c + 3] = af3;
  a0 += aml[w][2 * t];
  a1 += aml[w][2 * t + 1];

  // ---- finalize: normalize; store a_norm (msgb) and arbn (into qe buffer) ----
  float4 s4;
  s4.x = __shfl(s, 0) + __shfl(sf, 0);
  s4.y = __shfl(s, 16) + __shfl(sf, 8);
  s4.z = __shfl(s, 32) + __shfl(sf, 16);
  s4.w = __shfl(s, 48) + __shfl(sf, 24);
  float4 inv4 = {1.f / (s4.x + 1e-9f), 1.f / (s4.y + 1e-9f),
                 1.f / (s4.z + 1e-9f), 1.f / (s4.w + 1e-9f)};
  float invo = (h == 0) ? inv4.x : (h == 1) ? inv4.y : (h == 2) ? inv4.z : inv4.w;
  if (t < NRAD) {
    ushort4 o = {f2bf(arb.x * inv4.x), f2bf(arb.y * inv4.y),
                 f2bf(arb.z * inv4.z), f2bf(arb.w * inv4.w)};
    *(ushort4*)&qe[(size_t)n * 200 + 4 * t] = o;
  }
  a0 *= invo;
  a1 *= invo;
  uint pk = (uint)f2bf(a0) | ((uint)f2bf(a1) << 16);
  *(uint*)&msgb[(size_t)n * DDIM + 2 * t] = pk;
}

// ---------------- graph sum (batch is sorted): 32 nodes/block, boundary atomics ----------------

#define GS_NODES 32
__global__ void k_graphsum(const float* __restrict__ x, const int* __restrict__ batch,
                           float* __restrict__ g) {
  int t = threadIdx.x;  // 128 dims
  int n0 = blockIdx.x * GS_NODES;
  int nend = n0 + GS_NODES;
  if (nend > NN) nend = NN;
  if (n0 >= NN) return;
  float acc = 0.f;
  int cur = batch[n0];
  for (int n = n0; n < nend; ++n) {
    int bb = batch[n];
    if (bb != cur) {
      atomicAdd(&g[(size_t)cur * DDIM + t], acc);
      acc = 0.f;
      cur = bb;
    }
    acc += x[(size_t)n * DDIM + t];
  }
  atomicAdd(&g[(size_t)cur * DDIM + t], acc);
}

// ---------------- output projection ----------------

__global__ void k_out(const float* __restrict__ g, const float* __restrict__ W,
                      const float* __restrict__ b, float* __restrict__ out) {
  int idx = blockIdx.x * blockDim.x + threadIdx.x;
  if (idx >= NGRAPH * DOUT) return;
  int r = idx / DOUT, c = idx % DOUT;
  float acc = b[c];
#pragma unroll 8
  for (int k = 0; k < DDIM; ++k) acc = fmaf(g[r * DDIM + k], W[k * DOUT + c], acc);
  out[idx] = acc;
}

// ---------------- launch ----------------

extern "C" void kernel_launch(void* const* d_in, const int* in_sizes, int n_in,
                              void* d_out, int out_size, void* d_ws, size_t ws_size,
                              hipStream_t stream) {
  const float* pos = (const float*)d_in[0];
  const int* at = (const int*)d_in[1];
  const int* ei = (const int*)d_in[2];
  const int* batch = (const int*)d_in[3];
  const float* emb = (const float*)d_in[4];
  const float* W_init = (const float*)d_in[5];
  const float* b_init = (const float*)d_in[6];
  const float* Wq = (const float*)d_in[7];
  const float* Wk = (const float*)d_in[8];
  const float* Wv = (const float*)d_in[9];
  const float* We = (const float*)d_in[10];
  const float* Wo = (const float*)d_in[11];
  const float* Wm1 = (const float*)d_in[12];
  const float* bm1 = (const float*)d_in[13];
  const float* Wm2 = (const float*)d_in[14];
  const float* bm2 = (const float*)d_in[15];
  const float* ln_g = (const float*)d_in[16];
  const float* ln_b = (const float*)d_in[17];
  const float* W_out = (const float*)d_in[18];
  const float* b_out = (const float*)d_in[19];
  float* out = (float*)d_out;

  const size_t ND = (size_t)NN * DDIM;  // 6.4M
  float* x = (float*)d_ws;              // f32 ND
  ushort* qnb = (ushort*)(x + ND);      // bf16 ND (alias hb)
  ushort* kvb = qnb + ND;               // bf16 2*ND interleaved k/v (alias h2 first half)
  ushort* msgb = kvb + 2 * ND;          // bf16 ND
  ushort* qe = msgb + ND;               // bf16 NN*200 (doubles as arbn)
  ushort* Wtb = qe + (size_t)NN * 200;  // bf16 12*16384
  ushort* WW = Wtb + 12 * 16384;        // bf16 2*128*256 (WeWo)
  ushort* WQET = WW + 2 * 32768;        // bf16 2*256*128 (WqWe^T)
  float* embW = (float*)(WQET + 2 * 32768);  // f32 NTYPE*DDIM
  float* de = embW + NTYPE * DDIM;      // f32 NE
  int* deg = (int*)(de + NE);
  int* cnear = deg + NN;
  int* cfar = cnear + NN;
  int* rowptr = cfar + NN;
  int2* er = (int2*)(rowptr + NN + 64);  // NE int2
  float* gb = (float*)(er + NE);         // NG*DDIM
  int* bsum = (int*)(gb + NGRAPH * DDIM);  // SCAN_N
  // total ~96.6 MB

  ushort* hb = qnb;
  ushort* h2 = kvb;  // kvb dead after attn within a layer; reused as h2

  k_pre<<<1526, 256, 0, stream>>>(Wq, Wk, Wv, Wo, Wm1, Wm2, We, emb, W_init, b_init,
                                  Wtb, WW, WQET, embW, deg);
  k_init2<<<(NN * 32 + 255) / 256, 256, 0, stream>>>(pos, at, embW, W_init, x);
  k_edge<<<(NE + 255) / 256, 256, 0, stream>>>(pos, ei, de, deg);
  k_scan1<<<SCAN_N, 256, 0, stream>>>(deg, bsum);
  k_scan2<<<1, 256, 0, stream>>>(bsum);
  k_scan3<<<SCAN_N, 256, 0, stream>>>(deg, bsum, rowptr, cnear, cfar);
  k_scatter<<<(NE + 255) / 256, 256, 0, stream>>>(ei, de, cnear, cfar, er);

  const int gg = (NN + 127) / 128;  // 391
  for (int l = 0; l < 2; ++l) {
    const ushort* Wt_l = Wtb + (size_t)l * 6 * 16384;
    const ushort* WQET_l = WQET + (size_t)l * 32768;
    const ushort* WW_l = WW + (size_t)l * 32768;

    k_qkv<<<gg, 256, 0, stream>>>(x, Wt_l, WQET_l, qnb, kvb, qe);
    k_attn10<<<NN / 4, 256, 0, stream>>>(qnb, kvb, qe, er, rowptr, cnear, msgb);

    // x += msg@Wo + arbn@WeWo, fused layernorm -> hb
    k_gemm2<false, false, true, true, true><<<gg, 256, 0, stream>>>(
        msgb, Wt_l + 3 * 16384, nullptr, x, x,
        ln_g + (size_t)l * DDIM, ln_b + (size_t)l * DDIM, hb, qe, WW_l);
    // h2 = gelu(hb@Wm1 + bm1)
    k_gemm2<true, true, false, false, false><<<gg, 256, 0, stream>>>(
        hb, Wt_l + 4 * 16384, bm1 + (size_t)l * DDIM, nullptr, h2,
        nullptr, nullptr, nullptr, nullptr, nullptr);
    // x += h2@Wm2 + bm2
    k_gemm2<true, false, true, false, false><<<gg, 256, 0, stream>>>(
        h2, Wt_l + 5 * 16384, bm2 + (size_t)l * DDIM, x, x,
        nullptr, nullptr, nullptr, nullptr, nullptr);
  }

  k_fill_f<<<(NGRAPH * DDIM + 255) / 256, 256, 0, stream>>>(gb, 0.f, NGRAPH * DDIM);
  k_graphsum<<<(NN + GS_NODES - 1) / GS_NODES, 128, 0, stream>>>(x, batch, gb);
  k_out<<<(NGRAPH * DOUT + 255) / 256, 256, 0, stream>>>(gb, W_out, b_out, out);
}